// Round 8
// baseline (22614.511 us; speedup 1.0000x reference)
//
#include <hip/hip_runtime.h>
#include <hip/hip_bf16.h>
#include <math.h>

#ifndef M_PIf
#define M_PIf 3.14159265358979323846f
#endif

static constexpr int kNFFT = 2048;
static constexpr int kHOP  = 512;
static constexpr int kBINS = 1025;
static constexpr int kT    = 862;     // frames == sequence length
static constexpr int kL    = 441000;
static constexpr int kB    = 4;
static constexpr int kNSIG = 8;       // B * 2 channels
static constexpr int kD    = 2050;
static constexpr int kHD   = 1025;    // head dim
static constexpr int kDFF  = 8200;
static constexpr int kBS   = kB * kT; // 3448 token rows
static constexpr int kD3   = 3 * kD;  // 6150
static constexpr float kAttnScale = 0.031234752377721214f; // 1/sqrt(1025)
static constexpr long kQK  = (long)kT * kHD;   // 883,550
static constexpr long kS2  = (long)kT * kT;    // 743,044
// padded bf16 strides (rows 16-B aligned)
static constexpr int kDP   = 2056;    // pad of 2050
static constexpr int kHDP  = 1032;    // pad of 1025
static constexpr int kTP   = 864;     // pad of 862
static constexpr long kS2P = (long)kT * kTP;   // 744,768
static constexpr int kMC   = 1724;    // FFN row chunk (2 chunks)

using bf16 = __hip_bfloat16;
typedef __attribute__((ext_vector_type(4))) float f32x4;
typedef __attribute__((ext_vector_type(8))) short bf16x8;

__device__ __forceinline__ float ldf(const float* p, long i) { return p[i]; }
__device__ __forceinline__ float ldf(const bf16* p, long i) {
  return __bfloat162float(p[i]);
}
__device__ __forceinline__ void sto(float* p, long i, float v) { p[i] = v; }
__device__ __forceinline__ void sto(bf16* p, long i, float v) {
  p[i] = __float2bfloat16(v);
}
// 16-element row loads for MFMA staging. bf16 path assumes 16-B alignment
// (all bf16 buffers use padded strides).
__device__ __forceinline__ void load16(const float* src, bf16* dst) {
#pragma unroll
  for (int e = 0; e < 16; ++e) dst[e] = __float2bfloat16(src[e]);
}
__device__ __forceinline__ void load16(const bf16* src, bf16* dst) {
  *(bf16x8*)(dst)     = *(const bf16x8*)(src);
  *(bf16x8*)(dst + 8) = *(const bf16x8*)(src + 8);
}

// Twiddle table: tw[m] = (cos(pi*m/1024), sin(pi*m/1024)), m in [0,1024).
__global__ void k_twiddle(float2* __restrict__ tw) {
  int m = blockIdx.x * 256 + threadIdx.x;
  if (m < 1024) {
    float s, c;
    sincosf(M_PIf * (float)m / 1024.f, &s, &c);
    tw[m] = make_float2(c, s);
  }
}

// ---------------------------------------------------------------------------
// 2048-point radix-2 Stockham FFT in LDS (natural order in/out), table-driven.
// ---------------------------------------------------------------------------
__device__ __forceinline__ void fft2048_lds(float*& sr, float*& si,
                                            float* dr, float* di, int tid,
                                            float dir,
                                            const float2* __restrict__ tw) {
  int s = 0;
  for (int Ns = 1; Ns < 2048; Ns <<= 1, ++s) {
#pragma unroll
    for (int q = 0; q < 4; ++q) {
      int j = tid + q * 256;          // 0..1023
      int base = j & (Ns - 1);
      int grp = j >> s;
      float2 t = tw[base << (10 - s)];
      float c = t.x, sn = dir * t.y;
      float ar = sr[j],       ai = si[j];
      float br = sr[j + 1024], bi = si[j + 1024];
      float tbr = br * c - bi * sn;
      float tbi = br * sn + bi * c;
      int o = (grp << (s + 1)) + base;
      dr[o]      = ar + tbr;  di[o]      = ai + tbi;
      dr[o + Ns] = ar - tbr;  di[o + Ns] = ai - tbi;
    }
    __syncthreads();
    float* t0 = sr; sr = dr; dr = t0;
    float* t1 = si; si = di; di = t1;
  }
}

// STFT: one block per (frame, signal). Writes interleaved (re,im) into out1.
__global__ __launch_bounds__(256) void k_stft(const float* __restrict__ mix,
                                              const float* __restrict__ win,
                                              const float2* __restrict__ tw,
                                              float* __restrict__ spec) {
  __shared__ float b0r[2048], b0i[2048], b1r[2048], b1i[2048];
  int t = blockIdx.x, sig = blockIdx.y, tid = threadIdx.x;
  const float* x = mix + (long)sig * kL;
  for (int i = tid; i < 2048; i += 256) {
    int src = t * kHOP + i - 1024;
    if (src < 0) src = -src;
    if (src >= kL) src = 2 * kL - 2 - src;
    b0r[i] = x[src] * win[i];
    b0i[i] = 0.f;
  }
  __syncthreads();
  float* sr = b0r; float* si = b0i;
  fft2048_lds(sr, si, b1r, b1i, tid, -1.f, tw);
  for (int k = tid; k < kBINS; k += 256) {
    long o = ((long)sig * kBINS + k) * kT + t;
    spec[o * 2]     = sr[k];
    spec[o * 2 + 1] = si[k];
  }
}

// iSTFT per-frame from interleaved spec: hermitian extend, iFFT, window.
__global__ __launch_bounds__(256) void k_istft(const float* __restrict__ spec,
                                               const float* __restrict__ win,
                                               const float2* __restrict__ tw,
                                               float* __restrict__ frames) {
  __shared__ float b0r[2048], b0i[2048], b1r[2048], b1i[2048];
  int t = blockIdx.x, sig = blockIdx.y, tid = threadIdx.x;
  for (int k = tid; k < kBINS; k += 256) {
    long o = ((long)sig * kBINS + k) * kT + t;
    b0r[k] = spec[o * 2];
    b0i[k] = spec[o * 2 + 1];
  }
  __syncthreads();
  for (int k = 1025 + tid; k < 2048; k += 256) {
    b0r[k] = b0r[2048 - k];
    b0i[k] = -b0i[2048 - k];
  }
  __syncthreads();
  float* sr = b0r; float* si = b0i;
  fft2048_lds(sr, si, b1r, b1i, tid, +1.f, tw);
  const float scale = 1.f / 2048.f;
  float* fo = frames + ((long)sig * kT + t) * 2048;
  for (int n = tid; n < 2048; n += 256) fo[n] = sr[n] * scale * win[n];
}

// Deterministic overlap-add gather (<=4 frames per output sample) + wsq div.
__global__ void k_gather(const float* __restrict__ frames,
                         const float* __restrict__ win,
                         float* __restrict__ out0) {
  long idx = (long)blockIdx.x * 256 + threadIdx.x;
  long total = (long)kNSIG * kL;
  if (idx >= total) return;
  int sig = (int)(idx / kL);
  int l = (int)(idx % kL);
  int j = l + 1024;
  int tmax = j >> 9; if (tmax > kT - 1) tmax = kT - 1;
  int v = j - 1536;
  int tmin = v > 0 ? (v >> 9) : 0;
  float acc = 0.f, w2 = 0.f;
  for (int t = tmin; t <= tmax; ++t) {
    int n = j - (t << 9);
    float w = win[n];
    acc += frames[((long)sig * kT + t) * 2048 + n];
    w2 = fmaf(w, w, w2);
  }
  out0[idx] = acc / (w2 > 1e-11f ? w2 : 1.f);
}

// conv1x1 (complex, per-channel) + transpose to (B,T,D) + positional enc.
__global__ void k_conv1_pe(const float* __restrict__ spec,
                           const float* __restrict__ c1wr, const float* __restrict__ c1br,
                           const float* __restrict__ c1wi, const float* __restrict__ c1bi,
                           float* __restrict__ xr, float* __restrict__ xi) {
  long idx = (long)blockIdx.x * 256 + threadIdx.x;
  long total = (long)kB * 2 * kBINS * kT;
  if (idx >= total) return;
  int t = (int)(idx % kT);
  long r0 = idx / kT;
  int bin = (int)(r0 % kBINS);
  long r1 = r0 / kBINS;
  int ch = (int)(r1 % 2);
  int b = (int)(r1 / 2);
  float re = spec[idx * 2], im = spec[idx * 2 + 1];
  float wr = c1wr[ch], br = c1br[ch], wi = c1wi[ch], bi = c1bi[ch];
  float nr = (re * wr + br) - (im * wi + bi);
  float ni = (im * wr + br) + (re * wi + bi);
  int d = bin * 2 + ch;
  int k = d >> 1;
  float dv = expf((float)k * (-9.210340371976184f / 1025.0f));
  float arg = (float)t * dv;
  float pe = (d & 1) ? cosf(arg) : sinf(arg);
  long ro = ((long)(b * kT + t)) * kD + d;
  xr[ro] = nr + pe;
  xi[ro] = ni + pe;
}

// strided fp32 -> bf16 matrix convert (dst rows padded/16-B aligned)
__global__ void k_cvt(const float* __restrict__ src, bf16* __restrict__ dst,
                      long total, int cols, int lds, int ldd) {
  long idx = (long)blockIdx.x * 256 + threadIdx.x;
  if (idx >= total) return;
  int r = (int)(idx / cols), c = (int)(idx % cols);
  dst[(long)r * ldd + c] = __float2bfloat16(src[(long)r * lds + c]);
}

// ---------------------------------------------------------------------------
// fp32 VALU GEMM (numerically-critical Q/K/score path). BMODE=0: C = A*B^T.
// ---------------------------------------------------------------------------
template <int BMODE, typename TA, typename TB, typename TC>
__global__ __launch_bounds__(256) void k_gemm(
    const TA* __restrict__ A, const TB* __restrict__ B,
    TC* __restrict__ C, const float* __restrict__ bias,
    int M, int N, int K, int lda, int ldb, int ldc,
    float sign, float bscale, int accum, int relu) {
  __shared__ __align__(16) float As[16][64];
  __shared__ __align__(16) float Bs[16][64];
  int tid = threadIdx.x;
  int tx = tid & 15, ty = tid >> 4;
  int bm = blockIdx.y * 64, bn = blockIdx.x * 64;
  float acc[4][4] = {};
  for (int k0 = 0; k0 < K; k0 += 16) {
    {
      int row = tid >> 2, kq = (tid & 3) * 4;
      int gm = bm + row;
#pragma unroll
      for (int e = 0; e < 4; ++e) {
        int gk = k0 + kq + e;
        As[kq + e][row] = (gm < M && gk < K) ? ldf(A, (long)gm * lda + gk) : 0.f;
      }
    }
    if (BMODE == 0) {
      int row = tid >> 2, kq = (tid & 3) * 4;
      int gn = bn + row;
#pragma unroll
      for (int e = 0; e < 4; ++e) {
        int gk = k0 + kq + e;
        Bs[kq + e][row] = (gn < N && gk < K) ? ldf(B, (long)gn * ldb + gk) : 0.f;
      }
    } else {
      int kk = tid >> 4, nq = (tid & 15) * 4;
#pragma unroll
      for (int e = 0; e < 4; ++e) {
        int gn = bn + nq + e;
        Bs[kk][nq + e] =
            ((k0 + kk) < K && gn < N) ? ldf(B, (long)(k0 + kk) * ldb + gn) : 0.f;
      }
    }
    __syncthreads();
#pragma unroll
    for (int kk = 0; kk < 16; ++kk) {
      const float4 av = *(const float4*)&As[kk][ty * 4];
      const float4 bv = *(const float4*)&Bs[kk][tx * 4];
      float a4[4] = {av.x, av.y, av.z, av.w};
      float b4[4] = {bv.x, bv.y, bv.z, bv.w};
#pragma unroll
      for (int i = 0; i < 4; ++i)
#pragma unroll
        for (int jj = 0; jj < 4; ++jj)
          acc[i][jj] = fmaf(a4[i], b4[jj], acc[i][jj]);
    }
    __syncthreads();
  }
#pragma unroll
  for (int i = 0; i < 4; ++i) {
    int gm = bm + ty * 4 + i;
    if (gm >= M) continue;
#pragma unroll
    for (int jj = 0; jj < 4; ++jj) {
      int gn = bn + tx * 4 + jj;
      if (gn >= N) continue;
      float v = sign * acc[i][jj];
      if (bias) v += bscale * bias[gn];
      long co = (long)gm * ldc + gn;
      if (accum) v += ldf(C, co);
      if (relu) v = fmaxf(v, 0.f);
      sto(C, co, v);
    }
  }
}

// ---------------------------------------------------------------------------
// bf16 MFMA GEMM (16x16x32), fp32 accumulate. 128x128 tile, BK=32, 4 waves.
// z-batched via aSz/bSz/cSz element strides. bf16 operands use 16-B vector
// staging (all bf16 buffers have 16-B-aligned row strides).
// ---------------------------------------------------------------------------
template <int BMODE, typename TA, typename TB, typename TC>
__global__ __launch_bounds__(256) void k_mfma(
    const TA* __restrict__ A, const TB* __restrict__ B,
    TC* __restrict__ C, const float* __restrict__ bias,
    int M, int N, int K, int lda, int ldb, int ldc,
    long aSz, long bSz, long cSz,
    float sign, float bscale, int accum, int relu) {
  A += (long)blockIdx.z * aSz;
  B += (long)blockIdx.z * bSz;
  C += (long)blockIdx.z * cSz;
  __shared__ __align__(16) bf16 As[128][40];
  __shared__ __align__(16) bf16 Bs[128][40];
  int tid = threadIdx.x;
  int bm = blockIdx.y * 128, bn = blockIdx.x * 128;
  int lane = tid & 63, w = tid >> 6;
  int wr = (w >> 1) * 64, wc = (w & 1) * 64;
  int fr = lane & 15;
  int fq = lane >> 4;
  f32x4 acc[4][4] = {};

  int sr = tid >> 1;            // staging row 0..127
  int sk = (tid & 1) * 16;      // staging k offset 0/16

  for (int k0 = 0; k0 < K; k0 += 32) {
    // ---- stage A (row-major MxK) -> As[r][k]
    {
      int gm = bm + sr;
      bf16 tmp[16];
      if (gm < M && k0 + sk + 16 <= K) {
        load16(A + (long)gm * lda + k0 + sk, tmp);
      } else {
#pragma unroll
        for (int e = 0; e < 16; ++e) {
          int gk = k0 + sk + e;
          tmp[e] = __float2bfloat16(
              (gm < M && gk < K) ? ldf(A, (long)gm * lda + gk) : 0.f);
        }
      }
      *(bf16x8*)&As[sr][sk]     = *(bf16x8*)&tmp[0];
      *(bf16x8*)&As[sr][sk + 8] = *(bf16x8*)&tmp[8];
    }
    // ---- stage B -> Bs[n][k]
    if (BMODE == 0) {
      int gn = bn + sr;
      bf16 tmp[16];
      if (gn < N && k0 + sk + 16 <= K) {
        load16(B + (long)gn * ldb + k0 + sk, tmp);
      } else {
#pragma unroll
        for (int e = 0; e < 16; ++e) {
          int gk = k0 + sk + e;
          tmp[e] = __float2bfloat16(
              (gn < N && gk < K) ? ldf(B, (long)gn * ldb + gk) : 0.f);
        }
      }
      *(bf16x8*)&Bs[sr][sk]     = *(bf16x8*)&tmp[0];
      *(bf16x8*)&Bs[sr][sk + 8] = *(bf16x8*)&tmp[8];
    } else {
      int kk = tid >> 3;          // 0..31
      int nq = (tid & 7) * 16;    // 0..112
      int gk = k0 + kk;
      bf16 tmp[16];
      if (gk < K && bn + nq + 16 <= N) {
        load16(B + (long)gk * ldb + bn + nq, tmp);
      } else {
#pragma unroll
        for (int e = 0; e < 16; ++e) {
          int gn = bn + nq + e;
          tmp[e] = __float2bfloat16(
              (gk < K && gn < N) ? ldf(B, (long)gk * ldb + gn) : 0.f);
        }
      }
#pragma unroll
      for (int e = 0; e < 16; ++e) Bs[nq + e][kk] = tmp[e];
    }
    __syncthreads();
    bf16x8 a[4], b[4];
#pragma unroll
    for (int i = 0; i < 4; ++i)
      a[i] = *(const bf16x8*)&As[wr + i * 16 + fr][fq * 8];
#pragma unroll
    for (int j = 0; j < 4; ++j)
      b[j] = *(const bf16x8*)&Bs[wc + j * 16 + fr][fq * 8];
#pragma unroll
    for (int i = 0; i < 4; ++i)
#pragma unroll
      for (int j = 0; j < 4; ++j)
        acc[i][j] = __builtin_amdgcn_mfma_f32_16x16x32_bf16(
            a[i], b[j], acc[i][j], 0, 0, 0);
    __syncthreads();
  }
  // ---- epilogue: C/D layout col=lane&15, row=4*(lane>>4)+reg
#pragma unroll
  for (int i = 0; i < 4; ++i) {
#pragma unroll
    for (int j = 0; j < 4; ++j) {
      int gn = bn + wc + j * 16 + fr;
      if (gn >= N) continue;
      float bv = bias ? bscale * bias[gn] : 0.f;
#pragma unroll
      for (int r = 0; r < 4; ++r) {
        int gm = bm + wr + i * 16 + fq * 4 + r;
        if (gm >= M) continue;
        float v = sign * acc[i][j][r] + bv;
        long co = (long)gm * ldc + gn;
        if (accum) v += ldf(C, co);
        if (relu) v = fmaxf(v, 0.f);
        sto(C, co, v);
      }
    }
  }
}

// Per-head fused softmax over 4 fp32 score mats (stride kS2) + fold into
// 3 bf16 prob mats (row stride kTP): P0=Arr-Aii, P1=Ari+Air, P2=Ari-Air.
__global__ __launch_bounds__(256) void k_smf(const float* __restrict__ S,
                                             bf16* __restrict__ P) {
  long rbase = (long)blockIdx.x * kT;
  long pbase = (long)blockIdx.x * kTP;
  int tid = threadIdx.x;
  int lane = tid & 63, w = tid >> 6;
  float v[4][4];
  float mx[4] = {-3.4e38f, -3.4e38f, -3.4e38f, -3.4e38f};
#pragma unroll
  for (int c = 0; c < 4; ++c) {
    const float* row = S + c * kS2 + rbase;
#pragma unroll
    for (int q = 0; q < 4; ++q) {
      int i = tid + q * 256;
      v[c][q] = (i < kT) ? row[i] : -3.4e38f;
      mx[c] = fmaxf(mx[c], v[c][q]);
    }
  }
  __shared__ float redm[4][4];
  for (int o = 32; o > 0; o >>= 1)
#pragma unroll
    for (int c = 0; c < 4; ++c) mx[c] = fmaxf(mx[c], __shfl_down(mx[c], o));
  if (lane == 0)
#pragma unroll
    for (int c = 0; c < 4; ++c) redm[w][c] = mx[c];
  __syncthreads();
#pragma unroll
  for (int c = 0; c < 4; ++c)
    mx[c] = fmaxf(fmaxf(redm[0][c], redm[1][c]), fmaxf(redm[2][c], redm[3][c]));
  __syncthreads();
  float sm[4] = {0.f, 0.f, 0.f, 0.f};
#pragma unroll
  for (int c = 0; c < 4; ++c)
#pragma unroll
    for (int q = 0; q < 4; ++q) {
      int i = tid + q * 256;
      if (i < kT) {
        v[c][q] = expf(kAttnScale * (v[c][q] - mx[c]));
        sm[c] += v[c][q];
      }
    }
  __shared__ float reds[4][4];
  for (int o = 32; o > 0; o >>= 1)
#pragma unroll
    for (int c = 0; c < 4; ++c) sm[c] += __shfl_down(sm[c], o);
  if (lane == 0)
#pragma unroll
    for (int c = 0; c < 4; ++c) reds[w][c] = sm[c];
  __syncthreads();
  float inv[4];
#pragma unroll
  for (int c = 0; c < 4; ++c)
    inv[c] = 1.f / (reds[0][c] + reds[1][c] + reds[2][c] + reds[3][c]);
  bf16* p0 = P + pbase;
  bf16* p1 = P + kS2P + pbase;
  bf16* p2 = P + 2 * kS2P + pbase;
#pragma unroll
  for (int q = 0; q < 4; ++q) {
    int i = tid + q * 256;
    if (i >= kT) continue;
    float a0 = v[0][q] * inv[0], a1 = v[1][q] * inv[1];
    float a2 = v[2][q] * inv[2], a3 = v[3][q] * inv[3];
    p0[i] = __float2bfloat16(a0 - a3);
    p1[i] = __float2bfloat16(a1 + a2);
    p2[i] = __float2bfloat16(a1 - a2);
  }
}

// LayerNorm over rows of length d, in place (fp32).
__global__ __launch_bounds__(256) void k_ln(float* __restrict__ X,
                                            const float* __restrict__ g,
                                            const float* __restrict__ b, int d) {
  long row = blockIdx.x;
  float* x = X + row * d;
  int tid = threadIdx.x;
  float s = 0.f, s2 = 0.f;
  for (int i = tid; i < d; i += 256) {
    float v = x[i];
    s += v;
    s2 = fmaf(v, v, s2);
  }
  __shared__ float rs[4], rs2[4];
  for (int o = 32; o > 0; o >>= 1) {
    s += __shfl_down(s, o);
    s2 += __shfl_down(s2, o);
  }
  int lane = tid & 63, w = tid >> 6;
  if (lane == 0) { rs[w] = s; rs2[w] = s2; }
  __syncthreads();
  float st = rs[0] + rs[1] + rs[2] + rs[3];
  float s2t = rs2[0] + rs2[1] + rs2[2] + rs2[3];
  float m = st / d;
  float var = s2t / d - m * m;
  float inv = rsqrtf(var + 1e-5f);
  for (int i = tid; i < d; i += 256) x[i] = (x[i] - m) * inv * g[i] + b[i];
}

// Final complex conv1x1 mask + sigmoid gating of spec (in-place in out1).
__global__ void k_mask(const float* __restrict__ gr_, const float* __restrict__ gi_,
                       const float* __restrict__ c2wr, const float* __restrict__ c2br,
                       const float* __restrict__ c2wi, const float* __restrict__ c2bi,
                       float* __restrict__ spec) {
  long idx = (long)blockIdx.x * 256 + threadIdx.x;
  long total = (long)kB * 2 * kBINS * kT;
  if (idx >= total) return;
  int t = (int)(idx % kT);
  long r0 = idx / kT;
  int bin = (int)(r0 % kBINS);
  long r1 = r0 / kBINS;
  int ch = (int)(r1 % 2);
  int b = (int)(r1 / 2);
  long ro = ((long)(b * kT + t)) * kD + (bin * 2 + ch);
  float gr = gr_[ro], gi = gi_[ro];
  float wr = c2wr[ch], br = c2br[ch], wi = c2wi[ch], bi = c2bi[ch];
  float mr = (gr * wr + br) - (gi * wi + bi);
  float mi = (gi * wr + br) + (gr * wi + bi);
  float re = spec[idx * 2], im = spec[idx * 2 + 1];
  spec[idx * 2]     = re / (1.f + expf(-mr));
  spec[idx * 2 + 1] = im / (1.f + expf(-mi));
}

extern "C" void kernel_launch(void* const* d_in, const int* in_sizes, int n_in,
                              void* d_out, int out_size, void* d_ws, size_t ws_size,
                              hipStream_t stream) {
  const float* mix        = (const float*)d_in[0];
  const float* window     = (const float*)d_in[1];
  const float* c1wr       = (const float*)d_in[2];
  const float* c1br       = (const float*)d_in[3];
  const float* c1wi       = (const float*)d_in[4];
  const float* c1bi       = (const float*)d_in[5];
  const float* c2wr       = (const float*)d_in[6];
  const float* c2br       = (const float*)d_in[7];
  const float* c2wi       = (const float*)d_in[8];
  const float* c2bi       = (const float*)d_in[9];
  const float* attn_in_w  = (const float*)d_in[10];
  const float* attn_in_b  = (const float*)d_in[11];
  const float* attn_out_w = (const float*)d_in[12];
  const float* attn_out_b = (const float*)d_in[13];
  const float* l1wr       = (const float*)d_in[14];
  const float* l1br       = (const float*)d_in[15];
  const float* l1wi       = (const float*)d_in[16];
  const float* l1bi       = (const float*)d_in[17];
  const float* l2wr       = (const float*)d_in[18];
  const float* l2br       = (const float*)d_in[19];
  const float* l2wi       = (const float*)d_in[20];
  const float* l2bi       = (const float*)d_in[21];
  const float* n1_gr      = (const float*)d_in[22];
  const float* n1_br      = (const float*)d_in[23];
  const float* n1_gi      = (const float*)d_in[24];
  const float* n1_bi      = (const float*)d_in[25];
  const float* n2_gr      = (const float*)d_in[26];
  const float* n2_br      = (const float*)d_in[27];
  const float* n2_gi      = (const float*)d_in[28];
  const float* n2_bi      = (const float*)d_in[29];

  // ---- Workspace arenas (bytes). Total 169,649,792 (< 188.9 MB proven).
  char* wsb = (char*)d_ws;
  const size_t oT = 0;               // xr, xi fp32 (56,547,200)
  const size_t oO = 56547200;        // or_, oi fp32 / FFN hidden chunk / frames
  const size_t oS = 113094400;       // attention scratch / FFN weight scratch
  const size_t oTW = 169641600;      // twiddle table (8,192)
  const size_t kNeed = 169649792;
  if (ws_size < kNeed) return;  // fail signature: out0 all-zero (2.578125)

  float* xr  = (float*)(wsb + oT);
  float* xi  = xr + 7068400L;
  float* or_ = (float*)(wsb + oO);
  float* oi  = or_ + 7068400L;
  // attention-phase scratch inside S:
  float* qr = (float*)(wsb + oS);                 // 862x1025 f32
  float* qi = qr + kQK;
  float* kr = qi + kQK;
  float* ki = kr + kQK;
  bf16*  vr = (bf16*)(wsb + oS + 14136800);       // 4 x 862 x 1032 bf16
  bf16*  vi = (bf16*)(wsb + oS + 21253472);
  float* sS = (float*)(wsb + oS + 28370144);      // 4 x 862x862 f32
  bf16*  sP = (bf16*)(wsb + oS + 40258848);       // 3 x 862x864 bf16
  bf16*  Wvb = (bf16*)(wsb + oS + 44727456);      // 1025x2056 bf16
  bf16*  Wob = (bf16*)(wsb + oS);                 // 2050x2056 (after attn)
  // FFN-phase overlays:
  bf16*  Wb  = (bf16*)(wsb + oS);                 // 8200x2056 / 2050x8200
  bf16*  Abr = (bf16*)(wsb + oS + 33718400);      // 1724x2056
  bf16*  Abi = (bf16*)(wsb + oS + 40807488);
  bf16*  hrc = (bf16*)(wsb + oO);                 // 1724x8200
  bf16*  hic = (bf16*)(wsb + oO + 28273600);
  float* frames = (float*)(wsb + oO);             // 14,123,008 f32
  float2* tw = (float2*)(wsb + oTW);

  float* out0 = (float*)d_out;
  float* spec = out0 + (long)kNSIG * kL;  // out1: interleaved (re,im)

  auto cvt = [&](const float* src, bf16* dst, long rows, int cols, int lds,
                 int ldd) {
    long total = rows * cols;
    k_cvt<<<(int)((total + 255) / 256), 256, 0, stream>>>(src, dst, total,
                                                          cols, lds, ldd);
  };

  // 0) twiddle table
  k_twiddle<<<4, 256, 0, stream>>>(tw);

  // 1) STFT -> spec (out1)
  k_stft<<<dim3(kT, kNSIG), 256, 0, stream>>>(mix, window, tw, spec);

  // 2) conv1 + pos-enc -> fp32 tokens (T arena)
  long nct = (long)kB * 2 * kBINS * kT;
  k_conv1_pe<<<(nct + 255) / 256, 256, 0, stream>>>(spec, c1wr, c1br, c1wi,
                                                    c1bi, xr, xi);

  // 3) attention: h-outer (share Wv convert + batched V proj), b-inner.
  for (int h = 0; h < 2; ++h) {
    const float* Wq = attn_in_w + (long)(h * kHD) * kD;
    const float* Wk = attn_in_w + (long)(kD + h * kHD) * kD;
    const float* Wv = attn_in_w + (long)(2 * kD + h * kHD) * kD;
    const float* bq = attn_in_b + h * kHD;
    const float* bk = attn_in_b + kD + h * kHD;
    const float* bv = attn_in_b + 2 * kD + h * kHD;
    // Wv slice -> bf16 padded
    cvt(Wv, Wvb, kHD, kD, kD, kDP);
    // V projection, z-batched over b: vr/vi are (4 x 862 x 1032)
    dim3 gv((kHD + 127) / 128, (kT + 127) / 128, 4);
    k_mfma<0, float, bf16, bf16><<<gv, 256, 0, stream>>>(
        xr, Wvb, vr, bv, kT, kHD, kD, kD, kDP, kHDP,
        (long)kT * kD, 0, (long)kT * kHDP, 1.f, 1.f, 0, 0);
    k_mfma<0, float, bf16, bf16><<<gv, 256, 0, stream>>>(
        xi, Wvb, vi, bv, kT, kHD, kD, kD, kDP, kHDP,
        (long)kT * kD, 0, (long)kT * kHDP, 1.f, 1.f, 0, 0);
    for (int b = 0; b < kB; ++b) {
      const float* xrb = xr + (long)b * kT * kD;
      const float* xib = xi + (long)b * kT * kD;
      // Q,K projections: fp32 VALU (argmax-critical)
      dim3 gp((kHD + 63) / 64, (kT + 63) / 64, 1);
      k_gemm<0, float, float, float><<<gp, 256, 0, stream>>>(
          xrb, Wq, qr, bq, kT, kHD, kD, kD, kD, kHD, 1.f, 1.f, 0, 0);
      k_gemm<0, float, float, float><<<gp, 256, 0, stream>>>(
          xib, Wq, qi, bq, kT, kHD, kD, kD, kD, kHD, 1.f, 1.f, 0, 0);
      k_gemm<0, float, float, float><<<gp, 256, 0, stream>>>(
          xrb, Wk, kr, bk, kT, kHD, kD, kD, kD, kHD, 1.f, 1.f, 0, 0);
      k_gemm<0, float, float, float><<<gp, 256, 0, stream>>>(
          xib, Wk, ki, bk, kT, kHD, kD, kD, kD, kHD, 1.f, 1.f, 0, 0);
      // scores: rr, ri, ir, ii (fp32 VALU)
      dim3 gs((kT + 63) / 64, (kT + 63) / 64, 1);
      k_gemm<0, float, float, float><<<gs, 256, 0, stream>>>(
          qr, kr, sS,          nullptr, kT, kT, kHD, kHD, kHD, kT, 1.f, 0.f, 0, 0);
      k_gemm<0, float, float, float><<<gs, 256, 0, stream>>>(
          qr, ki, sS + kS2,    nullptr, kT, kT, kHD, kHD, kHD, kT, 1.f, 0.f, 0, 0);
      k_gemm<0, float, float, float><<<gs, 256, 0, stream>>>(
          qi, kr, sS + 2*kS2,  nullptr, kT, kT, kHD, kHD, kHD, kT, 1.f, 0.f, 0, 0);
      k_gemm<0, float, float, float><<<gs, 256, 0, stream>>>(
          qi, ki, sS + 3*kS2,  nullptr, kT, kT, kHD, kHD, kHD, kT, 1.f, 0.f, 0, 0);
      // fused softmax + fold -> P0,P1,P2 (bf16, stride kTP)
      k_smf<<<kT, 256, 0, stream>>>(sS, sP);
      // PV: MFMA bf16 (A=sP stride kTP, B=V slice stride kHDP)
      const bf16* vrb = vr + (long)b * kT * kHDP;
      const bf16* vib = vi + (long)b * kT * kHDP;
      float* Cr = or_ + (long)b * kT * kD + h * kHD;
      float* Ci = oi  + (long)b * kT * kD + h * kHD;
      dim3 gpv((kHD + 127) / 128, (kT + 127) / 128, 1);
      k_mfma<1, bf16, bf16, float><<<gpv, 256, 0, stream>>>(
          sP,           vrb, Cr, nullptr, kT, kHD, kT, kTP, kHDP, kD,
          0, 0, 0, 1.f, 0.f, 0, 0);
      k_mfma<1, bf16, bf16, float><<<gpv, 256, 0, stream>>>(
          sP + 2*kS2P,  vib, Cr, nullptr, kT, kHD, kT, kTP, kHDP, kD,
          0, 0, 0, 1.f, 0.f, 1, 0);
      k_mfma<1, bf16, bf16, float><<<gpv, 256, 0, stream>>>(
          sP,           vib, Ci, nullptr, kT, kHD, kT, kTP, kHDP, kD,
          0, 0, 0, 1.f, 0.f, 0, 0);
      k_mfma<1, bf16, bf16, float><<<gpv, 256, 0, stream>>>(
          sP + kS2P,    vrb, Ci, nullptr, kT, kHD, kT, kTP, kHDP, kD,
          0, 0, 0, 1.f, 0.f, 1, 0);
    }
  }

  // 4) output projection (attn scratch dead -> Wob at S base)
  cvt(attn_out_w, Wob, kD, kD, kD, kDP);
  {
    dim3 g((kD + 127) / 128, (kBS + 127) / 128, 1);
    k_mfma<0, float, bf16, float><<<g, 256, 0, stream>>>(
        or_, Wob, xr, nullptr,    kBS, kD, kD, kD, kDP, kD, 0,0,0, 1.f, 0.f, 0, 0);
    k_mfma<0, float, bf16, float><<<g, 256, 0, stream>>>(
        oi,  Wob, xi, attn_out_b, kBS, kD, kD, kD, kDP, kD, 0,0,0, 1.f, 2.f, 0, 0);
  }

  // 5) LN1 (fp32, in T)
  k_ln<<<kBS, 256, 0, stream>>>(xr, n1_gr, n1_br, kD);
  k_ln<<<kBS, 256, 0, stream>>>(xi, n1_gi, n1_bi, kD);

  // 6+7) FFN in 2 row-chunks; weights converted bf16 one-at-a-time into S.
  for (int c = 0; c < 2; ++c) {
    const float* xrc = xr + (long)c * kMC * kD;
    const float* xic = xi + (long)c * kMC * kD;
    float* xro = xr + (long)c * kMC * kD;
    float* xio = xi + (long)c * kMC * kD;
    cvt(xrc, Abr, kMC, kD, kD, kDP);
    cvt(xic, Abi, kMC, kD, kD, kDP);
    dim3 g1((kDFF + 127) / 128, (kMC + 127) / 128, 1);
    // FFN1
    cvt(l1wr, Wb, kDFF, kD, kD, kDP);
    k_mfma<0, bf16, bf16, bf16><<<g1, 256, 0, stream>>>(
        Abr, Wb, hrc, l1br, kMC, kDFF, kD, kDP, kDP, kDFF, 0,0,0,  1.f,  1.f, 0, 0);
    k_mfma<0, bf16, bf16, bf16><<<g1, 256, 0, stream>>>(
        Abi, Wb, hic, l1br, kMC, kDFF, kD, kDP, kDP, kDFF, 0,0,0,  1.f,  1.f, 0, 0);
    cvt(l1wi, Wb, kDFF, kD, kD, kDP);
    k_mfma<0, bf16, bf16, bf16><<<g1, 256, 0, stream>>>(
        Abi, Wb, hrc, l1bi, kMC, kDFF, kD, kDP, kDP, kDFF, 0,0,0, -1.f, -1.f, 1, 1);
    k_mfma<0, bf16, bf16, bf16><<<g1, 256, 0, stream>>>(
        Abr, Wb, hic, l1bi, kMC, kDFF, kD, kDP, kDP, kDFF, 0,0,0,  1.f,  1.f, 1, 1);
    // FFN2
    dim3 g2((kD + 127) / 128, (kMC + 127) / 128, 1);
    cvt(l2wr, Wb, kD, kDFF, kDFF, kDFF);
    k_mfma<0, bf16, bf16, float><<<g2, 256, 0, stream>>>(
        hrc, Wb, xro, l2br, kMC, kD, kDFF, kDFF, kDFF, kD, 0,0,0,  1.f,  1.f, 0, 0);
    k_mfma<0, bf16, bf16, float><<<g2, 256, 0, stream>>>(
        hic, Wb, xio, l2br, kMC, kD, kDFF, kDFF, kDFF, kD, 0,0,0,  1.f,  1.f, 0, 0);
    cvt(l2wi, Wb, kD, kDFF, kDFF, kDFF);
    k_mfma<0, bf16, bf16, float><<<g2, 256, 0, stream>>>(
        hic, Wb, xro, l2bi, kMC, kD, kDFF, kDFF, kDFF, kD, 0,0,0, -1.f, -1.f, 1, 0);
    k_mfma<0, bf16, bf16, float><<<g2, 256, 0, stream>>>(
        hrc, Wb, xio, l2bi, kMC, kD, kDFF, kDFF, kDFF, kD, 0,0,0,  1.f,  1.f, 1, 0);
  }

  // 8) LN2 (fp32, in T)
  k_ln<<<kBS, 256, 0, stream>>>(xr, n2_gr, n2_br, kD);
  k_ln<<<kBS, 256, 0, stream>>>(xi, n2_gi, n2_bi, kD);

  // 9) mask + gate spec in-place (out1 holds final spec2)
  k_mask<<<(nct + 255) / 256, 256, 0, stream>>>(xr, xi, c2wr, c2br, c2wi,
                                                c2bi, spec);

  // 10) iSTFT (frames over O arena) + overlap-add -> out0
  k_istft<<<dim3(kT, kNSIG), 256, 0, stream>>>(spec, window, tw, frames);
  k_gather<<<(int)(((long)kNSIG * kL + 255) / 256), 256, 0, stream>>>(
      frames, window, out0);
}

// Round 10
// 13277.492 us; speedup vs baseline: 1.7032x; 1.7032x over previous
//
#include <hip/hip_runtime.h>
#include <hip/hip_bf16.h>
#include <math.h>

#ifndef M_PIf
#define M_PIf 3.14159265358979323846f
#endif

static constexpr int kNFFT = 2048;
static constexpr int kHOP  = 512;
static constexpr int kBINS = 1025;
static constexpr int kT    = 862;
static constexpr int kL    = 441000;
static constexpr int kB    = 4;
static constexpr int kNSIG = 8;
static constexpr int kD    = 2050;
static constexpr int kHD   = 1025;
static constexpr int kDFF  = 8200;
static constexpr int kBS   = kB * kT;   // 3448
static constexpr float kAttnScale = 0.031234752377721214f; // 1/sqrt(1025)
static constexpr long kS2  = (long)kT * kT;    // 743,044
static constexpr int kTP   = 864;
static constexpr long kS2P = (long)kT * kTP;   // 744,768
static constexpr int kDP   = 2056;   // padded row (bf16, 16B aligned)
static constexpr int kHDP  = 1032;
static constexpr int kMC   = 1724;   // FFN M chunk
static constexpr int kNH   = 4104;   // FFN1 N-half / FFN2 K-half (8-mult)
static constexpr int kHLD  = 8208;   // hidden row stride

using bf16 = __hip_bfloat16;
typedef __attribute__((ext_vector_type(4))) float f32x4;
typedef __attribute__((ext_vector_type(8))) short bf16x8;

__device__ __forceinline__ float ldf(const float* p, long i) { return p[i]; }
__device__ __forceinline__ float ldf(const bf16* p, long i) {
  return __bfloat162float(p[i]);
}
__device__ __forceinline__ void sto(float* p, long i, float v) { p[i] = v; }
__device__ __forceinline__ void sto(bf16* p, long i, float v) {
  p[i] = __float2bfloat16(v);
}
__device__ __forceinline__ void load16(const float* src, bf16* dst) {
#pragma unroll
  for (int e = 0; e < 16; ++e) dst[e] = __float2bfloat16(src[e]);
}
__device__ __forceinline__ void load16(const bf16* src, bf16* dst) {
  *(bf16x8*)(dst)     = *(const bf16x8*)(src);
  *(bf16x8*)(dst + 8) = *(const bf16x8*)(src + 8);
}

// Stage one 16-element bf16 chunk of a row-major matrix into LDS row.
template <typename T>
__device__ __forceinline__ void stage_row16(const T* S, int grow, int glim,
                                            int lda, int k0sk, int K,
                                            bf16* dst) {
  bf16 tmp[16];
  if (grow < glim && k0sk + 16 <= K) {
    load16(S + (long)grow * lda + k0sk, tmp);
  } else {
#pragma unroll
    for (int e = 0; e < 16; ++e) {
      int gk = k0sk + e;
      tmp[e] = __float2bfloat16(
          (grow < glim && gk < K) ? ldf(S, (long)grow * lda + gk) : 0.f);
    }
  }
  *(bf16x8*)(dst)     = *(bf16x8*)&tmp[0];
  *(bf16x8*)(dst + 8) = *(bf16x8*)&tmp[8];
}

// ---------------------------------------------------------------------------
__global__ void k_twiddle(float2* __restrict__ tw) {
  int m = blockIdx.x * 256 + threadIdx.x;
  if (m < 1024) {
    float s, c;
    sincosf(M_PIf * (float)m / 1024.f, &s, &c);
    tw[m] = make_float2(c, s);
  }
}

__device__ __forceinline__ void fft2048_lds(float*& sr, float*& si,
                                            float* dr, float* di, int tid,
                                            float dir,
                                            const float2* __restrict__ tw) {
  int s = 0;
  for (int Ns = 1; Ns < 2048; Ns <<= 1, ++s) {
#pragma unroll
    for (int q = 0; q < 4; ++q) {
      int j = tid + q * 256;
      int base = j & (Ns - 1);
      int grp = j >> s;
      float2 t = tw[base << (10 - s)];
      float c = t.x, sn = dir * t.y;
      float ar = sr[j],        ai = si[j];
      float br = sr[j + 1024], bi = si[j + 1024];
      float tbr = br * c - bi * sn;
      float tbi = br * sn + bi * c;
      int o = (grp << (s + 1)) + base;
      dr[o]      = ar + tbr;  di[o]      = ai + tbi;
      dr[o + Ns] = ar - tbr;  di[o + Ns] = ai - tbi;
    }
    __syncthreads();
    float* t0 = sr; sr = dr; dr = t0;
    float* t1 = si; si = di; di = t1;
  }
}

__global__ __launch_bounds__(256) void k_stft(const float* __restrict__ mix,
                                              const float* __restrict__ win,
                                              const float2* __restrict__ tw,
                                              float* __restrict__ spec) {
  __shared__ float b0r[2048], b0i[2048], b1r[2048], b1i[2048];
  int t = blockIdx.x, sig = blockIdx.y, tid = threadIdx.x;
  const float* x = mix + (long)sig * kL;
  for (int i = tid; i < 2048; i += 256) {
    int src = t * kHOP + i - 1024;
    if (src < 0) src = -src;
    if (src >= kL) src = 2 * kL - 2 - src;
    b0r[i] = x[src] * win[i];
    b0i[i] = 0.f;
  }
  __syncthreads();
  float* sr = b0r; float* si = b0i;
  fft2048_lds(sr, si, b1r, b1i, tid, -1.f, tw);
  for (int k = tid; k < kBINS; k += 256) {
    long o = ((long)sig * kBINS + k) * kT + t;
    spec[o * 2]     = sr[k];
    spec[o * 2 + 1] = si[k];
  }
}

__global__ __launch_bounds__(256) void k_istft(const float* __restrict__ spec,
                                               const float* __restrict__ win,
                                               const float2* __restrict__ tw,
                                               float* __restrict__ frames) {
  __shared__ float b0r[2048], b0i[2048], b1r[2048], b1i[2048];
  int t = blockIdx.x, sig = blockIdx.y, tid = threadIdx.x;
  for (int k = tid; k < kBINS; k += 256) {
    long o = ((long)sig * kBINS + k) * kT + t;
    b0r[k] = spec[o * 2];
    b0i[k] = spec[o * 2 + 1];
  }
  __syncthreads();
  for (int k = 1025 + tid; k < 2048; k += 256) {
    b0r[k] = b0r[2048 - k];
    b0i[k] = -b0i[2048 - k];
  }
  __syncthreads();
  float* sr = b0r; float* si = b0i;
  fft2048_lds(sr, si, b1r, b1i, tid, +1.f, tw);
  const float scale = 1.f / 2048.f;
  float* fo = frames + ((long)sig * kT + t) * 2048;
  for (int n = tid; n < 2048; n += 256) fo[n] = sr[n] * scale * win[n];
}

__global__ void k_gather(const float* __restrict__ frames,
                         const float* __restrict__ win,
                         float* __restrict__ out0) {
  long idx = (long)blockIdx.x * 256 + threadIdx.x;
  long total = (long)kNSIG * kL;
  if (idx >= total) return;
  int sig = (int)(idx / kL);
  int l = (int)(idx % kL);
  int j = l + 1024;
  int tmax = j >> 9; if (tmax > kT - 1) tmax = kT - 1;
  int v = j - 1536;
  int tmin = v > 0 ? (v >> 9) : 0;
  float acc = 0.f, w2 = 0.f;
  for (int t = tmin; t <= tmax; ++t) {
    int n = j - (t << 9);
    float w = win[n];
    acc += frames[((long)sig * kT + t) * 2048 + n];
    w2 = fmaf(w, w, w2);
  }
  out0[idx] = acc / (w2 > 1e-11f ? w2 : 1.f);
}

__global__ void k_conv1_pe(const float* __restrict__ spec,
                           const float* __restrict__ c1wr, const float* __restrict__ c1br,
                           const float* __restrict__ c1wi, const float* __restrict__ c1bi,
                           float* __restrict__ xr, float* __restrict__ xi) {
  long idx = (long)blockIdx.x * 256 + threadIdx.x;
  long total = (long)kB * 2 * kBINS * kT;
  if (idx >= total) return;
  int t = (int)(idx % kT);
  long r0 = idx / kT;
  int bin = (int)(r0 % kBINS);
  long r1 = r0 / kBINS;
  int ch = (int)(r1 % 2);
  int b = (int)(r1 / 2);
  float re = spec[idx * 2], im = spec[idx * 2 + 1];
  float wr = c1wr[ch], br = c1br[ch], wi = c1wi[ch], bi = c1bi[ch];
  float nr = (re * wr + br) - (im * wi + bi);
  float ni = (im * wr + br) + (re * wi + bi);
  int d = bin * 2 + ch;
  int k = d >> 1;
  float dv = expf((float)k * (-9.210340371976184f / 1025.0f));
  float arg = (float)t * dv;
  float pe = (d & 1) ? cosf(arg) : sinf(arg);
  long ro = ((long)(b * kT + t)) * kD + d;
  xr[ro] = nr + pe;
  xi[ro] = ni + pe;
}

// fp32 -> bf16 convert with zero-fill outside (srows x scols) into dst
// (dstRows x ldd, full width written).
__global__ void k_cvt2(const float* __restrict__ src, bf16* __restrict__ dst,
                       long total, int ldd, int srows, int scols, int lds) {
  long idx = (long)blockIdx.x * 256 + threadIdx.x;
  if (idx >= total) return;
  int r = (int)(idx / ldd), c = (int)(idx % ldd);
  float v = (r < srows && c < scols) ? src[(long)r * lds + c] : 0.f;
  dst[idx] = __float2bfloat16(v);
}

// ---------------------------------------------------------------------------
// fp32 VALU GEMM (scores): C = A(MxK) * B(NxK)^T.
// ---------------------------------------------------------------------------
__global__ __launch_bounds__(256) void k_gemm(
    const float* __restrict__ A, const float* __restrict__ B,
    float* __restrict__ C, int M, int N, int K, int lda, int ldb, int ldc) {
  __shared__ __align__(16) float As[16][64];
  __shared__ __align__(16) float Bs[16][64];
  int tid = threadIdx.x;
  int tx = tid & 15, ty = tid >> 4;
  int bm = blockIdx.y * 64, bn = blockIdx.x * 64;
  float acc[4][4] = {};
  for (int k0 = 0; k0 < K; k0 += 16) {
    {
      int row = tid >> 2, kq = (tid & 3) * 4;
      int gm = bm + row;
#pragma unroll
      for (int e = 0; e < 4; ++e) {
        int gk = k0 + kq + e;
        As[kq + e][row] = (gm < M && gk < K) ? A[(long)gm * lda + gk] : 0.f;
      }
      int gn = bn + row;
#pragma unroll
      for (int e = 0; e < 4; ++e) {
        int gk = k0 + kq + e;
        Bs[kq + e][row] = (gn < N && gk < K) ? B[(long)gn * ldb + gk] : 0.f;
      }
    }
    __syncthreads();
#pragma unroll
    for (int kk = 0; kk < 16; ++kk) {
      const float4 av = *(const float4*)&As[kk][ty * 4];
      const float4 bv = *(const float4*)&Bs[kk][tx * 4];
      float a4[4] = {av.x, av.y, av.z, av.w};
      float b4[4] = {bv.x, bv.y, bv.z, bv.w};
#pragma unroll
      for (int i = 0; i < 4; ++i)
#pragma unroll
        for (int jj = 0; jj < 4; ++jj)
          acc[i][jj] = fmaf(a4[i], b4[jj], acc[i][jj]);
    }
    __syncthreads();
  }
#pragma unroll
  for (int i = 0; i < 4; ++i) {
    int gm = bm + ty * 4 + i;
    if (gm >= M) continue;
#pragma unroll
    for (int jj = 0; jj < 4; ++jj) {
      int gn = bn + tx * 4 + jj;
      if (gn >= N) continue;
      C[(long)gm * ldc + gn] = acc[i][jj];
    }
  }
}

// ---------------------------------------------------------------------------
// fp32 VALU, 2 A's sharing one B: C1 = A1*B^T + bias, C2 = A2*B^T + bias.
// Used for Q and K projections (argmax-critical, fp32 end-to-end).
// ---------------------------------------------------------------------------
__global__ __launch_bounds__(256) void k_gemm2f(
    const float* __restrict__ A1, const float* __restrict__ A2,
    const float* __restrict__ B, float* __restrict__ C1,
    float* __restrict__ C2, const float* __restrict__ bias,
    int M, int N, int K, int lda, int ldb, int ldc) {
  __shared__ __align__(16) float As1[16][64];
  __shared__ __align__(16) float As2[16][64];
  __shared__ __align__(16) float Bs[16][64];
  int tid = threadIdx.x;
  int tx = tid & 15, ty = tid >> 4;
  int bm = blockIdx.y * 64, bn = blockIdx.x * 64;
  float ac1[4][4] = {}, ac2[4][4] = {};
  for (int k0 = 0; k0 < K; k0 += 16) {
    int row = tid >> 2, kq = (tid & 3) * 4;
    int gm = bm + row;
    int gn = bn + row;
#pragma unroll
    for (int e = 0; e < 4; ++e) {
      int gk = k0 + kq + e;
      bool okm = (gm < M && gk < K);
      As1[kq + e][row] = okm ? A1[(long)gm * lda + gk] : 0.f;
      As2[kq + e][row] = okm ? A2[(long)gm * lda + gk] : 0.f;
      Bs[kq + e][row] = (gn < N && gk < K) ? B[(long)gn * ldb + gk] : 0.f;
    }
    __syncthreads();
#pragma unroll
    for (int kk = 0; kk < 16; ++kk) {
      const float4 a1 = *(const float4*)&As1[kk][ty * 4];
      const float4 a2 = *(const float4*)&As2[kk][ty * 4];
      const float4 bv = *(const float4*)&Bs[kk][tx * 4];
      float v1[4] = {a1.x, a1.y, a1.z, a1.w};
      float v2[4] = {a2.x, a2.y, a2.z, a2.w};
      float b4[4] = {bv.x, bv.y, bv.z, bv.w};
#pragma unroll
      for (int i = 0; i < 4; ++i)
#pragma unroll
        for (int jj = 0; jj < 4; ++jj) {
          ac1[i][jj] = fmaf(v1[i], b4[jj], ac1[i][jj]);
          ac2[i][jj] = fmaf(v2[i], b4[jj], ac2[i][jj]);
        }
    }
    __syncthreads();
  }
#pragma unroll
  for (int i = 0; i < 4; ++i) {
    int gm = bm + ty * 4 + i;
    if (gm >= M) continue;
#pragma unroll
    for (int jj = 0; jj < 4; ++jj) {
      int gn = bn + tx * 4 + jj;
      if (gn >= N) continue;
      float bv = bias[gn];
      long co = (long)gm * ldc + gn;
      C1[co] = ac1[i][jj] + bv;
      C2[co] = ac2[i][jj] + bv;
    }
  }
}

// ---------------------------------------------------------------------------
// MFMA, 2 A's sharing one B (bf16 NxK): C1 = A1*B^T + bs1*bias,
// C2 = A2*B^T + bs2*bias. 128x128 tile, BK=32, 4 waves.
// ---------------------------------------------------------------------------
template <typename TA, typename TC>
__global__ __launch_bounds__(256) void k_mfma2(
    const TA* __restrict__ A1, const TA* __restrict__ A2,
    const bf16* __restrict__ B, TC* __restrict__ C1, TC* __restrict__ C2,
    const float* __restrict__ bias, float bs1, float bs2,
    int M, int N, int K, int lda, int ldb, int ldc) {
  __shared__ __align__(16) bf16 As1[128][40];
  __shared__ __align__(16) bf16 As2[128][40];
  __shared__ __align__(16) bf16 Bs[128][40];
  int tid = threadIdx.x;
  int bm = blockIdx.y * 128, bn = blockIdx.x * 128;
  int lane = tid & 63, w = tid >> 6;
  int wr = (w >> 1) * 64, wc = (w & 1) * 64;
  int fr = lane & 15, fq = lane >> 4;
  f32x4 ac1[4][4] = {}, ac2[4][4] = {};
  int sr = tid >> 1, sk = (tid & 1) * 16;
  for (int k0 = 0; k0 < K; k0 += 32) {
    stage_row16(A1, bm + sr, M, lda, k0 + sk, K, &As1[sr][sk]);
    stage_row16(A2, bm + sr, M, lda, k0 + sk, K, &As2[sr][sk]);
    stage_row16(B,  bn + sr, N, ldb, k0 + sk, K, &Bs[sr][sk]);
    __syncthreads();
    bf16x8 a1[4], a2[4], b[4];
#pragma unroll
    for (int i = 0; i < 4; ++i) {
      a1[i] = *(const bf16x8*)&As1[wr + i * 16 + fr][fq * 8];
      a2[i] = *(const bf16x8*)&As2[wr + i * 16 + fr][fq * 8];
      b[i]  = *(const bf16x8*)&Bs[wc + i * 16 + fr][fq * 8];
    }
#pragma unroll
    for (int i = 0; i < 4; ++i)
#pragma unroll
      for (int j = 0; j < 4; ++j) {
        ac1[i][j] = __builtin_amdgcn_mfma_f32_16x16x32_bf16(a1[i], b[j], ac1[i][j], 0, 0, 0);
        ac2[i][j] = __builtin_amdgcn_mfma_f32_16x16x32_bf16(a2[i], b[j], ac2[i][j], 0, 0, 0);
      }
    __syncthreads();
  }
#pragma unroll
  for (int i = 0; i < 4; ++i)
#pragma unroll
    for (int j = 0; j < 4; ++j) {
      int gn = bn + wc + j * 16 + fr;
      if (gn >= N) continue;
      float bv = bias ? bias[gn] : 0.f;
#pragma unroll
      for (int r = 0; r < 4; ++r) {
        int gm = bm + wr + i * 16 + fq * 4 + r;
        if (gm >= M) continue;
        long co = (long)gm * ldc + gn;
        sto(C1, co, ac1[i][j][r] + bs1 * bv);
        sto(C2, co, ac2[i][j][r] + bs2 * bv);
      }
    }
}

// ---------------------------------------------------------------------------
// Complex-fused MFMA GEMM: Cr = Ar*Br^T - Ai*Bi^T + bs*(br-bi);
//                          Ci = Ai*Br^T + Ar*Bi^T + bs*(br+bi).
// Optional relu and accumulate (into fp32 C). Bias guarded by Nreal.
// ---------------------------------------------------------------------------
template <typename TC>
__global__ __launch_bounds__(256) void k_cgemm(
    const bf16* __restrict__ Ar, const bf16* __restrict__ Ai,
    const bf16* __restrict__ Br, const bf16* __restrict__ Bi,
    TC* __restrict__ Cr, TC* __restrict__ Ci,
    const float* __restrict__ biasR, const float* __restrict__ biasI,
    float bscale, int accum, int relu, int Nreal,
    int M, int N, int K, int lda, int ldb, int ldc) {
  __shared__ __align__(16) bf16 Asr[128][40];
  __shared__ __align__(16) bf16 Asi[128][40];
  __shared__ __align__(16) bf16 Bsr[128][40];
  __shared__ __align__(16) bf16 Bsi[128][40];
  int tid = threadIdx.x;
  int bm = blockIdx.y * 128, bn = blockIdx.x * 128;
  int lane = tid & 63, w = tid >> 6;
  int wr = (w >> 1) * 64, wc = (w & 1) * 64;
  int fr = lane & 15, fq = lane >> 4;
  f32x4 acR[4][4] = {}, acI[4][4] = {};
  int sr = tid >> 1, sk = (tid & 1) * 16;
  const short ks = (short)0x8000;
  const bf16x8 sgn = {ks, ks, ks, ks, ks, ks, ks, ks};
  for (int k0 = 0; k0 < K; k0 += 32) {
    stage_row16(Ar, bm + sr, M, lda, k0 + sk, K, &Asr[sr][sk]);
    stage_row16(Ai, bm + sr, M, lda, k0 + sk, K, &Asi[sr][sk]);
    stage_row16(Br, bn + sr, N, ldb, k0 + sk, K, &Bsr[sr][sk]);
    stage_row16(Bi, bn + sr, N, ldb, k0 + sk, K, &Bsi[sr][sk]);
    __syncthreads();
    bf16x8 ar[4], ai[4], nai[4], br[4], bi[4];
#pragma unroll
    for (int i = 0; i < 4; ++i) {
      ar[i] = *(const bf16x8*)&Asr[wr + i * 16 + fr][fq * 8];
      ai[i] = *(const bf16x8*)&Asi[wr + i * 16 + fr][fq * 8];
      nai[i] = ai[i] ^ sgn;
      br[i] = *(const bf16x8*)&Bsr[wc + i * 16 + fr][fq * 8];
      bi[i] = *(const bf16x8*)&Bsi[wc + i * 16 + fr][fq * 8];
    }
#pragma unroll
    for (int i = 0; i < 4; ++i)
#pragma unroll
      for (int j = 0; j < 4; ++j) {
        acR[i][j] = __builtin_amdgcn_mfma_f32_16x16x32_bf16(ar[i],  br[j], acR[i][j], 0, 0, 0);
        acR[i][j] = __builtin_amdgcn_mfma_f32_16x16x32_bf16(nai[i], bi[j], acR[i][j], 0, 0, 0);
        acI[i][j] = __builtin_amdgcn_mfma_f32_16x16x32_bf16(ai[i],  br[j], acI[i][j], 0, 0, 0);
        acI[i][j] = __builtin_amdgcn_mfma_f32_16x16x32_bf16(ar[i],  bi[j], acI[i][j], 0, 0, 0);
      }
    __syncthreads();
  }
#pragma unroll
  for (int i = 0; i < 4; ++i)
#pragma unroll
    for (int j = 0; j < 4; ++j) {
      int gn = bn + wc + j * 16 + fr;
      if (gn >= N) continue;
      float br_ = 0.f, bi_ = 0.f;
      if (gn < Nreal) { br_ = biasR[gn]; bi_ = biasI[gn]; }
#pragma unroll
      for (int r = 0; r < 4; ++r) {
        int gm = bm + wr + i * 16 + fq * 4 + r;
        if (gm >= M) continue;
        long co = (long)gm * ldc + gn;
        float vR = acR[i][j][r] + bscale * (br_ - bi_);
        float vI = acI[i][j][r] + bscale * (br_ + bi_);
        if (accum) { vR += ldf(Cr, co); vI += ldf(Ci, co); }
        if (relu) { vR = fmaxf(vR, 0.f); vI = fmaxf(vI, 0.f); }
        sto(Cr, co, vR);
        sto(Ci, co, vI);
      }
    }
}

// ---------------------------------------------------------------------------
// Fused PV: Cr = P0@Vr + P2@Vi ; Ci = P0@Vi + P1@Vr. B is KxN. z = batch b.
// ---------------------------------------------------------------------------
__global__ __launch_bounds__(256) void k_pv(
    const bf16* __restrict__ P, const bf16* __restrict__ Vr,
    const bf16* __restrict__ Vi, bf16* __restrict__ Cr,
    bf16* __restrict__ Ci, int M, int N, int K, int ldp, int ldv, int ldc,
    long pz, long vz, long cz) {
  P  += (long)blockIdx.z * pz;
  Vr += (long)blockIdx.z * vz;
  Vi += (long)blockIdx.z * vz;
  Cr += (long)blockIdx.z * cz;
  Ci += (long)blockIdx.z * cz;
  __shared__ __align__(16) bf16 Ps0[128][40];
  __shared__ __align__(16) bf16 Ps1[128][40];
  __shared__ __align__(16) bf16 Ps2[128][40];
  __shared__ __align__(16) bf16 Vsr[128][40];
  __shared__ __align__(16) bf16 Vsi[128][40];
  int tid = threadIdx.x;
  int bm = blockIdx.y * 128, bn = blockIdx.x * 128;
  int lane = tid & 63, w = tid >> 6;
  int wr = (w >> 1) * 64, wc = (w & 1) * 64;
  int fr = lane & 15, fq = lane >> 4;
  f32x4 acR[4][4] = {}, acI[4][4] = {};
  int sr = tid >> 1, sk = (tid & 1) * 16;
  int kk = tid >> 3, nq = (tid & 7) * 16;
  for (int k0 = 0; k0 < K; k0 += 32) {
    stage_row16(P,              bm + sr, M, ldp, k0 + sk, K, &Ps0[sr][sk]);
    stage_row16(P + kS2P,       bm + sr, M, ldp, k0 + sk, K, &Ps1[sr][sk]);
    stage_row16(P + 2 * kS2P,   bm + sr, M, ldp, k0 + sk, K, &Ps2[sr][sk]);
    // V tiles: B[k][n] -> Bs[n][k]
    {
      int gk = k0 + kk;
      bf16 t0[16], t1[16];
      if (gk < K && bn + nq + 16 <= N) {
        load16(Vr + (long)gk * ldv + bn + nq, t0);
        load16(Vi + (long)gk * ldv + bn + nq, t1);
      } else {
#pragma unroll
        for (int e = 0; e < 16; ++e) {
          int gn = bn + nq + e;
          bool ok = (gk < K && gn < N);
          t0[e] = __float2bfloat16(ok ? ldf(Vr, (long)gk * ldv + gn) : 0.f);
          t1[e] = __float2bfloat16(ok ? ldf(Vi, (long)gk * ldv + gn) : 0.f);
        }
      }
#pragma unroll
      for (int e = 0; e < 16; ++e) {
        Vsr[nq + e][kk] = t0[e];
        Vsi[nq + e][kk] = t1[e];
      }
    }
    __syncthreads();
    bf16x8 p0[4], p1[4], p2[4], vr[4], vi[4];
#pragma unroll
    for (int i = 0; i < 4; ++i) {
      p0[i] = *(const bf16x8*)&Ps0[wr + i * 16 + fr][fq * 8];
      p1[i] = *(const bf16x8*)&Ps1[wr + i * 16 + fr][fq * 8];
      p2[i] = *(const bf16x8*)&Ps2[wr + i * 16 + fr][fq * 8];
      vr[i] = *(const bf16x8*)&Vsr[wc + i * 16 + fr][fq * 8];
      vi[i] = *(const bf16x8*)&Vsi[wc + i * 16 + fr][fq * 8];
    }
#pragma unroll
    for (int i = 0; i < 4; ++i)
#pragma unroll
      for (int j = 0; j < 4; ++j) {
        acR[i][j] = __builtin_amdgcn_mfma_f32_16x16x32_bf16(p0[i], vr[j], acR[i][j], 0, 0, 0);
        acR[i][j] = __builtin_amdgcn_mfma_f32_16x16x32_bf16(p2[i], vi[j], acR[i][j], 0, 0, 0);
        acI[i][j] = __builtin_amdgcn_mfma_f32_16x16x32_bf16(p0[i], vi[j], acI[i][j], 0, 0, 0);
        acI[i][j] = __builtin_amdgcn_mfma_f32_16x16x32_bf16(p1[i], vr[j], acI[i][j], 0, 0, 0);
      }
    __syncthreads();
  }
#pragma unroll
  for (int i = 0; i < 4; ++i)
#pragma unroll
    for (int j = 0; j < 4; ++j) {
      int gn = bn + wc + j * 16 + fr;
      if (gn >= N) continue;
#pragma unroll
      for (int r = 0; r < 4; ++r) {
        int gm = bm + wr + i * 16 + fq * 4 + r;
        if (gm >= M) continue;
        long co = (long)gm * ldc + gn;
        Cr[co] = __float2bfloat16(acR[i][j][r]);
        Ci[co] = __float2bfloat16(acI[i][j][r]);
      }
    }
}

// Fused softmax over 4 fp32 score mats + fold to 3 bf16 P mats (stride kS2P).
__global__ __launch_bounds__(256) void k_smf(const float* __restrict__ S,
                                             bf16* __restrict__ P) {
  long rbase = (long)blockIdx.x * kT;
  long pbase = (long)blockIdx.x * kTP;
  int tid = threadIdx.x;
  int lane = tid & 63, w = tid >> 6;
  float v[4][4];
  float mx[4] = {-3.4e38f, -3.4e38f, -3.4e38f, -3.4e38f};
#pragma unroll
  for (int c = 0; c < 4; ++c) {
    const float* row = S + c * kS2 + rbase;
#pragma unroll
    for (int q = 0; q < 4; ++q) {
      int i = tid + q * 256;
      v[c][q] = (i < kT) ? row[i] : -3.4e38f;
      mx[c] = fmaxf(mx[c], v[c][q]);
    }
  }
  __shared__ float redm[4][4];
  for (int o = 32; o > 0; o >>= 1)
#pragma unroll
    for (int c = 0; c < 4; ++c) mx[c] = fmaxf(mx[c], __shfl_down(mx[c], o));
  if (lane == 0)
#pragma unroll
    for (int c = 0; c < 4; ++c) redm[w][c] = mx[c];
  __syncthreads();
#pragma unroll
  for (int c = 0; c < 4; ++c)
    mx[c] = fmaxf(fmaxf(redm[0][c], redm[1][c]), fmaxf(redm[2][c], redm[3][c]));
  __syncthreads();
  float sm[4] = {0.f, 0.f, 0.f, 0.f};
#pragma unroll
  for (int c = 0; c < 4; ++c)
#pragma unroll
    for (int q = 0; q < 4; ++q) {
      int i = tid + q * 256;
      if (i < kT) {
        v[c][q] = expf(kAttnScale * (v[c][q] - mx[c]));
        sm[c] += v[c][q];
      }
    }
  __shared__ float reds[4][4];
  for (int o = 32; o > 0; o >>= 1)
#pragma unroll
    for (int c = 0; c < 4; ++c) sm[c] += __shfl_down(sm[c], o);
  if (lane == 0)
#pragma unroll
    for (int c = 0; c < 4; ++c) reds[w][c] = sm[c];
  __syncthreads();
  float inv[4];
#pragma unroll
  for (int c = 0; c < 4; ++c)
    inv[c] = 1.f / (reds[0][c] + reds[1][c] + reds[2][c] + reds[3][c]);
  bf16* p0 = P + pbase;
  bf16* p1 = P + kS2P + pbase;
  bf16* p2 = P + 2 * kS2P + pbase;
#pragma unroll
  for (int q = 0; q < 4; ++q) {
    int i = tid + q * 256;
    if (i >= kT) continue;
    float a0 = v[0][q] * inv[0], a1 = v[1][q] * inv[1];
    float a2 = v[2][q] * inv[2], a3 = v[3][q] * inv[3];
    p0[i] = __float2bfloat16(a0 - a3);
    p1[i] = __float2bfloat16(a1 + a2);
    p2[i] = __float2bfloat16(a1 - a2);
  }
}

__global__ __launch_bounds__(256) void k_ln(float* __restrict__ X,
                                            const float* __restrict__ g,
                                            const float* __restrict__ b, int d) {
  long row = blockIdx.x;
  float* x = X + row * d;
  int tid = threadIdx.x;
  float s = 0.f, s2 = 0.f;
  for (int i = tid; i < d; i += 256) {
    float v = x[i];
    s += v;
    s2 = fmaf(v, v, s2);
  }
  __shared__ float rs[4], rs2[4];
  for (int o = 32; o > 0; o >>= 1) {
    s += __shfl_down(s, o);
    s2 += __shfl_down(s2, o);
  }
  int lane = tid & 63, w = tid >> 6;
  if (lane == 0) { rs[w] = s; rs2[w] = s2; }
  __syncthreads();
  float st = rs[0] + rs[1] + rs[2] + rs[3];
  float s2t = rs2[0] + rs2[1] + rs2[2] + rs2[3];
  float m = st / d;
  float var = s2t / d - m * m;
  float inv = rsqrtf(var + 1e-5f);
  for (int i = tid; i < d; i += 256) x[i] = (x[i] - m) * inv * g[i] + b[i];
}

__global__ void k_mask(const float* __restrict__ gr_, const float* __restrict__ gi_,
                       const float* __restrict__ c2wr, const float* __restrict__ c2br,
                       const float* __restrict__ c2wi, const float* __restrict__ c2bi,
                       float* __restrict__ spec) {
  long idx = (long)blockIdx.x * 256 + threadIdx.x;
  long total = (long)kB * 2 * kBINS * kT;
  if (idx >= total) return;
  int t = (int)(idx % kT);
  long r0 = idx / kT;
  int bin = (int)(r0 % kBINS);
  long r1 = r0 / kBINS;
  int ch = (int)(r1 % 2);
  int b = (int)(r1 / 2);
  long ro = ((long)(b * kT + t)) * kD + (bin * 2 + ch);
  float gr = gr_[ro], gi = gi_[ro];
  float wr = c2wr[ch], br = c2br[ch], wi = c2wi[ch], bi = c2bi[ch];
  float mr = (gr * wr + br) - (gi * wi + bi);
  float mi = (gi * wr + br) + (gr * wi + bi);
  float re = spec[idx * 2], im = spec[idx * 2 + 1];
  spec[idx * 2]     = re / (1.f + expf(-mr));
  spec[idx * 2 + 1] = im / (1.f + expf(-mi));
}

extern "C" void kernel_launch(void* const* d_in, const int* in_sizes, int n_in,
                              void* d_out, int out_size, void* d_ws, size_t ws_size,
                              hipStream_t stream) {
  const float* mix        = (const float*)d_in[0];
  const float* window     = (const float*)d_in[1];
  const float* c1wr       = (const float*)d_in[2];
  const float* c1br       = (const float*)d_in[3];
  const float* c1wi       = (const float*)d_in[4];
  const float* c1bi       = (const float*)d_in[5];
  const float* c2wr       = (const float*)d_in[6];
  const float* c2br       = (const float*)d_in[7];
  const float* c2wi       = (const float*)d_in[8];
  const float* c2bi       = (const float*)d_in[9];
  const float* attn_in_w  = (const float*)d_in[10];
  const float* attn_in_b  = (const float*)d_in[11];
  const float* attn_out_w = (const float*)d_in[12];
  const float* attn_out_b = (const float*)d_in[13];
  const float* l1wr       = (const float*)d_in[14];
  const float* l1br       = (const float*)d_in[15];
  const float* l1wi       = (const float*)d_in[16];
  const float* l1bi       = (const float*)d_in[17];
  const float* l2wr       = (const float*)d_in[18];
  const float* l2br       = (const float*)d_in[19];
  const float* l2wi       = (const float*)d_in[20];
  const float* l2bi       = (const float*)d_in[21];
  const float* n1_gr      = (const float*)d_in[22];
  const float* n1_br      = (const float*)d_in[23];
  const float* n1_gi      = (const float*)d_in[24];
  const float* n1_bi      = (const float*)d_in[25];
  const float* n2_gr      = (const float*)d_in[26];
  const float* n2_br      = (const float*)d_in[27];
  const float* n2_gi      = (const float*)d_in[28];
  const float* n2_bi      = (const float*)d_in[29];

  // ---- workspace layout: ALL offsets computed (round-9 bug was a
  // hand-computed stride: w1iH off by +288 elems overlapped hidR row 0).
  constexpr long eTok  = (long)kBS * kD;    // 7,068,400 f32
  constexpr long eAout = (long)kBS * kDP;   // 7,089,088 bf16
  constexpr long eQK   = (long)kBS * kHD;   // 3,534,200 f32
  constexpr long eV    = (long)kBS * kHDP;  // 3,558,336 bf16
  constexpr long eW1   = (long)kNH * kDP;   // 8,437,824 bf16
  constexpr long eW2   = (long)kD * kNH;    // 8,413,200 bf16
  constexpr long eHid  = (long)kMC * kHLD;  // 14,150,592 bf16

  constexpr size_t oTok  = 0;
  constexpr size_t oAout = oTok + 2 * eTok * 4;          //  56,547,200
  constexpr size_t oQ    = oAout + 2 * eAout * 2;        //  84,903,552
  constexpr size_t oK    = oQ + 2 * eQK * 4;             // 113,177,152
  constexpr size_t oV    = oK + 2 * eQK * 4;             // 141,450,752
  constexpr size_t oP    = oV + 2 * eV * 2;              // 155,684,096
  constexpr size_t oSS   = oP + 4 * 3 * kS2P * 2;        // 173,558,528
  constexpr size_t oTW   = oSS + 4 * kS2 * 4;            // 185,447,232
  constexpr size_t kNeed = oTW + 8192;                   // 185,455,424
  // FFN overlays (attention transients dead by then):
  constexpr size_t oW1r  = oQ;
  constexpr size_t oW1i  = oW1r + eW1 * 2;               // 101,779,200
  constexpr size_t oHidR = oW1i + eW1 * 2;               // 118,654,848
  constexpr size_t oHidI = oHidR + eHid * 2;             // 146,956,032
  static_assert(oHidI + eHid * 2 <= kNeed, "hid overflow");
  static_assert(oW1i + eW1 * 2 <= oHidR, "w1i/hid overlap");
  constexpr size_t oW2r  = oQ;
  constexpr size_t oW2i  = oW2r + eW2 * 2;               // 101,729,952
  static_assert(oW2i + eW2 * 2 <= oHidR, "w2/hid overlap");

  char* wsb = (char*)d_ws;
  if (ws_size < kNeed) return;  // fail signature: out0 all-zero (2.578125)

  float* xr    = (float*)(wsb + oTok);
  float* xi    = xr + eTok;
  bf16*  aoutR = (bf16*)(wsb + oAout);
  bf16*  aoutI = aoutR + eAout;
  float* Qr = (float*)(wsb + oQ);
  float* Qi = Qr + eQK;
  float* Kr = (float*)(wsb + oK);
  float* Ki = Kr + eQK;
  bf16*  Vr = (bf16*)(wsb + oV);
  bf16*  Vi = Vr + eV;
  bf16*  Pbuf = (bf16*)(wsb + oP);
  float* sS = (float*)(wsb + oSS);
  bf16*  Wvb = (bf16*)(wsb + oP);      // overlay: dead before k_smf writes P
  bf16*  Wob = (bf16*)(wsb + oQ);      // out-proj W (Q dead)
  bf16*  AbR = (bf16*)(wsb + oAout);   // FFN activations (aout dead)
  bf16*  AbI = AbR + eAout;
  bf16*  w1rH = (bf16*)(wsb + oW1r);
  bf16*  w1iH = (bf16*)(wsb + oW1i);
  bf16*  w2rH = (bf16*)(wsb + oW2r);
  bf16*  w2iH = (bf16*)(wsb + oW2i);
  bf16*  hidR = (bf16*)(wsb + oHidR);
  bf16*  hidI = (bf16*)(wsb + oHidI);
  float* frames = (float*)(wsb + oAout);  // post-FFN overlay
  float2* tw = (float2*)(wsb + oTW);

  float* out0 = (float*)d_out;
  float* spec = out0 + (long)kNSIG * kL;

  auto cvt2 = [&](const float* src, bf16* dst, int dstRows, int ldd,
                  int srows, int scols, int lds) {
    long total = (long)dstRows * ldd;
    k_cvt2<<<(int)((total + 255) / 256), 256, 0, stream>>>(src, dst, total,
                                                           ldd, srows, scols,
                                                           lds);
  };

  // 0) zero workspace (pad-poison kill), twiddle table
  hipMemsetAsync(d_ws, 0, kNeed, stream);
  k_twiddle<<<4, 256, 0, stream>>>(tw);

  // 1) STFT -> spec (out1)
  k_stft<<<dim3(kT, kNSIG), 256, 0, stream>>>(mix, window, tw, spec);

  // 2) conv1 + pos-enc -> fp32 tokens
  long nct = (long)kB * 2 * kBINS * kT;
  k_conv1_pe<<<(nct + 255) / 256, 256, 0, stream>>>(spec, c1wr, c1br, c1wi,
                                                    c1bi, xr, xi);

  // 3) attention, per head
  for (int h = 0; h < 2; ++h) {
    const float* Wq = attn_in_w + (long)(h * kHD) * kD;
    const float* Wk = attn_in_w + (long)(kD + h * kHD) * kD;
    const float* Wv = attn_in_w + (long)(2 * kD + h * kHD) * kD;
    const float* bq = attn_in_b + h * kHD;
    const float* bk = attn_in_b + kD + h * kHD;
    const float* bv = attn_in_b + 2 * kD + h * kHD;
    // V projection (MFMA, shared Wv for r/i)
    cvt2(Wv, Wvb, kHD, kDP, kHD, kD, kD);
    k_mfma2<float, bf16><<<dim3(9, 27), 256, 0, stream>>>(
        xr, xi, Wvb, Vr, Vi, bv, 1.f, 1.f, kBS, kHD, kD, kD, kDP, kHDP);
    // Q, K projections (fp32 VALU, shared W for r/i)
    k_gemm2f<<<dim3(17, 54), 256, 0, stream>>>(xr, xi, Wq, Qr, Qi, bq,
                                               kBS, kHD, kD, kD, kD, kHD);
    k_gemm2f<<<dim3(17, 54), 256, 0, stream>>>(xr, xi, Wk, Kr, Ki, bk,
                                               kBS, kHD, kD, kD, kD, kHD);
    // scores + softmax-fold per b
    for (int b = 0; b < kB; ++b) {
      long off = (long)b * kT * kHD;
      const float* qs[4] = {Qr + off, Qr + off, Qi + off, Qi + off};
      const float* ks[4] = {Kr + off, Ki + off, Kr + off, Ki + off};
      for (int c = 0; c < 4; ++c)
        k_gemm<<<dim3(14, 14), 256, 0, stream>>>(qs[c], ks[c], sS + c * kS2,
                                                 kT, kT, kHD, kHD, kHD, kT);
      k_smf<<<kT, 256, 0, stream>>>(sS, Pbuf + (long)b * 3 * kS2P);
    }
    // fused PV, z-batched over b
    k_pv<<<dim3(9, 7, 4), 256, 0, stream>>>(
        Pbuf, Vr, Vi, aoutR + h * kHD, aoutI + h * kHD,
        kT, kHD, kT, kTP, kHDP, kDP,
        3 * kS2P, (long)kT * kHDP, (long)kT * kDP);
  }

  // 4) output projection (MFMA, shared Wo) -> fp32 xr, xi
  cvt2(attn_out_w, Wob, kD, kDP, kD, kD, kD);
  k_mfma2<bf16, float><<<dim3(17, 27), 256, 0, stream>>>(
      aoutR, aoutI, Wob, xr, xi, attn_out_b, 0.f, 2.f,
      kBS, kD, kD, kDP, kDP, kD);

  // 5) LN1
  k_ln<<<kBS, 256, 0, stream>>>(xr, n1_gr, n1_br, kD);
  k_ln<<<kBS, 256, 0, stream>>>(xi, n1_gi, n1_bi, kD);

  // 6) FFN (complex-fused), M-chunked; activations -> bf16 once
  cvt2(xr, AbR, kBS, kDP, kBS, kD, kD);
  cvt2(xi, AbI, kBS, kDP, kBS, kD, kD);
  for (int c = 0; c < 2; ++c) {
    const bf16* ArC = AbR + (long)c * kMC * kDP;
    const bf16* AiC = AbI + (long)c * kMC * kDP;
    // FFN1: hidden = relu(complex(A @ W1^T) + bias), N in halves
    for (int nh = 0; nh < 2; ++nh) {
      int srows = (nh ? kDFF - kNH : kNH);
      cvt2(l1wr + (long)nh * kNH * kD, w1rH, kNH, kDP, srows, kD, kD);
      cvt2(l1wi + (long)nh * kNH * kD, w1iH, kNH, kDP, srows, kD, kD);
      k_cgemm<bf16><<<dim3(33, 14), 256, 0, stream>>>(
          ArC, AiC, w1rH, w1iH, hidR + nh * kNH, hidI + nh * kNH,
          l1br + nh * kNH, l1bi + nh * kNH, 1.f, 0, 1, srows,
          kMC, kNH, kD, kDP, kDP, kHLD);
    }
    // FFN2: out = complex(hidden @ W2^T) + bias, K in halves (accumulate)
    float* xrC = xr + (long)c * kMC * kD;
    float* xiC = xi + (long)c * kMC * kD;
    for (int kh = 0; kh < 2; ++kh) {
      int scols = (kh ? kDFF - kNH : kNH);
      cvt2(l2wr + kh * kNH, w2rH, kD, kNH, kD, scols, kDFF);
      cvt2(l2wi + kh * kNH, w2iH, kD, kNH, kD, scols, kDFF);
      k_cgemm<float><<<dim3(17, 14), 256, 0, stream>>>(
          hidR + kh * kNH, hidI + kh * kNH, w2rH, w2iH, xrC, xiC,
          l2br, l2bi, (kh == 0 ? 1.f : 0.f), kh, 0, kD,
          kMC, kD, kNH, kHLD, kNH, kD);
    }
  }

  // 7) LN2
  k_ln<<<kBS, 256, 0, stream>>>(xr, n2_gr, n2_br, kD);
  k_ln<<<kBS, 256, 0, stream>>>(xi, n2_gi, n2_bi, kD);

  // 8) mask + gate spec in place
  k_mask<<<(nct + 255) / 256, 256, 0, stream>>>(xr, xi, c2wr, c2br, c2wi,
                                                c2bi, spec);

  // 9) iSTFT + overlap-add
  k_istft<<<dim3(kT, kNSIG), 256, 0, stream>>>(spec, window, tw, frames);
  k_gather<<<(int)(((long)kNSIG * kL + 255) / 256), 256, 0, stream>>>(
      frames, window, out0);
}

// Round 11
// 8186.947 us; speedup vs baseline: 2.7623x; 1.6218x over previous
//
#include <hip/hip_runtime.h>
#include <hip/hip_bf16.h>
#include <math.h>

#ifndef M_PIf
#define M_PIf 3.14159265358979323846f
#endif

static constexpr int kNFFT = 2048;
static constexpr int kHOP  = 512;
static constexpr int kBINS = 1025;
static constexpr int kT    = 862;
static constexpr int kL    = 441000;
static constexpr int kB    = 4;
static constexpr int kNSIG = 8;
static constexpr int kD    = 2050;
static constexpr int kHD   = 1025;
static constexpr int kDFF  = 8200;
static constexpr int kBS   = kB * kT;   // 3448
static constexpr float kAttnScale = 0.031234752377721214f; // 1/sqrt(1025)
static constexpr long kS2  = (long)kT * kT;    // 743,044
static constexpr int kTP   = 864;
static constexpr long kS2P = (long)kT * kTP;   // 744,768
static constexpr int kDP   = 2056;   // padded row (bf16, 16B aligned)
static constexpr int kHDP  = 1032;
static constexpr int kMC   = 1724;   // FFN M chunk
static constexpr int kNH   = 4104;   // FFN1 N-half / FFN2 K-half
static constexpr int kHLD  = 8208;   // hidden row stride

using bf16 = __hip_bfloat16;
typedef __attribute__((ext_vector_type(4))) float f32x4;
typedef __attribute__((ext_vector_type(8))) short bf16x8;

__device__ __forceinline__ float ldf(const float* p, long i) { return p[i]; }
__device__ __forceinline__ float ldf(const bf16* p, long i) {
  return __bfloat162float(p[i]);
}
__device__ __forceinline__ void sto(float* p, long i, float v) { p[i] = v; }
__device__ __forceinline__ void sto(bf16* p, long i, float v) {
  p[i] = __float2bfloat16(v);
}
__device__ __forceinline__ void load16(const float* src, bf16* dst) {
#pragma unroll
  for (int e = 0; e < 16; ++e) dst[e] = __float2bfloat16(src[e]);
}
__device__ __forceinline__ void load16(const bf16* src, bf16* dst) {
  *(bf16x8*)(dst)     = *(const bf16x8*)(src);
  *(bf16x8*)(dst + 8) = *(const bf16x8*)(src + 8);
}

// Stage one 16-element bf16 chunk of a row-major matrix into LDS row.
template <typename T>
__device__ __forceinline__ void stage_row16(const T* S, int grow, int glim,
                                            int lda, int k0sk, int K,
                                            bf16* dst) {
  bf16 tmp[16];
  if (grow < glim && k0sk + 16 <= K) {
    load16(S + (long)grow * lda + k0sk, tmp);
  } else {
#pragma unroll
    for (int e = 0; e < 16; ++e) {
      int gk = k0sk + e;
      tmp[e] = __float2bfloat16(
          (grow < glim && gk < K) ? ldf(S, (long)grow * lda + gk) : 0.f);
    }
  }
  *(bf16x8*)(dst)     = *(bf16x8*)&tmp[0];
  *(bf16x8*)(dst + 8) = *(bf16x8*)&tmp[8];
}

// ---------------------------------------------------------------------------
__global__ void k_twiddle(float2* __restrict__ tw) {
  int m = blockIdx.x * 256 + threadIdx.x;
  if (m < 1024) {
    float s, c;
    sincosf(M_PIf * (float)m / 1024.f, &s, &c);
    tw[m] = make_float2(c, s);
  }
}

__device__ __forceinline__ void fft2048_lds(float*& sr, float*& si,
                                            float* dr, float* di, int tid,
                                            float dir,
                                            const float2* __restrict__ tw) {
  int s = 0;
  for (int Ns = 1; Ns < 2048; Ns <<= 1, ++s) {
#pragma unroll
    for (int q = 0; q < 4; ++q) {
      int j = tid + q * 256;
      int base = j & (Ns - 1);
      int grp = j >> s;
      float2 t = tw[base << (10 - s)];
      float c = t.x, sn = dir * t.y;
      float ar = sr[j],        ai = si[j];
      float br = sr[j + 1024], bi = si[j + 1024];
      float tbr = br * c - bi * sn;
      float tbi = br * sn + bi * c;
      int o = (grp << (s + 1)) + base;
      dr[o]      = ar + tbr;  di[o]      = ai + tbi;
      dr[o + Ns] = ar - tbr;  di[o + Ns] = ai - tbi;
    }
    __syncthreads();
    float* t0 = sr; sr = dr; dr = t0;
    float* t1 = si; si = di; di = t1;
  }
}

__global__ __launch_bounds__(256) void k_stft(const float* __restrict__ mix,
                                              const float* __restrict__ win,
                                              const float2* __restrict__ tw,
                                              float* __restrict__ spec) {
  __shared__ float b0r[2048], b0i[2048], b1r[2048], b1i[2048];
  int t = blockIdx.x, sig = blockIdx.y, tid = threadIdx.x;
  const float* x = mix + (long)sig * kL;
  for (int i = tid; i < 2048; i += 256) {
    int src = t * kHOP + i - 1024;
    if (src < 0) src = -src;
    if (src >= kL) src = 2 * kL - 2 - src;
    b0r[i] = x[src] * win[i];
    b0i[i] = 0.f;
  }
  __syncthreads();
  float* sr = b0r; float* si = b0i;
  fft2048_lds(sr, si, b1r, b1i, tid, -1.f, tw);
  for (int k = tid; k < kBINS; k += 256) {
    long o = ((long)sig * kBINS + k) * kT + t;
    spec[o * 2]     = sr[k];
    spec[o * 2 + 1] = si[k];
  }
}

__global__ __launch_bounds__(256) void k_istft(const float* __restrict__ spec,
                                               const float* __restrict__ win,
                                               const float2* __restrict__ tw,
                                               float* __restrict__ frames) {
  __shared__ float b0r[2048], b0i[2048], b1r[2048], b1i[2048];
  int t = blockIdx.x, sig = blockIdx.y, tid = threadIdx.x;
  for (int k = tid; k < kBINS; k += 256) {
    long o = ((long)sig * kBINS + k) * kT + t;
    b0r[k] = spec[o * 2];
    b0i[k] = spec[o * 2 + 1];
  }
  __syncthreads();
  for (int k = 1025 + tid; k < 2048; k += 256) {
    b0r[k] = b0r[2048 - k];
    b0i[k] = -b0i[2048 - k];
  }
  __syncthreads();
  float* sr = b0r; float* si = b0i;
  fft2048_lds(sr, si, b1r, b1i, tid, +1.f, tw);
  const float scale = 1.f / 2048.f;
  float* fo = frames + ((long)sig * kT + t) * 2048;
  for (int n = tid; n < 2048; n += 256) fo[n] = sr[n] * scale * win[n];
}

__global__ void k_gather(const float* __restrict__ frames,
                         const float* __restrict__ win,
                         float* __restrict__ out0) {
  long idx = (long)blockIdx.x * 256 + threadIdx.x;
  long total = (long)kNSIG * kL;
  if (idx >= total) return;
  int sig = (int)(idx / kL);
  int l = (int)(idx % kL);
  int j = l + 1024;
  int tmax = j >> 9; if (tmax > kT - 1) tmax = kT - 1;
  int v = j - 1536;
  int tmin = v > 0 ? (v >> 9) : 0;
  float acc = 0.f, w2 = 0.f;
  for (int t = tmin; t <= tmax; ++t) {
    int n = j - (t << 9);
    float w = win[n];
    acc += frames[((long)sig * kT + t) * 2048 + n];
    w2 = fmaf(w, w, w2);
  }
  out0[idx] = acc / (w2 > 1e-11f ? w2 : 1.f);
}

// conv1x1 + pos-enc -> tokens written DIRECTLY as bf16 hi/lo split pairs.
__global__ void k_conv1_pe(const float* __restrict__ spec,
                           const float* __restrict__ c1wr, const float* __restrict__ c1br,
                           const float* __restrict__ c1wi, const float* __restrict__ c1bi,
                           bf16* __restrict__ xrh, bf16* __restrict__ xrl,
                           bf16* __restrict__ xih, bf16* __restrict__ xil) {
  long idx = (long)blockIdx.x * 256 + threadIdx.x;
  long total = (long)kB * 2 * kBINS * kT;
  if (idx >= total) return;
  int t = (int)(idx % kT);
  long r0 = idx / kT;
  int bin = (int)(r0 % kBINS);
  long r1 = r0 / kBINS;
  int ch = (int)(r1 % 2);
  int b = (int)(r1 / 2);
  float re = spec[idx * 2], im = spec[idx * 2 + 1];
  float wr = c1wr[ch], br = c1br[ch], wi = c1wi[ch], bi = c1bi[ch];
  float nr = (re * wr + br) - (im * wi + bi);
  float ni = (im * wr + br) + (re * wi + bi);
  int d = bin * 2 + ch;
  int k = d >> 1;
  float dv = expf((float)k * (-9.210340371976184f / 1025.0f));
  float arg = (float)t * dv;
  float pe = (d & 1) ? cosf(arg) : sinf(arg);
  long ro = ((long)(b * kT + t)) * kDP + d;
  float vr = nr + pe, vi = ni + pe;
  bf16 hr = __float2bfloat16(vr);
  bf16 hi = __float2bfloat16(vi);
  xrh[ro] = hr; xrl[ro] = __float2bfloat16(vr - __bfloat162float(hr));
  xih[ro] = hi; xil[ro] = __float2bfloat16(vi - __bfloat162float(hi));
}

// fp32 -> bf16 convert, zero-fill outside (srows x scols).
__global__ void k_cvt2(const float* __restrict__ src, bf16* __restrict__ dst,
                       long total, int ldd, int srows, int scols, int lds) {
  long idx = (long)blockIdx.x * 256 + threadIdx.x;
  if (idx >= total) return;
  int r = (int)(idx / ldd), c = (int)(idx % ldd);
  float v = (r < srows && c < scols) ? src[(long)r * lds + c] : 0.f;
  dst[idx] = __float2bfloat16(v);
}

// fp32 -> split bf16 (hi + lo), zero-fill outside.
__global__ void k_cvt2s(const float* __restrict__ src, bf16* __restrict__ dh,
                        bf16* __restrict__ dl, long total, int ldd, int srows,
                        int scols, int lds) {
  long idx = (long)blockIdx.x * 256 + threadIdx.x;
  if (idx >= total) return;
  int r = (int)(idx / ldd), c = (int)(idx % ldd);
  float v = (r < srows && c < scols) ? src[(long)r * lds + c] : 0.f;
  bf16 h = __float2bfloat16(v);
  dh[idx] = h;
  dl[idx] = __float2bfloat16(v - __bfloat162float(h));
}

// ---------------------------------------------------------------------------
// MFMA, 2 A's sharing one B (bf16 NxK): C1 = A1*B^T + bs1*bias,
// C2 = A2*B^T + bs2*bias. 128x128 tile, BK=32, 4 waves.
// ---------------------------------------------------------------------------
template <typename TA, typename TC>
__global__ __launch_bounds__(256) void k_mfma2(
    const TA* __restrict__ A1, const TA* __restrict__ A2,
    const bf16* __restrict__ B, TC* __restrict__ C1, TC* __restrict__ C2,
    const float* __restrict__ bias, float bs1, float bs2,
    int M, int N, int K, int lda, int ldb, int ldc) {
  __shared__ __align__(16) bf16 As1[128][40];
  __shared__ __align__(16) bf16 As2[128][40];
  __shared__ __align__(16) bf16 Bs[128][40];
  int tid = threadIdx.x;
  int bm = blockIdx.y * 128, bn = blockIdx.x * 128;
  int lane = tid & 63, w = tid >> 6;
  int wr = (w >> 1) * 64, wc = (w & 1) * 64;
  int fr = lane & 15, fq = lane >> 4;
  f32x4 ac1[4][4] = {}, ac2[4][4] = {};
  int sr = tid >> 1, sk = (tid & 1) * 16;
  for (int k0 = 0; k0 < K; k0 += 32) {
    stage_row16(A1, bm + sr, M, lda, k0 + sk, K, &As1[sr][sk]);
    stage_row16(A2, bm + sr, M, lda, k0 + sk, K, &As2[sr][sk]);
    stage_row16(B,  bn + sr, N, ldb, k0 + sk, K, &Bs[sr][sk]);
    __syncthreads();
    bf16x8 a1[4], a2[4], b[4];
#pragma unroll
    for (int i = 0; i < 4; ++i) {
      a1[i] = *(const bf16x8*)&As1[wr + i * 16 + fr][fq * 8];
      a2[i] = *(const bf16x8*)&As2[wr + i * 16 + fr][fq * 8];
      b[i]  = *(const bf16x8*)&Bs[wc + i * 16 + fr][fq * 8];
    }
#pragma unroll
    for (int i = 0; i < 4; ++i)
#pragma unroll
      for (int j = 0; j < 4; ++j) {
        ac1[i][j] = __builtin_amdgcn_mfma_f32_16x16x32_bf16(a1[i], b[j], ac1[i][j], 0, 0, 0);
        ac2[i][j] = __builtin_amdgcn_mfma_f32_16x16x32_bf16(a2[i], b[j], ac2[i][j], 0, 0, 0);
      }
    __syncthreads();
  }
#pragma unroll
  for (int i = 0; i < 4; ++i)
#pragma unroll
    for (int j = 0; j < 4; ++j) {
      int gn = bn + wc + j * 16 + fr;
      if (gn >= N) continue;
      float bv = bias ? bias[gn] : 0.f;
#pragma unroll
      for (int r = 0; r < 4; ++r) {
        int gm = bm + wr + i * 16 + fq * 4 + r;
        if (gm >= M) continue;
        long co = (long)gm * ldc + gn;
        sto(C1, co, ac1[i][j][r] + bs1 * bv);
        sto(C2, co, ac2[i][j][r] + bs2 * bv);
      }
    }
}

// ---------------------------------------------------------------------------
// Split-precision projection: Or = (Arh+Arl)@(Bh+Bl)^T + bias (3 products,
// drops l@l), Oi likewise. Outputs re-split into hi/lo bf16 pairs.
// Used for Q/K projections: ~2^-16 operand precision on the argmax path.
// ---------------------------------------------------------------------------
__global__ __launch_bounds__(256) void k_mfma2s(
    const bf16* __restrict__ Arh, const bf16* __restrict__ Arl,
    const bf16* __restrict__ Aih, const bf16* __restrict__ Ail,
    const bf16* __restrict__ Bh, const bf16* __restrict__ Bl,
    bf16* __restrict__ Crh, bf16* __restrict__ Crl,
    bf16* __restrict__ Cih, bf16* __restrict__ Cil,
    const float* __restrict__ bias,
    int M, int N, int K, int lda, int ldb, int ldc) {
  __shared__ __align__(16) bf16 Sarh[128][40];
  __shared__ __align__(16) bf16 Sarl[128][40];
  __shared__ __align__(16) bf16 Saih[128][40];
  __shared__ __align__(16) bf16 Sail[128][40];
  __shared__ __align__(16) bf16 Sbh[128][40];
  __shared__ __align__(16) bf16 Sbl[128][40];
  int tid = threadIdx.x;
  int bm = blockIdx.y * 128, bn = blockIdx.x * 128;
  int lane = tid & 63, w = tid >> 6;
  int wr = (w >> 1) * 64, wc = (w & 1) * 64;
  int fr = lane & 15, fq = lane >> 4;
  f32x4 acR[4][4] = {}, acI[4][4] = {};
  int sr = tid >> 1, sk = (tid & 1) * 16;
  for (int k0 = 0; k0 < K; k0 += 32) {
    stage_row16(Arh, bm + sr, M, lda, k0 + sk, K, &Sarh[sr][sk]);
    stage_row16(Arl, bm + sr, M, lda, k0 + sk, K, &Sarl[sr][sk]);
    stage_row16(Aih, bm + sr, M, lda, k0 + sk, K, &Saih[sr][sk]);
    stage_row16(Ail, bm + sr, M, lda, k0 + sk, K, &Sail[sr][sk]);
    stage_row16(Bh,  bn + sr, N, ldb, k0 + sk, K, &Sbh[sr][sk]);
    stage_row16(Bl,  bn + sr, N, ldb, k0 + sk, K, &Sbl[sr][sk]);
    __syncthreads();
    bf16x8 bh[4], bl[4];
#pragma unroll
    for (int j = 0; j < 4; ++j) {
      bh[j] = *(const bf16x8*)&Sbh[wc + j * 16 + fr][fq * 8];
      bl[j] = *(const bf16x8*)&Sbl[wc + j * 16 + fr][fq * 8];
    }
#pragma unroll
    for (int i = 0; i < 4; ++i) {
      bf16x8 arh = *(const bf16x8*)&Sarh[wr + i * 16 + fr][fq * 8];
      bf16x8 arl = *(const bf16x8*)&Sarl[wr + i * 16 + fr][fq * 8];
      bf16x8 aih = *(const bf16x8*)&Saih[wr + i * 16 + fr][fq * 8];
      bf16x8 ail = *(const bf16x8*)&Sail[wr + i * 16 + fr][fq * 8];
#pragma unroll
      for (int j = 0; j < 4; ++j) {
        acR[i][j] = __builtin_amdgcn_mfma_f32_16x16x32_bf16(arh, bh[j], acR[i][j], 0, 0, 0);
        acR[i][j] = __builtin_amdgcn_mfma_f32_16x16x32_bf16(arh, bl[j], acR[i][j], 0, 0, 0);
        acR[i][j] = __builtin_amdgcn_mfma_f32_16x16x32_bf16(arl, bh[j], acR[i][j], 0, 0, 0);
        acI[i][j] = __builtin_amdgcn_mfma_f32_16x16x32_bf16(aih, bh[j], acI[i][j], 0, 0, 0);
        acI[i][j] = __builtin_amdgcn_mfma_f32_16x16x32_bf16(aih, bl[j], acI[i][j], 0, 0, 0);
        acI[i][j] = __builtin_amdgcn_mfma_f32_16x16x32_bf16(ail, bh[j], acI[i][j], 0, 0, 0);
      }
    }
    __syncthreads();
  }
#pragma unroll
  for (int i = 0; i < 4; ++i)
#pragma unroll
    for (int j = 0; j < 4; ++j) {
      int gn = bn + wc + j * 16 + fr;
      if (gn >= N) continue;
      float bv = bias[gn];
#pragma unroll
      for (int r = 0; r < 4; ++r) {
        int gm = bm + wr + i * 16 + fq * 4 + r;
        if (gm >= M) continue;
        long co = (long)gm * ldc + gn;
        float vR = acR[i][j][r] + bv;
        float vI = acI[i][j][r] + bv;
        bf16 hR = __float2bfloat16(vR);
        bf16 hI = __float2bfloat16(vI);
        Crh[co] = hR; Crl[co] = __float2bfloat16(vR - __bfloat162float(hR));
        Cih[co] = hI; Cil[co] = __float2bfloat16(vI - __bfloat162float(hI));
      }
    }
}

// ---------------------------------------------------------------------------
// Split-precision QK^T scores. z = bLocal*2 + qsel (2 batches per launch).
// For the selected Q (split), computes S(q,Kr) and S(q,Ki) fp32 (3 products).
// ---------------------------------------------------------------------------
__global__ __launch_bounds__(256) void k_qkt(
    const bf16* __restrict__ Qrh, const bf16* __restrict__ Qrl,
    const bf16* __restrict__ Qih, const bf16* __restrict__ Qil,
    const bf16* __restrict__ Krh, const bf16* __restrict__ Krl,
    const bf16* __restrict__ Kih, const bf16* __restrict__ Kil,
    float* __restrict__ S, int bp) {
  int bl = blockIdx.z >> 1, qsel = blockIdx.z & 1;
  long roff = (long)(bp * 2 + bl) * kT * kHDP;
  const bf16* qh = (qsel ? Qih : Qrh) + roff;
  const bf16* ql = (qsel ? Qil : Qrl) + roff;
  const bf16* krh = Krh + roff;
  const bf16* krl = Krl + roff;
  const bf16* kih = Kih + roff;
  const bf16* kil = Kil + roff;
  float* S0 = S + ((long)bl * 4 + qsel * 2) * kS2;
  float* S1 = S0 + kS2;
  __shared__ __align__(16) bf16 Sqh[128][40];
  __shared__ __align__(16) bf16 Sql[128][40];
  __shared__ __align__(16) bf16 Skrh[128][40];
  __shared__ __align__(16) bf16 Skrl[128][40];
  __shared__ __align__(16) bf16 Skih[128][40];
  __shared__ __align__(16) bf16 Skil[128][40];
  int tid = threadIdx.x;
  int bm = blockIdx.y * 128, bn = blockIdx.x * 128;
  int lane = tid & 63, w = tid >> 6;
  int wr = (w >> 1) * 64, wc = (w & 1) * 64;
  int fr = lane & 15, fq = lane >> 4;
  f32x4 ac0[4][4] = {}, ac1[4][4] = {};
  int sr = tid >> 1, sk = (tid & 1) * 16;
  for (int k0 = 0; k0 < kHD; k0 += 32) {
    stage_row16(qh,  bm + sr, kT, kHDP, k0 + sk, kHD, &Sqh[sr][sk]);
    stage_row16(ql,  bm + sr, kT, kHDP, k0 + sk, kHD, &Sql[sr][sk]);
    stage_row16(krh, bn + sr, kT, kHDP, k0 + sk, kHD, &Skrh[sr][sk]);
    stage_row16(krl, bn + sr, kT, kHDP, k0 + sk, kHD, &Skrl[sr][sk]);
    stage_row16(kih, bn + sr, kT, kHDP, k0 + sk, kHD, &Skih[sr][sk]);
    stage_row16(kil, bn + sr, kT, kHDP, k0 + sk, kHD, &Skil[sr][sk]);
    __syncthreads();
    bf16x8 q_h[4], q_l[4];
#pragma unroll
    for (int i = 0; i < 4; ++i) {
      q_h[i] = *(const bf16x8*)&Sqh[wr + i * 16 + fr][fq * 8];
      q_l[i] = *(const bf16x8*)&Sql[wr + i * 16 + fr][fq * 8];
    }
#pragma unroll
    for (int j = 0; j < 4; ++j) {
      bf16x8 k_rh = *(const bf16x8*)&Skrh[wc + j * 16 + fr][fq * 8];
      bf16x8 k_rl = *(const bf16x8*)&Skrl[wc + j * 16 + fr][fq * 8];
      bf16x8 k_ih = *(const bf16x8*)&Skih[wc + j * 16 + fr][fq * 8];
      bf16x8 k_il = *(const bf16x8*)&Skil[wc + j * 16 + fr][fq * 8];
#pragma unroll
      for (int i = 0; i < 4; ++i) {
        ac0[i][j] = __builtin_amdgcn_mfma_f32_16x16x32_bf16(q_h[i], k_rh, ac0[i][j], 0, 0, 0);
        ac0[i][j] = __builtin_amdgcn_mfma_f32_16x16x32_bf16(q_h[i], k_rl, ac0[i][j], 0, 0, 0);
        ac0[i][j] = __builtin_amdgcn_mfma_f32_16x16x32_bf16(q_l[i], k_rh, ac0[i][j], 0, 0, 0);
        ac1[i][j] = __builtin_amdgcn_mfma_f32_16x16x32_bf16(q_h[i], k_ih, ac1[i][j], 0, 0, 0);
        ac1[i][j] = __builtin_amdgcn_mfma_f32_16x16x32_bf16(q_h[i], k_il, ac1[i][j], 0, 0, 0);
        ac1[i][j] = __builtin_amdgcn_mfma_f32_16x16x32_bf16(q_l[i], k_ih, ac1[i][j], 0, 0, 0);
      }
    }
    __syncthreads();
  }
#pragma unroll
  for (int i = 0; i < 4; ++i)
#pragma unroll
    for (int j = 0; j < 4; ++j) {
      int gn = bn + wc + j * 16 + fr;
      if (gn >= kT) continue;
#pragma unroll
      for (int r = 0; r < 4; ++r) {
        int gm = bm + wr + i * 16 + fq * 4 + r;
        if (gm >= kT) continue;
        long co = (long)gm * kT + gn;
        S0[co] = ac0[i][j][r];
        S1[co] = ac1[i][j][r];
      }
    }
}

// ---------------------------------------------------------------------------
// Complex-fused MFMA GEMM (FFN): Cr = Ar*Br^T - Ai*Bi^T + bs*(br-bi);
//                                Ci = Ai*Br^T + Ar*Bi^T + bs*(br+bi).
// ---------------------------------------------------------------------------
template <typename TC>
__global__ __launch_bounds__(256) void k_cgemm(
    const bf16* __restrict__ Ar, const bf16* __restrict__ Ai,
    const bf16* __restrict__ Br, const bf16* __restrict__ Bi,
    TC* __restrict__ Cr, TC* __restrict__ Ci,
    const float* __restrict__ biasR, const float* __restrict__ biasI,
    float bscale, int accum, int relu, int Nreal,
    int M, int N, int K, int lda, int ldb, int ldc) {
  __shared__ __align__(16) bf16 Asr[128][40];
  __shared__ __align__(16) bf16 Asi[128][40];
  __shared__ __align__(16) bf16 Bsr[128][40];
  __shared__ __align__(16) bf16 Bsi[128][40];
  int tid = threadIdx.x;
  int bm = blockIdx.y * 128, bn = blockIdx.x * 128;
  int lane = tid & 63, w = tid >> 6;
  int wr = (w >> 1) * 64, wc = (w & 1) * 64;
  int fr = lane & 15, fq = lane >> 4;
  f32x4 acR[4][4] = {}, acI[4][4] = {};
  int sr = tid >> 1, sk = (tid & 1) * 16;
  const short ks = (short)0x8000;
  const bf16x8 sgn = {ks, ks, ks, ks, ks, ks, ks, ks};
  for (int k0 = 0; k0 < K; k0 += 32) {
    stage_row16(Ar, bm + sr, M, lda, k0 + sk, K, &Asr[sr][sk]);
    stage_row16(Ai, bm + sr, M, lda, k0 + sk, K, &Asi[sr][sk]);
    stage_row16(Br, bn + sr, N, ldb, k0 + sk, K, &Bsr[sr][sk]);
    stage_row16(Bi, bn + sr, N, ldb, k0 + sk, K, &Bsi[sr][sk]);
    __syncthreads();
    bf16x8 ar[4], ai[4], nai[4], br[4], bi[4];
#pragma unroll
    for (int i = 0; i < 4; ++i) {
      ar[i] = *(const bf16x8*)&Asr[wr + i * 16 + fr][fq * 8];
      ai[i] = *(const bf16x8*)&Asi[wr + i * 16 + fr][fq * 8];
      nai[i] = ai[i] ^ sgn;
      br[i] = *(const bf16x8*)&Bsr[wc + i * 16 + fr][fq * 8];
      bi[i] = *(const bf16x8*)&Bsi[wc + i * 16 + fr][fq * 8];
    }
#pragma unroll
    for (int i = 0; i < 4; ++i)
#pragma unroll
      for (int j = 0; j < 4; ++j) {
        acR[i][j] = __builtin_amdgcn_mfma_f32_16x16x32_bf16(ar[i],  br[j], acR[i][j], 0, 0, 0);
        acR[i][j] = __builtin_amdgcn_mfma_f32_16x16x32_bf16(nai[i], bi[j], acR[i][j], 0, 0, 0);
        acI[i][j] = __builtin_amdgcn_mfma_f32_16x16x32_bf16(ai[i],  br[j], acI[i][j], 0, 0, 0);
        acI[i][j] = __builtin_amdgcn_mfma_f32_16x16x32_bf16(ar[i],  bi[j], acI[i][j], 0, 0, 0);
      }
    __syncthreads();
  }
#pragma unroll
  for (int i = 0; i < 4; ++i)
#pragma unroll
    for (int j = 0; j < 4; ++j) {
      int gn = bn + wc + j * 16 + fr;
      if (gn >= N) continue;
      float br_ = 0.f, bi_ = 0.f;
      if (gn < Nreal) { br_ = biasR[gn]; bi_ = biasI[gn]; }
#pragma unroll
      for (int r = 0; r < 4; ++r) {
        int gm = bm + wr + i * 16 + fq * 4 + r;
        if (gm >= M) continue;
        long co = (long)gm * ldc + gn;
        float vR = acR[i][j][r] + bscale * (br_ - bi_);
        float vI = acI[i][j][r] + bscale * (br_ + bi_);
        if (accum) { vR += ldf(Cr, co); vI += ldf(Ci, co); }
        if (relu) { vR = fmaxf(vR, 0.f); vI = fmaxf(vI, 0.f); }
        sto(Cr, co, vR);
        sto(Ci, co, vI);
      }
    }
}

// ---------------------------------------------------------------------------
// Fused PV: Cr = P0@Vr + P2@Vi ; Ci = P0@Vi + P1@Vr. B is KxN (single batch).
// ---------------------------------------------------------------------------
__global__ __launch_bounds__(256) void k_pv(
    const bf16* __restrict__ P, const bf16* __restrict__ Vr,
    const bf16* __restrict__ Vi, bf16* __restrict__ Cr,
    bf16* __restrict__ Ci, int M, int N, int K, int ldp, int ldv, int ldc) {
  __shared__ __align__(16) bf16 Ps0[128][40];
  __shared__ __align__(16) bf16 Ps1[128][40];
  __shared__ __align__(16) bf16 Ps2[128][40];
  __shared__ __align__(16) bf16 Vsr[128][40];
  __shared__ __align__(16) bf16 Vsi[128][40];
  int tid = threadIdx.x;
  int bm = blockIdx.y * 128, bn = blockIdx.x * 128;
  int lane = tid & 63, w = tid >> 6;
  int wr = (w >> 1) * 64, wc = (w & 1) * 64;
  int fr = lane & 15, fq = lane >> 4;
  f32x4 acR[4][4] = {}, acI[4][4] = {};
  int sr = tid >> 1, sk = (tid & 1) * 16;
  int kk = tid >> 3, nq = (tid & 7) * 16;
  for (int k0 = 0; k0 < K; k0 += 32) {
    stage_row16(P,            bm + sr, M, ldp, k0 + sk, K, &Ps0[sr][sk]);
    stage_row16(P + kS2P,     bm + sr, M, ldp, k0 + sk, K, &Ps1[sr][sk]);
    stage_row16(P + 2 * kS2P, bm + sr, M, ldp, k0 + sk, K, &Ps2[sr][sk]);
    {
      int gk = k0 + kk;
      bf16 t0[16], t1[16];
      if (gk < K && bn + nq + 16 <= N) {
        load16(Vr + (long)gk * ldv + bn + nq, t0);
        load16(Vi + (long)gk * ldv + bn + nq, t1);
      } else {
#pragma unroll
        for (int e = 0; e < 16; ++e) {
          int gn = bn + nq + e;
          bool ok = (gk < K && gn < N);
          t0[e] = __float2bfloat16(ok ? ldf(Vr, (long)gk * ldv + gn) : 0.f);
          t1[e] = __float2bfloat16(ok ? ldf(Vi, (long)gk * ldv + gn) : 0.f);
        }
      }
#pragma unroll
      for (int e = 0; e < 16; ++e) {
        Vsr[nq + e][kk] = t0[e];
        Vsi[nq + e][kk] = t1[e];
      }
    }
    __syncthreads();
    bf16x8 p0[4], p1[4], p2[4], vr[4], vi[4];
#pragma unroll
    for (int i = 0; i < 4; ++i) {
      p0[i] = *(const bf16x8*)&Ps0[wr + i * 16 + fr][fq * 8];
      p1[i] = *(const bf16x8*)&Ps1[wr + i * 16 + fr][fq * 8];
      p2[i] = *(const bf16x8*)&Ps2[wr + i * 16 + fr][fq * 8];
      vr[i] = *(const bf16x8*)&Vsr[wc + i * 16 + fr][fq * 8];
      vi[i] = *(const bf16x8*)&Vsi[wc + i * 16 + fr][fq * 8];
    }
#pragma unroll
    for (int i = 0; i < 4; ++i)
#pragma unroll
      for (int j = 0; j < 4; ++j) {
        acR[i][j] = __builtin_amdgcn_mfma_f32_16x16x32_bf16(p0[i], vr[j], acR[i][j], 0, 0, 0);
        acR[i][j] = __builtin_amdgcn_mfma_f32_16x16x32_bf16(p2[i], vi[j], acR[i][j], 0, 0, 0);
        acI[i][j] = __builtin_amdgcn_mfma_f32_16x16x32_bf16(p0[i], vi[j], acI[i][j], 0, 0, 0);
        acI[i][j] = __builtin_amdgcn_mfma_f32_16x16x32_bf16(p1[i], vr[j], acI[i][j], 0, 0, 0);
      }
    __syncthreads();
  }
#pragma unroll
  for (int i = 0; i < 4; ++i)
#pragma unroll
    for (int j = 0; j < 4; ++j) {
      int gn = bn + wc + j * 16 + fr;
      if (gn >= N) continue;
#pragma unroll
      for (int r = 0; r < 4; ++r) {
        int gm = bm + wr + i * 16 + fq * 4 + r;
        if (gm >= M) continue;
        long co = (long)gm * ldc + gn;
        Cr[co] = __float2bfloat16(acR[i][j][r]);
        Ci[co] = __float2bfloat16(acI[i][j][r]);
      }
    }
}

// Fused softmax over 4 fp32 score mats + fold to 3 bf16 P mats (stride kS2P).
__global__ __launch_bounds__(256) void k_smf(const float* __restrict__ S,
                                             bf16* __restrict__ P) {
  long rbase = (long)blockIdx.x * kT;
  long pbase = (long)blockIdx.x * kTP;
  int tid = threadIdx.x;
  int lane = tid & 63, w = tid >> 6;
  float v[4][4];
  float mx[4] = {-3.4e38f, -3.4e38f, -3.4e38f, -3.4e38f};
#pragma unroll
  for (int c = 0; c < 4; ++c) {
    const float* row = S + c * kS2 + rbase;
#pragma unroll
    for (int q = 0; q < 4; ++q) {
      int i = tid + q * 256;
      v[c][q] = (i < kT) ? row[i] : -3.4e38f;
      mx[c] = fmaxf(mx[c], v[c][q]);
    }
  }
  __shared__ float redm[4][4];
  for (int o = 32; o > 0; o >>= 1)
#pragma unroll
    for (int c = 0; c < 4; ++c) mx[c] = fmaxf(mx[c], __shfl_down(mx[c], o));
  if (lane == 0)
#pragma unroll
    for (int c = 0; c < 4; ++c) redm[w][c] = mx[c];
  __syncthreads();
#pragma unroll
  for (int c = 0; c < 4; ++c)
    mx[c] = fmaxf(fmaxf(redm[0][c], redm[1][c]), fmaxf(redm[2][c], redm[3][c]));
  __syncthreads();
  float sm[4] = {0.f, 0.f, 0.f, 0.f};
#pragma unroll
  for (int c = 0; c < 4; ++c)
#pragma unroll
    for (int q = 0; q < 4; ++q) {
      int i = tid + q * 256;
      if (i < kT) {
        v[c][q] = expf(kAttnScale * (v[c][q] - mx[c]));
        sm[c] += v[c][q];
      }
    }
  __shared__ float reds[4][4];
  for (int o = 32; o > 0; o >>= 1)
#pragma unroll
    for (int c = 0; c < 4; ++c) sm[c] += __shfl_down(sm[c], o);
  if (lane == 0)
#pragma unroll
    for (int c = 0; c < 4; ++c) reds[w][c] = sm[c];
  __syncthreads();
  float inv[4];
#pragma unroll
  for (int c = 0; c < 4; ++c)
    inv[c] = 1.f / (reds[0][c] + reds[1][c] + reds[2][c] + reds[3][c]);
  bf16* p0 = P + pbase;
  bf16* p1 = P + kS2P + pbase;
  bf16* p2 = P + 2 * kS2P + pbase;
#pragma unroll
  for (int q = 0; q < 4; ++q) {
    int i = tid + q * 256;
    if (i >= kT) continue;
    float a0 = v[0][q] * inv[0], a1 = v[1][q] * inv[1];
    float a2 = v[2][q] * inv[2], a3 = v[3][q] * inv[3];
    p0[i] = __float2bfloat16(a0 - a3);
    p1[i] = __float2bfloat16(a1 + a2);
    p2[i] = __float2bfloat16(a1 - a2);
  }
}

__global__ __launch_bounds__(256) void k_ln(float* __restrict__ X,
                                            const float* __restrict__ g,
                                            const float* __restrict__ b, int d) {
  long row = blockIdx.x;
  float* x = X + row * d;
  int tid = threadIdx.x;
  float s = 0.f, s2 = 0.f;
  for (int i = tid; i < d; i += 256) {
    float v = x[i];
    s += v;
    s2 = fmaf(v, v, s2);
  }
  __shared__ float rs[4], rs2[4];
  for (int o = 32; o > 0; o >>= 1) {
    s += __shfl_down(s, o);
    s2 += __shfl_down(s2, o);
  }
  int lane = tid & 63, w = tid >> 6;
  if (lane == 0) { rs[w] = s; rs2[w] = s2; }
  __syncthreads();
  float st = rs[0] + rs[1] + rs[2] + rs[3];
  float s2t = rs2[0] + rs2[1] + rs2[2] + rs2[3];
  float m = st / d;
  float var = s2t / d - m * m;
  float inv = rsqrtf(var + 1e-5f);
  for (int i = tid; i < d; i += 256) x[i] = (x[i] - m) * inv * g[i] + b[i];
}

__global__ void k_mask(const float* __restrict__ gr_, const float* __restrict__ gi_,
                       const float* __restrict__ c2wr, const float* __restrict__ c2br,
                       const float* __restrict__ c2wi, const float* __restrict__ c2bi,
                       float* __restrict__ spec) {
  long idx = (long)blockIdx.x * 256 + threadIdx.x;
  long total = (long)kB * 2 * kBINS * kT;
  if (idx >= total) return;
  int t = (int)(idx % kT);
  long r0 = idx / kT;
  int bin = (int)(r0 % kBINS);
  long r1 = r0 / kBINS;
  int ch = (int)(r1 % 2);
  int b = (int)(r1 / 2);
  long ro = ((long)(b * kT + t)) * kD + (bin * 2 + ch);
  float gr = gr_[ro], gi = gi_[ro];
  float wr = c2wr[ch], br = c2br[ch], wi = c2wi[ch], bi = c2bi[ch];
  float mr = (gr * wr + br) - (gi * wi + bi);
  float mi = (gi * wr + br) + (gr * wi + bi);
  float re = spec[idx * 2], im = spec[idx * 2 + 1];
  spec[idx * 2]     = re / (1.f + expf(-mr));
  spec[idx * 2 + 1] = im / (1.f + expf(-mi));
}

extern "C" void kernel_launch(void* const* d_in, const int* in_sizes, int n_in,
                              void* d_out, int out_size, void* d_ws, size_t ws_size,
                              hipStream_t stream) {
  const float* mix        = (const float*)d_in[0];
  const float* window     = (const float*)d_in[1];
  const float* c1wr       = (const float*)d_in[2];
  const float* c1br       = (const float*)d_in[3];
  const float* c1wi       = (const float*)d_in[4];
  const float* c1bi       = (const float*)d_in[5];
  const float* c2wr       = (const float*)d_in[6];
  const float* c2br       = (const float*)d_in[7];
  const float* c2wi       = (const float*)d_in[8];
  const float* c2bi       = (const float*)d_in[9];
  const float* attn_in_w  = (const float*)d_in[10];
  const float* attn_in_b  = (const float*)d_in[11];
  const float* attn_out_w = (const float*)d_in[12];
  const float* attn_out_b = (const float*)d_in[13];
  const float* l1wr       = (const float*)d_in[14];
  const float* l1br       = (const float*)d_in[15];
  const float* l1wi       = (const float*)d_in[16];
  const float* l1bi       = (const float*)d_in[17];
  const float* l2wr       = (const float*)d_in[18];
  const float* l2br       = (const float*)d_in[19];
  const float* l2wi       = (const float*)d_in[20];
  const float* l2bi       = (const float*)d_in[21];
  const float* n1_gr      = (const float*)d_in[22];
  const float* n1_br      = (const float*)d_in[23];
  const float* n1_gi      = (const float*)d_in[24];
  const float* n1_bi      = (const float*)d_in[25];
  const float* n2_gr      = (const float*)d_in[26];
  const float* n2_br      = (const float*)d_in[27];
  const float* n2_gi      = (const float*)d_in[28];
  const float* n2_bi      = (const float*)d_in[29];

  // ---- workspace layout, all constexpr (round-9 lesson). kNeed = 188,922,816
  // (exactly the round-4 proven-safe size).
  constexpr long eTokF = (long)kBS * kD;    // 7,068,400 f32 (out-proj/FFN out)
  constexpr long eAout = (long)kBS * kDP;   // 7,089,088 bf16
  constexpr long eXs   = (long)kBS * kDP;   // 7,089,088 bf16
  constexpr long eQKb  = (long)kBS * kHDP;  // 3,558,336 bf16
  constexpr long eWb   = (long)kHD * kDP;   // 2,107,400 bf16
  constexpr long eW1   = (long)kNH * kDP;   // 8,437,824 bf16
  constexpr long eW2   = (long)kD * kNH;    // 8,413,200 bf16
  constexpr long eHid  = (long)kMC * kHLD;  // 14,150,592 bf16

  constexpr size_t oT    = 0;                           // QK splits / fp32 out
  constexpr size_t oAout = oT + 2 * eTokF * 4;          //  56,547,200
  constexpr size_t oXs   = oAout + 2 * eAout * 2;       //  84,903,552
  constexpr size_t oD    = oXs + 4 * eXs * 2;           // 141,616,256
  constexpr size_t kNeed = 188922816;
  constexpr size_t oTW   = kNeed - 8192;                // 188,914,624
  // T arena: 7 QK-split buffers + per-batch P tail
  constexpr size_t oP    = oT + 7 * eQKb * 2;           //  49,816,704
  static_assert(oP + 3 * kS2P * 2 <= oAout, "P overflow");
  // D arena: V | Kil | {W (phase1) / sS 2-batch (phase2)}
  constexpr size_t oV    = oD;
  constexpr size_t oK8   = oV + 2 * eQKb * 2;           // 155,849,600
  constexpr size_t oW    = oK8 + eQKb * 2;              // 162,966,272
  static_assert(oW + 5 * eWb * 2 <= oTW, "W overflow");
  constexpr size_t oSS   = oW;                          // overlay (W dead)
  static_assert(oSS + 8 * kS2 * 4 <= oTW, "sS overflow");
  // FFN overlays (attention dead)
  constexpr size_t oW1r  = oXs;
  constexpr size_t oW1i  = oW1r + eW1 * 2;
  constexpr size_t oHidR = oW1i + eW1 * 2;              // 118,654,848
  constexpr size_t oHidI = oHidR + eHid * 2;
  static_assert(oHidI + eHid * 2 <= oTW, "hid overflow");
  constexpr size_t oW2r  = oXs;
  constexpr size_t oW2i  = oW2r + eW2 * 2;
  static_assert(oW2i + eW2 * 2 <= oHidR, "w2/hid overlap");

  char* wsb = (char*)d_ws;
  if (ws_size < kNeed) return;  // fail signature: out0 all-zero (2.578125)

  float* xr    = (float*)(wsb + oT);       // fp32 out-proj/FFN (post-attn)
  float* xi    = xr + eTokF;
  bf16*  Qrh = (bf16*)(wsb + oT);          // attention-phase T overlay
  bf16*  Qrl = Qrh + eQKb;
  bf16*  Qih = Qrl + eQKb;
  bf16*  Qil = Qih + eQKb;
  bf16*  Krh = Qil + eQKb;
  bf16*  Krl = Krh + eQKb;
  bf16*  Kih = Krl + eQKb;
  bf16*  Kil = (bf16*)(wsb + oK8);
  bf16*  Pbuf = (bf16*)(wsb + oP);
  bf16*  aoutR = (bf16*)(wsb + oAout);
  bf16*  aoutI = aoutR + eAout;
  bf16*  Xrh = (bf16*)(wsb + oXs);
  bf16*  Xrl = Xrh + eXs;
  bf16*  Xih = Xrl + eXs;
  bf16*  Xil = Xih + eXs;
  bf16*  Vr = (bf16*)(wsb + oV);
  bf16*  Vi = Vr + eQKb;
  bf16*  Wqh = (bf16*)(wsb + oW);
  bf16*  Wql = Wqh + eWb;
  bf16*  Wkh = Wql + eWb;
  bf16*  Wkl = Wkh + eWb;
  bf16*  Wvh = Wkl + eWb;
  float* sS = (float*)(wsb + oSS);
  bf16*  Wob = (bf16*)(wsb + oV);          // out-proj W (V dead)
  bf16*  AbR = (bf16*)(wsb + oAout);       // FFN activations (aout dead)
  bf16*  AbI = AbR + eAout;
  bf16*  w1rH = (bf16*)(wsb + oW1r);
  bf16*  w1iH = (bf16*)(wsb + oW1i);
  bf16*  w2rH = (bf16*)(wsb + oW2r);
  bf16*  w2iH = (bf16*)(wsb + oW2i);
  bf16*  hidR = (bf16*)(wsb + oHidR);
  bf16*  hidI = (bf16*)(wsb + oHidI);
  float* frames = (float*)(wsb + oAout);
  float2* tw = (float2*)(wsb + oTW);

  float* out0 = (float*)d_out;
  float* spec = out0 + (long)kNSIG * kL;

  auto cvt2 = [&](const float* src, bf16* dst, int dstRows, int ldd,
                  int srows, int scols, int lds) {
    long total = (long)dstRows * ldd;
    k_cvt2<<<(int)((total + 255) / 256), 256, 0, stream>>>(src, dst, total,
                                                           ldd, srows, scols,
                                                           lds);
  };
  auto cvt2s = [&](const float* src, bf16* dh, bf16* dl, int dstRows, int ldd,
                   int srows, int scols, int lds) {
    long total = (long)dstRows * ldd;
    k_cvt2s<<<(int)((total + 255) / 256), 256, 0, stream>>>(
        src, dh, dl, total, ldd, srows, scols, lds);
  };

  // 0) zero workspace (pad zeros for all padded buffers), twiddle table
  hipMemsetAsync(d_ws, 0, kNeed, stream);
  k_twiddle<<<4, 256, 0, stream>>>(tw);

  // 1) STFT -> spec (out1)
  k_stft<<<dim3(kT, kNSIG), 256, 0, stream>>>(mix, window, tw, spec);

  // 2) conv1 + pos-enc -> split-bf16 tokens (Xrh/Xrl/Xih/Xil)
  long nct = (long)kB * 2 * kBINS * kT;
  k_conv1_pe<<<(nct + 255) / 256, 256, 0, stream>>>(spec, c1wr, c1br, c1wi,
                                                    c1bi, Xrh, Xrl, Xih, Xil);

  // 3) attention, per head — all GEMMs on MFMA (Q/K via split precision)
  for (int h = 0; h < 2; ++h) {
    const float* Wq = attn_in_w + (long)(h * kHD) * kD;
    const float* Wk = attn_in_w + (long)(kD + h * kHD) * kD;
    const float* Wv = attn_in_w + (long)(2 * kD + h * kHD) * kD;
    const float* bq = attn_in_b + h * kHD;
    const float* bk = attn_in_b + kD + h * kHD;
    const float* bv = attn_in_b + 2 * kD + h * kHD;
    cvt2s(Wq, Wqh, Wql, kHD, kDP, kHD, kD, kD);
    cvt2s(Wk, Wkh, Wkl, kHD, kDP, kHD, kD, kD);
    cvt2(Wv, Wvh, kHD, kDP, kHD, kD, kD);
    // V projection (bf16 A = Xh)
    k_mfma2<bf16, bf16><<<dim3(9, 27), 256, 0, stream>>>(
        Xrh, Xih, Wvh, Vr, Vi, bv, 1.f, 1.f, kBS, kHD, kD, kDP, kDP, kHDP);
    // Q, K projections (split precision, outputs re-split)
    k_mfma2s<<<dim3(9, 27), 256, 0, stream>>>(
        Xrh, Xrl, Xih, Xil, Wqh, Wql, Qrh, Qrl, Qih, Qil, bq,
        kBS, kHD, kD, kDP, kDP, kHDP);
    k_mfma2s<<<dim3(9, 27), 256, 0, stream>>>(
        Xrh, Xrl, Xih, Xil, Wkh, Wkl, Krh, Krl, Kih, Kil, bk,
        kBS, kHD, kD, kDP, kDP, kHDP);
    for (int bp = 0; bp < 2; ++bp) {
      // scores for 2 batches x 4 combos (split precision, fp32 out)
      k_qkt<<<dim3(7, 7, 4), 256, 0, stream>>>(Qrh, Qrl, Qih, Qil,
                                               Krh, Krl, Kih, Kil, sS, bp);
      for (int bl = 0; bl < 2; ++bl) {
        int b = bp * 2 + bl;
        k_smf<<<kT, 256, 0, stream>>>(sS + (long)bl * 4 * kS2, Pbuf);
        k_pv<<<dim3(9, 7), 256, 0, stream>>>(
            Pbuf, Vr + (long)b * kT * kHDP, Vi + (long)b * kT * kHDP,
            aoutR + (long)b * kT * kDP + h * kHD,
            aoutI + (long)b * kT * kDP + h * kHD,
            kT, kHD, kT, kTP, kHDP, kDP);
      }
    }
  }

  // 4) output projection (MFMA, shared Wo) -> fp32 xr, xi (T arena)
  cvt2(attn_out_w, Wob, kD, kDP, kD, kD, kD);
  k_mfma2<bf16, float><<<dim3(17, 27), 256, 0, stream>>>(
      aoutR, aoutI, Wob, xr, xi, attn_out_b, 0.f, 2.f,
      kBS, kD, kD, kDP, kDP, kD);

  // 5) LN1
  k_ln<<<kBS, 256, 0, stream>>>(xr, n1_gr, n1_br, kD);
  k_ln<<<kBS, 256, 0, stream>>>(xi, n1_gi, n1_bi, kD);

  // 6) FFN (complex-fused), M-chunked
  cvt2(xr, AbR, kBS, kDP, kBS, kD, kD);
  cvt2(xi, AbI, kBS, kDP, kBS, kD, kD);
  for (int c = 0; c < 2; ++c) {
    const bf16* ArC = AbR + (long)c * kMC * kDP;
    const bf16* AiC = AbI + (long)c * kMC * kDP;
    for (int nh = 0; nh < 2; ++nh) {
      int srows = (nh ? kDFF - kNH : kNH);
      cvt2(l1wr + (long)nh * kNH * kD, w1rH, kNH, kDP, srows, kD, kD);
      cvt2(l1wi + (long)nh * kNH * kD, w1iH, kNH, kDP, srows, kD, kD);
      k_cgemm<bf16><<<dim3(33, 14), 256, 0, stream>>>(
          ArC, AiC, w1rH, w1iH, hidR + nh * kNH, hidI + nh * kNH,
          l1br + nh * kNH, l1bi + nh * kNH, 1.f, 0, 1, srows,
          kMC, kNH, kD, kDP, kDP, kHLD);
    }
    float* xrC = xr + (long)c * kMC * kD;
    float* xiC = xi + (long)c * kMC * kD;
    for (int kh = 0; kh < 2; ++kh) {
      int scols = (kh ? kDFF - kNH : kNH);
      cvt2(l2wr + kh * kNH, w2rH, kD, kNH, kD, scols, kDFF);
      cvt2(l2wi + kh * kNH, w2iH, kD, kNH, kD, scols, kDFF);
      k_cgemm<float><<<dim3(17, 14), 256, 0, stream>>>(
          hidR + kh * kNH, hidI + kh * kNH, w2rH, w2iH, xrC, xiC,
          l2br, l2bi, (kh == 0 ? 1.f : 0.f), kh, 0, kD,
          kMC, kD, kNH, kHLD, kNH, kD);
    }
  }

  // 7) LN2
  k_ln<<<kBS, 256, 0, stream>>>(xr, n2_gr, n2_br, kD);
  k_ln<<<kBS, 256, 0, stream>>>(xi, n2_gi, n2_bi, kD);

  // 8) mask + gate spec in place
  k_mask<<<(nct + 255) / 256, 256, 0, stream>>>(xr, xi, c2wr, c2br, c2wi,
                                                c2bi, spec);

  // 9) iSTFT + overlap-add
  k_istft<<<dim3(kT, kNSIG), 256, 0, stream>>>(spec, window, tw, frames);
  k_gather<<<(int)(((long)kNSIG * kL + 255) / 256), 256, 0, stream>>>(
      frames, window, out0);
}

// Round 12
// 6957.118 us; speedup vs baseline: 3.2506x; 1.1768x over previous
//
#include <hip/hip_runtime.h>
#include <hip/hip_bf16.h>
#include <math.h>

#ifndef M_PIf
#define M_PIf 3.14159265358979323846f
#endif

static constexpr int kNFFT = 2048;
static constexpr int kHOP  = 512;
static constexpr int kBINS = 1025;
static constexpr int kT    = 862;
static constexpr int kL    = 441000;
static constexpr int kB    = 4;
static constexpr int kNSIG = 8;
static constexpr int kD    = 2050;
static constexpr int kHD   = 1025;
static constexpr int kDFF  = 8200;
static constexpr int kBS   = kB * kT;   // 3448
static constexpr float kAttnScale = 0.031234752377721214f; // 1/sqrt(1025)
static constexpr long kS2  = (long)kT * kT;    // 743,044
static constexpr int kTP   = 864;
static constexpr long kS2P = (long)kT * kTP;   // 744,768
static constexpr int kDP   = 2056;   // padded row (bf16, 16B aligned)
static constexpr int kHDP  = 1032;
static constexpr int kNH   = 4104;   // FFN N/K half (original slicing)
// FFN padded geometry (for unpredicated global_load_lds staging):
static constexpr int kDP2  = 2080;   // K padded to 32-mult (2050 -> 2080)
static constexpr int kNHP  = 4128;   // N/K half padded to 32-mult
static constexpr int kMP   = 3456;   // M padded to 128-mult (27 blocks)
static constexpr int kW1R  = 4224;   // W1 rows padded to 128-mult (33 blocks)
static constexpr int kW2R  = 2176;   // W2 rows padded to 128-mult (17 blocks)

using bf16 = __hip_bfloat16;
typedef __attribute__((ext_vector_type(4))) float f32x4;
typedef __attribute__((ext_vector_type(8))) short bf16x8;

__device__ __forceinline__ float ldf(const float* p, long i) { return p[i]; }
__device__ __forceinline__ float ldf(const bf16* p, long i) {
  return __bfloat162float(p[i]);
}
__device__ __forceinline__ void sto(float* p, long i, float v) { p[i] = v; }
__device__ __forceinline__ void sto(bf16* p, long i, float v) {
  p[i] = __float2bfloat16(v);
}
__device__ __forceinline__ void load16(const float* src, bf16* dst) {
#pragma unroll
  for (int e = 0; e < 16; ++e) dst[e] = __float2bfloat16(src[e]);
}
__device__ __forceinline__ void load16(const bf16* src, bf16* dst) {
  *(bf16x8*)(dst)     = *(const bf16x8*)(src);
  *(bf16x8*)(dst + 8) = *(const bf16x8*)(src + 8);
}

// Direct global->LDS 16B async copy. LDS dest must be wave-uniform base
// (HW adds lane*16); global src is per-lane.
__device__ __forceinline__ void glds16(const bf16* g, bf16* l) {
  __builtin_amdgcn_global_load_lds(
      (const __attribute__((address_space(1))) unsigned int*)g,
      (__attribute__((address_space(3))) unsigned int*)l, 16, 0, 0);
}

// Stage one 16-element bf16 chunk of a row-major matrix into LDS row.
template <typename T>
__device__ __forceinline__ void stage_row16(const T* S, int grow, int glim,
                                            int lda, int k0sk, int K,
                                            bf16* dst) {
  bf16 tmp[16];
  if (grow < glim && k0sk + 16 <= K) {
    load16(S + (long)grow * lda + k0sk, tmp);
  } else {
#pragma unroll
    for (int e = 0; e < 16; ++e) {
      int gk = k0sk + e;
      tmp[e] = __float2bfloat16(
          (grow < glim && gk < K) ? ldf(S, (long)grow * lda + gk) : 0.f);
    }
  }
  *(bf16x8*)(dst)     = *(bf16x8*)&tmp[0];
  *(bf16x8*)(dst + 8) = *(bf16x8*)&tmp[8];
}

// ---------------------------------------------------------------------------
__global__ void k_twiddle(float2* __restrict__ tw) {
  int m = blockIdx.x * 256 + threadIdx.x;
  if (m < 1024) {
    float s, c;
    sincosf(M_PIf * (float)m / 1024.f, &s, &c);
    tw[m] = make_float2(c, s);
  }
}

__device__ __forceinline__ void fft2048_lds(float*& sr, float*& si,
                                            float* dr, float* di, int tid,
                                            float dir,
                                            const float2* __restrict__ tw) {
  int s = 0;
  for (int Ns = 1; Ns < 2048; Ns <<= 1, ++s) {
#pragma unroll
    for (int q = 0; q < 4; ++q) {
      int j = tid + q * 256;
      int base = j & (Ns - 1);
      int grp = j >> s;
      float2 t = tw[base << (10 - s)];
      float c = t.x, sn = dir * t.y;
      float ar = sr[j],        ai = si[j];
      float br = sr[j + 1024], bi = si[j + 1024];
      float tbr = br * c - bi * sn;
      float tbi = br * sn + bi * c;
      int o = (grp << (s + 1)) + base;
      dr[o]      = ar + tbr;  di[o]      = ai + tbi;
      dr[o + Ns] = ar - tbr;  di[o + Ns] = ai - tbi;
    }
    __syncthreads();
    float* t0 = sr; sr = dr; dr = t0;
    float* t1 = si; si = di; di = t1;
  }
}

__global__ __launch_bounds__(256) void k_stft(const float* __restrict__ mix,
                                              const float* __restrict__ win,
                                              const float2* __restrict__ tw,
                                              float* __restrict__ spec) {
  __shared__ float b0r[2048], b0i[2048], b1r[2048], b1i[2048];
  int t = blockIdx.x, sig = blockIdx.y, tid = threadIdx.x;
  const float* x = mix + (long)sig * kL;
  for (int i = tid; i < 2048; i += 256) {
    int src = t * kHOP + i - 1024;
    if (src < 0) src = -src;
    if (src >= kL) src = 2 * kL - 2 - src;
    b0r[i] = x[src] * win[i];
    b0i[i] = 0.f;
  }
  __syncthreads();
  float* sr = b0r; float* si = b0i;
  fft2048_lds(sr, si, b1r, b1i, tid, -1.f, tw);
  for (int k = tid; k < kBINS; k += 256) {
    long o = ((long)sig * kBINS + k) * kT + t;
    spec[o * 2]     = sr[k];
    spec[o * 2 + 1] = si[k];
  }
}

__global__ __launch_bounds__(256) void k_istft(const float* __restrict__ spec,
                                               const float* __restrict__ win,
                                               const float2* __restrict__ tw,
                                               float* __restrict__ frames) {
  __shared__ float b0r[2048], b0i[2048], b1r[2048], b1i[2048];
  int t = blockIdx.x, sig = blockIdx.y, tid = threadIdx.x;
  for (int k = tid; k < kBINS; k += 256) {
    long o = ((long)sig * kBINS + k) * kT + t;
    b0r[k] = spec[o * 2];
    b0i[k] = spec[o * 2 + 1];
  }
  __syncthreads();
  for (int k = 1025 + tid; k < 2048; k += 256) {
    b0r[k] = b0r[2048 - k];
    b0i[k] = -b0i[2048 - k];
  }
  __syncthreads();
  float* sr = b0r; float* si = b0i;
  fft2048_lds(sr, si, b1r, b1i, tid, +1.f, tw);
  const float scale = 1.f / 2048.f;
  float* fo = frames + ((long)sig * kT + t) * 2048;
  for (int n = tid; n < 2048; n += 256) fo[n] = sr[n] * scale * win[n];
}

__global__ void k_gather(const float* __restrict__ frames,
                         const float* __restrict__ win,
                         float* __restrict__ out0) {
  long idx = (long)blockIdx.x * 256 + threadIdx.x;
  long total = (long)kNSIG * kL;
  if (idx >= total) return;
  int sig = (int)(idx / kL);
  int l = (int)(idx % kL);
  int j = l + 1024;
  int tmax = j >> 9; if (tmax > kT - 1) tmax = kT - 1;
  int v = j - 1536;
  int tmin = v > 0 ? (v >> 9) : 0;
  float acc = 0.f, w2 = 0.f;
  for (int t = tmin; t <= tmax; ++t) {
    int n = j - (t << 9);
    float w = win[n];
    acc += frames[((long)sig * kT + t) * 2048 + n];
    w2 = fmaf(w, w, w2);
  }
  out0[idx] = acc / (w2 > 1e-11f ? w2 : 1.f);
}

// conv1x1 + pos-enc -> tokens written DIRECTLY as bf16 hi/lo split pairs.
__global__ void k_conv1_pe(const float* __restrict__ spec,
                           const float* __restrict__ c1wr, const float* __restrict__ c1br,
                           const float* __restrict__ c1wi, const float* __restrict__ c1bi,
                           bf16* __restrict__ xrh, bf16* __restrict__ xrl,
                           bf16* __restrict__ xih, bf16* __restrict__ xil) {
  long idx = (long)blockIdx.x * 256 + threadIdx.x;
  long total = (long)kB * 2 * kBINS * kT;
  if (idx >= total) return;
  int t = (int)(idx % kT);
  long r0 = idx / kT;
  int bin = (int)(r0 % kBINS);
  long r1 = r0 / kBINS;
  int ch = (int)(r1 % 2);
  int b = (int)(r1 / 2);
  float re = spec[idx * 2], im = spec[idx * 2 + 1];
  float wr = c1wr[ch], br = c1br[ch], wi = c1wi[ch], bi = c1bi[ch];
  float nr = (re * wr + br) - (im * wi + bi);
  float ni = (im * wr + br) + (re * wi + bi);
  int d = bin * 2 + ch;
  int k = d >> 1;
  float dv = expf((float)k * (-9.210340371976184f / 1025.0f));
  float arg = (float)t * dv;
  float pe = (d & 1) ? cosf(arg) : sinf(arg);
  long ro = ((long)(b * kT + t)) * kDP + d;
  float vr = nr + pe, vi = ni + pe;
  bf16 hr = __float2bfloat16(vr);
  bf16 hi = __float2bfloat16(vi);
  xrh[ro] = hr; xrl[ro] = __float2bfloat16(vr - __bfloat162float(hr));
  xih[ro] = hi; xil[ro] = __float2bfloat16(vi - __bfloat162float(hi));
}

// fp32 -> bf16 convert, zero-fill outside (srows x scols).
__global__ void k_cvt2(const float* __restrict__ src, bf16* __restrict__ dst,
                       long total, int ldd, int srows, int scols, int lds) {
  long idx = (long)blockIdx.x * 256 + threadIdx.x;
  if (idx >= total) return;
  int r = (int)(idx / ldd), c = (int)(idx % ldd);
  float v = (r < srows && c < scols) ? src[(long)r * lds + c] : 0.f;
  dst[idx] = __float2bfloat16(v);
}

// fp32 -> split bf16 (hi + lo), zero-fill outside.
__global__ void k_cvt2s(const float* __restrict__ src, bf16* __restrict__ dh,
                        bf16* __restrict__ dl, long total, int ldd, int srows,
                        int scols, int lds) {
  long idx = (long)blockIdx.x * 256 + threadIdx.x;
  if (idx >= total) return;
  int r = (int)(idx / ldd), c = (int)(idx % ldd);
  float v = (r < srows && c < scols) ? src[(long)r * lds + c] : 0.f;
  bf16 h = __float2bfloat16(v);
  dh[idx] = h;
  dl[idx] = __float2bfloat16(v - __bfloat162float(h));
}

// ---------------------------------------------------------------------------
// MFMA, 2 A's sharing one B (bf16 NxK): C1 = A1*B^T + bs1*bias,
// C2 = A2*B^T + bs2*bias. 128x128 tile, BK=32, 4 waves. Register staging.
// ---------------------------------------------------------------------------
template <typename TA, typename TC>
__global__ __launch_bounds__(256) void k_mfma2(
    const TA* __restrict__ A1, const TA* __restrict__ A2,
    const bf16* __restrict__ B, TC* __restrict__ C1, TC* __restrict__ C2,
    const float* __restrict__ bias, float bs1, float bs2,
    int M, int N, int K, int lda, int ldb, int ldc) {
  __shared__ __align__(16) bf16 As1[128][40];
  __shared__ __align__(16) bf16 As2[128][40];
  __shared__ __align__(16) bf16 Bs[128][40];
  int tid = threadIdx.x;
  int bm = blockIdx.y * 128, bn = blockIdx.x * 128;
  int lane = tid & 63, w = tid >> 6;
  int wr = (w >> 1) * 64, wc = (w & 1) * 64;
  int fr = lane & 15, fq = lane >> 4;
  f32x4 ac1[4][4] = {}, ac2[4][4] = {};
  int sr = tid >> 1, sk = (tid & 1) * 16;
  for (int k0 = 0; k0 < K; k0 += 32) {
    stage_row16(A1, bm + sr, M, lda, k0 + sk, K, &As1[sr][sk]);
    stage_row16(A2, bm + sr, M, lda, k0 + sk, K, &As2[sr][sk]);
    stage_row16(B,  bn + sr, N, ldb, k0 + sk, K, &Bs[sr][sk]);
    __syncthreads();
    bf16x8 a1[4], a2[4], b[4];
#pragma unroll
    for (int i = 0; i < 4; ++i) {
      a1[i] = *(const bf16x8*)&As1[wr + i * 16 + fr][fq * 8];
      a2[i] = *(const bf16x8*)&As2[wr + i * 16 + fr][fq * 8];
      b[i]  = *(const bf16x8*)&Bs[wc + i * 16 + fr][fq * 8];
    }
#pragma unroll
    for (int i = 0; i < 4; ++i)
#pragma unroll
      for (int j = 0; j < 4; ++j) {
        ac1[i][j] = __builtin_amdgcn_mfma_f32_16x16x32_bf16(a1[i], b[j], ac1[i][j], 0, 0, 0);
        ac2[i][j] = __builtin_amdgcn_mfma_f32_16x16x32_bf16(a2[i], b[j], ac2[i][j], 0, 0, 0);
      }
    __syncthreads();
  }
#pragma unroll
  for (int i = 0; i < 4; ++i)
#pragma unroll
    for (int j = 0; j < 4; ++j) {
      int gn = bn + wc + j * 16 + fr;
      if (gn >= N) continue;
      float bv = bias ? bias[gn] : 0.f;
#pragma unroll
      for (int r = 0; r < 4; ++r) {
        int gm = bm + wr + i * 16 + fq * 4 + r;
        if (gm >= M) continue;
        long co = (long)gm * ldc + gn;
        sto(C1, co, ac1[i][j][r] + bs1 * bv);
        sto(C2, co, ac2[i][j][r] + bs2 * bv);
      }
    }
}

// ---------------------------------------------------------------------------
// Split-precision projection: Or = (Arh+Arl)@(Bh+Bl)^T + bias (3 products,
// drops l@l), Oi likewise. Outputs re-split into hi/lo bf16 pairs.
// ---------------------------------------------------------------------------
__global__ __launch_bounds__(256) void k_mfma2s(
    const bf16* __restrict__ Arh, const bf16* __restrict__ Arl,
    const bf16* __restrict__ Aih, const bf16* __restrict__ Ail,
    const bf16* __restrict__ Bh, const bf16* __restrict__ Bl,
    bf16* __restrict__ Crh, bf16* __restrict__ Crl,
    bf16* __restrict__ Cih, bf16* __restrict__ Cil,
    const float* __restrict__ bias,
    int M, int N, int K, int lda, int ldb, int ldc) {
  __shared__ __align__(16) bf16 Sarh[128][40];
  __shared__ __align__(16) bf16 Sarl[128][40];
  __shared__ __align__(16) bf16 Saih[128][40];
  __shared__ __align__(16) bf16 Sail[128][40];
  __shared__ __align__(16) bf16 Sbh[128][40];
  __shared__ __align__(16) bf16 Sbl[128][40];
  int tid = threadIdx.x;
  int bm = blockIdx.y * 128, bn = blockIdx.x * 128;
  int lane = tid & 63, w = tid >> 6;
  int wr = (w >> 1) * 64, wc = (w & 1) * 64;
  int fr = lane & 15, fq = lane >> 4;
  f32x4 acR[4][4] = {}, acI[4][4] = {};
  int sr = tid >> 1, sk = (tid & 1) * 16;
  for (int k0 = 0; k0 < K; k0 += 32) {
    stage_row16(Arh, bm + sr, M, lda, k0 + sk, K, &Sarh[sr][sk]);
    stage_row16(Arl, bm + sr, M, lda, k0 + sk, K, &Sarl[sr][sk]);
    stage_row16(Aih, bm + sr, M, lda, k0 + sk, K, &Saih[sr][sk]);
    stage_row16(Ail, bm + sr, M, lda, k0 + sk, K, &Sail[sr][sk]);
    stage_row16(Bh,  bn + sr, N, ldb, k0 + sk, K, &Sbh[sr][sk]);
    stage_row16(Bl,  bn + sr, N, ldb, k0 + sk, K, &Sbl[sr][sk]);
    __syncthreads();
    bf16x8 bh[4], bl[4];
#pragma unroll
    for (int j = 0; j < 4; ++j) {
      bh[j] = *(const bf16x8*)&Sbh[wc + j * 16 + fr][fq * 8];
      bl[j] = *(const bf16x8*)&Sbl[wc + j * 16 + fr][fq * 8];
    }
#pragma unroll
    for (int i = 0; i < 4; ++i) {
      bf16x8 arh = *(const bf16x8*)&Sarh[wr + i * 16 + fr][fq * 8];
      bf16x8 arl = *(const bf16x8*)&Sarl[wr + i * 16 + fr][fq * 8];
      bf16x8 aih = *(const bf16x8*)&Saih[wr + i * 16 + fr][fq * 8];
      bf16x8 ail = *(const bf16x8*)&Sail[wr + i * 16 + fr][fq * 8];
#pragma unroll
      for (int j = 0; j < 4; ++j) {
        acR[i][j] = __builtin_amdgcn_mfma_f32_16x16x32_bf16(arh, bh[j], acR[i][j], 0, 0, 0);
        acR[i][j] = __builtin_amdgcn_mfma_f32_16x16x32_bf16(arh, bl[j], acR[i][j], 0, 0, 0);
        acR[i][j] = __builtin_amdgcn_mfma_f32_16x16x32_bf16(arl, bh[j], acR[i][j], 0, 0, 0);
        acI[i][j] = __builtin_amdgcn_mfma_f32_16x16x32_bf16(aih, bh[j], acI[i][j], 0, 0, 0);
        acI[i][j] = __builtin_amdgcn_mfma_f32_16x16x32_bf16(aih, bl[j], acI[i][j], 0, 0, 0);
        acI[i][j] = __builtin_amdgcn_mfma_f32_16x16x32_bf16(ail, bh[j], acI[i][j], 0, 0, 0);
      }
    }
    __syncthreads();
  }
#pragma unroll
  for (int i = 0; i < 4; ++i)
#pragma unroll
    for (int j = 0; j < 4; ++j) {
      int gn = bn + wc + j * 16 + fr;
      if (gn >= N) continue;
      float bv = bias[gn];
#pragma unroll
      for (int r = 0; r < 4; ++r) {
        int gm = bm + wr + i * 16 + fq * 4 + r;
        if (gm >= M) continue;
        long co = (long)gm * ldc + gn;
        float vR = acR[i][j][r] + bv;
        float vI = acI[i][j][r] + bv;
        bf16 hR = __float2bfloat16(vR);
        bf16 hI = __float2bfloat16(vI);
        Crh[co] = hR; Crl[co] = __float2bfloat16(vR - __bfloat162float(hR));
        Cih[co] = hI; Cil[co] = __float2bfloat16(vI - __bfloat162float(hI));
      }
    }
}

// ---------------------------------------------------------------------------
// Split-precision QK^T scores. z = bLocal*2 + qsel (2 batches per launch).
// ---------------------------------------------------------------------------
__global__ __launch_bounds__(256) void k_qkt(
    const bf16* __restrict__ Qrh, const bf16* __restrict__ Qrl,
    const bf16* __restrict__ Qih, const bf16* __restrict__ Qil,
    const bf16* __restrict__ Krh, const bf16* __restrict__ Krl,
    const bf16* __restrict__ Kih, const bf16* __restrict__ Kil,
    float* __restrict__ S, int bp) {
  int bl = blockIdx.z >> 1, qsel = blockIdx.z & 1;
  long roff = (long)(bp * 2 + bl) * kT * kHDP;
  const bf16* qh = (qsel ? Qih : Qrh) + roff;
  const bf16* ql = (qsel ? Qil : Qrl) + roff;
  const bf16* krh = Krh + roff;
  const bf16* krl = Krl + roff;
  const bf16* kih = Kih + roff;
  const bf16* kil = Kil + roff;
  float* S0 = S + ((long)bl * 4 + qsel * 2) * kS2;
  float* S1 = S0 + kS2;
  __shared__ __align__(16) bf16 Sqh[128][40];
  __shared__ __align__(16) bf16 Sql[128][40];
  __shared__ __align__(16) bf16 Skrh[128][40];
  __shared__ __align__(16) bf16 Skrl[128][40];
  __shared__ __align__(16) bf16 Skih[128][40];
  __shared__ __align__(16) bf16 Skil[128][40];
  int tid = threadIdx.x;
  int bm = blockIdx.y * 128, bn = blockIdx.x * 128;
  int lane = tid & 63, w = tid >> 6;
  int wr = (w >> 1) * 64, wc = (w & 1) * 64;
  int fr = lane & 15, fq = lane >> 4;
  f32x4 ac0[4][4] = {}, ac1[4][4] = {};
  int sr = tid >> 1, sk = (tid & 1) * 16;
  for (int k0 = 0; k0 < kHD; k0 += 32) {
    stage_row16(qh,  bm + sr, kT, kHDP, k0 + sk, kHD, &Sqh[sr][sk]);
    stage_row16(ql,  bm + sr, kT, kHDP, k0 + sk, kHD, &Sql[sr][sk]);
    stage_row16(krh, bn + sr, kT, kHDP, k0 + sk, kHD, &Skrh[sr][sk]);
    stage_row16(krl, bn + sr, kT, kHDP, k0 + sk, kHD, &Skrl[sr][sk]);
    stage_row16(kih, bn + sr, kT, kHDP, k0 + sk, kHD, &Skih[sr][sk]);
    stage_row16(kil, bn + sr, kT, kHDP, k0 + sk, kHD, &Skil[sr][sk]);
    __syncthreads();
    bf16x8 q_h[4], q_l[4];
#pragma unroll
    for (int i = 0; i < 4; ++i) {
      q_h[i] = *(const bf16x8*)&Sqh[wr + i * 16 + fr][fq * 8];
      q_l[i] = *(const bf16x8*)&Sql[wr + i * 16 + fr][fq * 8];
    }
#pragma unroll
    for (int j = 0; j < 4; ++j) {
      bf16x8 k_rh = *(const bf16x8*)&Skrh[wc + j * 16 + fr][fq * 8];
      bf16x8 k_rl = *(const bf16x8*)&Skrl[wc + j * 16 + fr][fq * 8];
      bf16x8 k_ih = *(const bf16x8*)&Skih[wc + j * 16 + fr][fq * 8];
      bf16x8 k_il = *(const bf16x8*)&Skil[wc + j * 16 + fr][fq * 8];
#pragma unroll
      for (int i = 0; i < 4; ++i) {
        ac0[i][j] = __builtin_amdgcn_mfma_f32_16x16x32_bf16(q_h[i], k_rh, ac0[i][j], 0, 0, 0);
        ac0[i][j] = __builtin_amdgcn_mfma_f32_16x16x32_bf16(q_h[i], k_rl, ac0[i][j], 0, 0, 0);
        ac0[i][j] = __builtin_amdgcn_mfma_f32_16x16x32_bf16(q_l[i], k_rh, ac0[i][j], 0, 0, 0);
        ac1[i][j] = __builtin_amdgcn_mfma_f32_16x16x32_bf16(q_h[i], k_ih, ac1[i][j], 0, 0, 0);
        ac1[i][j] = __builtin_amdgcn_mfma_f32_16x16x32_bf16(q_h[i], k_il, ac1[i][j], 0, 0, 0);
        ac1[i][j] = __builtin_amdgcn_mfma_f32_16x16x32_bf16(q_l[i], k_ih, ac1[i][j], 0, 0, 0);
      }
    }
    __syncthreads();
  }
#pragma unroll
  for (int i = 0; i < 4; ++i)
#pragma unroll
    for (int j = 0; j < 4; ++j) {
      int gn = bn + wc + j * 16 + fr;
      if (gn >= kT) continue;
#pragma unroll
      for (int r = 0; r < 4; ++r) {
        int gm = bm + wr + i * 16 + fq * 4 + r;
        if (gm >= kT) continue;
        long co = (long)gm * kT + gn;
        S0[co] = ac0[i][j][r];
        S1[co] = ac1[i][j][r];
      }
    }
}

// ---------------------------------------------------------------------------
// Complex-fused MFMA GEMM (FFN) with direct global->LDS staging.
// REQUIREMENTS: A (MxK) and B (NxK) are bf16 with 16B-aligned rows; K == full
// padded row extent (mult of 32); allocations cover grid-rounded M/N rows
// (zero-padded). C-writes guarded by M/N.
// ---------------------------------------------------------------------------
template <typename TC>
__global__ __launch_bounds__(256) void k_cgemm(
    const bf16* __restrict__ Ar, const bf16* __restrict__ Ai,
    const bf16* __restrict__ Br, const bf16* __restrict__ Bi,
    TC* __restrict__ Cr, TC* __restrict__ Ci,
    const float* __restrict__ biasR, const float* __restrict__ biasI,
    float bscale, int accum, int relu, int Nreal,
    int M, int N, int K, int lda, int ldb, int ldc) {
  __shared__ __align__(16) bf16 Asr[128][32];
  __shared__ __align__(16) bf16 Asi[128][32];
  __shared__ __align__(16) bf16 Bsr[128][32];
  __shared__ __align__(16) bf16 Bsi[128][32];
  int tid = threadIdx.x;
  int bm = blockIdx.y * 128, bn = blockIdx.x * 128;
  int lane = tid & 63, w = tid >> 6;
  int wr = (w >> 1) * 64, wc = (w & 1) * 64;
  int fr = lane & 15, fq = lane >> 4;
  f32x4 acR[4][4] = {}, acI[4][4] = {};
  // global_load_lds mapping: wave w, call c: lane l -> row w*32+c*16+(l>>2),
  // col (l&3)*8; LDS base (elements) = w*1024 + c*512 (wave-uniform).
  int srow = w * 32 + (lane >> 2);
  int scol = (lane & 3) * 8;
  for (int k0 = 0; k0 < K; k0 += 32) {
#pragma unroll
    for (int c = 0; c < 2; ++c) {
      long ga = (long)(bm + srow + c * 16) * lda + k0 + scol;
      long gb = (long)(bn + srow + c * 16) * ldb + k0 + scol;
      int lb = w * 1024 + c * 512;
      glds16(Ar + ga, &Asr[0][0] + lb);
      glds16(Ai + ga, &Asi[0][0] + lb);
      glds16(Br + gb, &Bsr[0][0] + lb);
      glds16(Bi + gb, &Bsi[0][0] + lb);
    }
    __syncthreads();
    bf16x8 ar[4], ai[4], nai[4], br[4], bi[4];
    const short ks = (short)0x8000;
    const bf16x8 sgn = {ks, ks, ks, ks, ks, ks, ks, ks};
#pragma unroll
    for (int i = 0; i < 4; ++i) {
      ar[i] = *(const bf16x8*)&Asr[wr + i * 16 + fr][fq * 8];
      ai[i] = *(const bf16x8*)&Asi[wr + i * 16 + fr][fq * 8];
      nai[i] = ai[i] ^ sgn;
      br[i] = *(const bf16x8*)&Bsr[wc + i * 16 + fr][fq * 8];
      bi[i] = *(const bf16x8*)&Bsi[wc + i * 16 + fr][fq * 8];
    }
#pragma unroll
    for (int i = 0; i < 4; ++i)
#pragma unroll
      for (int j = 0; j < 4; ++j) {
        acR[i][j] = __builtin_amdgcn_mfma_f32_16x16x32_bf16(ar[i],  br[j], acR[i][j], 0, 0, 0);
        acR[i][j] = __builtin_amdgcn_mfma_f32_16x16x32_bf16(nai[i], bi[j], acR[i][j], 0, 0, 0);
        acI[i][j] = __builtin_amdgcn_mfma_f32_16x16x32_bf16(ai[i],  br[j], acI[i][j], 0, 0, 0);
        acI[i][j] = __builtin_amdgcn_mfma_f32_16x16x32_bf16(ar[i],  bi[j], acI[i][j], 0, 0, 0);
      }
    __syncthreads();
  }
#pragma unroll
  for (int i = 0; i < 4; ++i)
#pragma unroll
    for (int j = 0; j < 4; ++j) {
      int gn = bn + wc + j * 16 + fr;
      if (gn >= N) continue;
      float br_ = 0.f, bi_ = 0.f;
      if (gn < Nreal) { br_ = biasR[gn]; bi_ = biasI[gn]; }
#pragma unroll
      for (int r = 0; r < 4; ++r) {
        int gm = bm + wr + i * 16 + fq * 4 + r;
        if (gm >= M) continue;
        long co = (long)gm * ldc + gn;
        float vR = acR[i][j][r] + bscale * (br_ - bi_);
        float vI = acI[i][j][r] + bscale * (br_ + bi_);
        if (accum) { vR += ldf(Cr, co); vI += ldf(Ci, co); }
        if (relu) { vR = fmaxf(vR, 0.f); vI = fmaxf(vI, 0.f); }
        sto(Cr, co, vR);
        sto(Ci, co, vI);
      }
    }
}

// ---------------------------------------------------------------------------
// Fused PV: Cr = P0@Vr + P2@Vi ; Ci = P0@Vi + P1@Vr. B is KxN (single batch).
// ---------------------------------------------------------------------------
__global__ __launch_bounds__(256) void k_pv(
    const bf16* __restrict__ P, const bf16* __restrict__ Vr,
    const bf16* __restrict__ Vi, bf16* __restrict__ Cr,
    bf16* __restrict__ Ci, int M, int N, int K, int ldp, int ldv, int ldc) {
  __shared__ __align__(16) bf16 Ps0[128][40];
  __shared__ __align__(16) bf16 Ps1[128][40];
  __shared__ __align__(16) bf16 Ps2[128][40];
  __shared__ __align__(16) bf16 Vsr[128][40];
  __shared__ __align__(16) bf16 Vsi[128][40];
  int tid = threadIdx.x;
  int bm = blockIdx.y * 128, bn = blockIdx.x * 128;
  int lane = tid & 63, w = tid >> 6;
  int wr = (w >> 1) * 64, wc = (w & 1) * 64;
  int fr = lane & 15, fq = lane >> 4;
  f32x4 acR[4][4] = {}, acI[4][4] = {};
  int sr = tid >> 1, sk = (tid & 1) * 16;
  int kk = tid >> 3, nq = (tid & 7) * 16;
  for (int k0 = 0; k0 < K; k0 += 32) {
    stage_row16(P,            bm + sr, M, ldp, k0 + sk, K, &Ps0[sr][sk]);
    stage_row16(P + kS2P,     bm + sr, M, ldp, k0 + sk, K, &Ps1[sr][sk]);
    stage_row16(P + 2 * kS2P, bm + sr, M, ldp, k0 + sk, K, &Ps2[sr][sk]);
    {
      int gk = k0 + kk;
      bf16 t0[16], t1[16];
      if (gk < K && bn + nq + 16 <= N) {
        load16(Vr + (long)gk * ldv + bn + nq, t0);
        load16(Vi + (long)gk * ldv + bn + nq, t1);
      } else {
#pragma unroll
        for (int e = 0; e < 16; ++e) {
          int gn = bn + nq + e;
          bool ok = (gk < K && gn < N);
          t0[e] = __float2bfloat16(ok ? ldf(Vr, (long)gk * ldv + gn) : 0.f);
          t1[e] = __float2bfloat16(ok ? ldf(Vi, (long)gk * ldv + gn) : 0.f);
        }
      }
#pragma unroll
      for (int e = 0; e < 16; ++e) {
        Vsr[nq + e][kk] = t0[e];
        Vsi[nq + e][kk] = t1[e];
      }
    }
    __syncthreads();
    bf16x8 p0[4], p1[4], p2[4], vr[4], vi[4];
#pragma unroll
    for (int i = 0; i < 4; ++i) {
      p0[i] = *(const bf16x8*)&Ps0[wr + i * 16 + fr][fq * 8];
      p1[i] = *(const bf16x8*)&Ps1[wr + i * 16 + fr][fq * 8];
      p2[i] = *(const bf16x8*)&Ps2[wr + i * 16 + fr][fq * 8];
      vr[i] = *(const bf16x8*)&Vsr[wc + i * 16 + fr][fq * 8];
      vi[i] = *(const bf16x8*)&Vsi[wc + i * 16 + fr][fq * 8];
    }
#pragma unroll
    for (int i = 0; i < 4; ++i)
#pragma unroll
      for (int j = 0; j < 4; ++j) {
        acR[i][j] = __builtin_amdgcn_mfma_f32_16x16x32_bf16(p0[i], vr[j], acR[i][j], 0, 0, 0);
        acR[i][j] = __builtin_amdgcn_mfma_f32_16x16x32_bf16(p2[i], vi[j], acR[i][j], 0, 0, 0);
        acI[i][j] = __builtin_amdgcn_mfma_f32_16x16x32_bf16(p0[i], vi[j], acI[i][j], 0, 0, 0);
        acI[i][j] = __builtin_amdgcn_mfma_f32_16x16x32_bf16(p1[i], vr[j], acI[i][j], 0, 0, 0);
      }
    __syncthreads();
  }
#pragma unroll
  for (int i = 0; i < 4; ++i)
#pragma unroll
    for (int j = 0; j < 4; ++j) {
      int gn = bn + wc + j * 16 + fr;
      if (gn >= N) continue;
#pragma unroll
      for (int r = 0; r < 4; ++r) {
        int gm = bm + wr + i * 16 + fq * 4 + r;
        if (gm >= M) continue;
        long co = (long)gm * ldc + gn;
        Cr[co] = __float2bfloat16(acR[i][j][r]);
        Ci[co] = __float2bfloat16(acI[i][j][r]);
      }
    }
}

// Fused softmax over 4 fp32 score mats + fold to 3 bf16 P mats (stride kS2P).
__global__ __launch_bounds__(256) void k_smf(const float* __restrict__ S,
                                             bf16* __restrict__ P) {
  long rbase = (long)blockIdx.x * kT;
  long pbase = (long)blockIdx.x * kTP;
  int tid = threadIdx.x;
  int lane = tid & 63, w = tid >> 6;
  float v[4][4];
  float mx[4] = {-3.4e38f, -3.4e38f, -3.4e38f, -3.4e38f};
#pragma unroll
  for (int c = 0; c < 4; ++c) {
    const float* row = S + c * kS2 + rbase;
#pragma unroll
    for (int q = 0; q < 4; ++q) {
      int i = tid + q * 256;
      v[c][q] = (i < kT) ? row[i] : -3.4e38f;
      mx[c] = fmaxf(mx[c], v[c][q]);
    }
  }
  __shared__ float redm[4][4];
  for (int o = 32; o > 0; o >>= 1)
#pragma unroll
    for (int c = 0; c < 4; ++c) mx[c] = fmaxf(mx[c], __shfl_down(mx[c], o));
  if (lane == 0)
#pragma unroll
    for (int c = 0; c < 4; ++c) redm[w][c] = mx[c];
  __syncthreads();
#pragma unroll
  for (int c = 0; c < 4; ++c)
    mx[c] = fmaxf(fmaxf(redm[0][c], redm[1][c]), fmaxf(redm[2][c], redm[3][c]));
  __syncthreads();
  float sm[4] = {0.f, 0.f, 0.f, 0.f};
#pragma unroll
  for (int c = 0; c < 4; ++c)
#pragma unroll
    for (int q = 0; q < 4; ++q) {
      int i = tid + q * 256;
      if (i < kT) {
        v[c][q] = expf(kAttnScale * (v[c][q] - mx[c]));
        sm[c] += v[c][q];
      }
    }
  __shared__ float reds[4][4];
  for (int o = 32; o > 0; o >>= 1)
#pragma unroll
    for (int c = 0; c < 4; ++c) sm[c] += __shfl_down(sm[c], o);
  if (lane == 0)
#pragma unroll
    for (int c = 0; c < 4; ++c) reds[w][c] = sm[c];
  __syncthreads();
  float inv[4];
#pragma unroll
  for (int c = 0; c < 4; ++c)
    inv[c] = 1.f / (reds[0][c] + reds[1][c] + reds[2][c] + reds[3][c]);
  bf16* p0 = P + pbase;
  bf16* p1 = P + kS2P + pbase;
  bf16* p2 = P + 2 * kS2P + pbase;
#pragma unroll
  for (int q = 0; q < 4; ++q) {
    int i = tid + q * 256;
    if (i >= kT) continue;
    float a0 = v[0][q] * inv[0], a1 = v[1][q] * inv[1];
    float a2 = v[2][q] * inv[2], a3 = v[3][q] * inv[3];
    p0[i] = __float2bfloat16(a0 - a3);
    p1[i] = __float2bfloat16(a1 + a2);
    p2[i] = __float2bfloat16(a1 - a2);
  }
}

__global__ __launch_bounds__(256) void k_ln(float* __restrict__ X,
                                            const float* __restrict__ g,
                                            const float* __restrict__ b, int d) {
  long row = blockIdx.x;
  float* x = X + row * d;
  int tid = threadIdx.x;
  float s = 0.f, s2 = 0.f;
  for (int i = tid; i < d; i += 256) {
    float v = x[i];
    s += v;
    s2 = fmaf(v, v, s2);
  }
  __shared__ float rs[4], rs2[4];
  for (int o = 32; o > 0; o >>= 1) {
    s += __shfl_down(s, o);
    s2 += __shfl_down(s2, o);
  }
  int lane = tid & 63, w = tid >> 6;
  if (lane == 0) { rs[w] = s; rs2[w] = s2; }
  __syncthreads();
  float st = rs[0] + rs[1] + rs[2] + rs[3];
  float s2t = rs2[0] + rs2[1] + rs2[2] + rs2[3];
  float m = st / d;
  float var = s2t / d - m * m;
  float inv = rsqrtf(var + 1e-5f);
  for (int i = tid; i < d; i += 256) x[i] = (x[i] - m) * inv * g[i] + b[i];
}

__global__ void k_mask(const float* __restrict__ gr_, const float* __restrict__ gi_,
                       const float* __restrict__ c2wr, const float* __restrict__ c2br,
                       const float* __restrict__ c2wi, const float* __restrict__ c2bi,
                       float* __restrict__ spec) {
  long idx = (long)blockIdx.x * 256 + threadIdx.x;
  long total = (long)kB * 2 * kBINS * kT;
  if (idx >= total) return;
  int t = (int)(idx % kT);
  long r0 = idx / kT;
  int bin = (int)(r0 % kBINS);
  long r1 = r0 / kBINS;
  int ch = (int)(r1 % 2);
  int b = (int)(r1 / 2);
  long ro = ((long)(b * kT + t)) * kD + (bin * 2 + ch);
  float gr = gr_[ro], gi = gi_[ro];
  float wr = c2wr[ch], br = c2br[ch], wi = c2wi[ch], bi = c2bi[ch];
  float mr = (gr * wr + br) - (gi * wi + bi);
  float mi = (gi * wr + br) + (gr * wi + bi);
  float re = spec[idx * 2], im = spec[idx * 2 + 1];
  spec[idx * 2]     = re / (1.f + expf(-mr));
  spec[idx * 2 + 1] = im / (1.f + expf(-mi));
}

extern "C" void kernel_launch(void* const* d_in, const int* in_sizes, int n_in,
                              void* d_out, int out_size, void* d_ws, size_t ws_size,
                              hipStream_t stream) {
  const float* mix        = (const float*)d_in[0];
  const float* window     = (const float*)d_in[1];
  const float* c1wr       = (const float*)d_in[2];
  const float* c1br       = (const float*)d_in[3];
  const float* c1wi       = (const float*)d_in[4];
  const float* c1bi       = (const float*)d_in[5];
  const float* c2wr       = (const float*)d_in[6];
  const float* c2br       = (const float*)d_in[7];
  const float* c2wi       = (const float*)d_in[8];
  const float* c2bi       = (const float*)d_in[9];
  const float* attn_in_w  = (const float*)d_in[10];
  const float* attn_in_b  = (const float*)d_in[11];
  const float* attn_out_w = (const float*)d_in[12];
  const float* attn_out_b = (const float*)d_in[13];
  const float* l1wr       = (const float*)d_in[14];
  const float* l1br       = (const float*)d_in[15];
  const float* l1wi       = (const float*)d_in[16];
  const float* l1bi       = (const float*)d_in[17];
  const float* l2wr       = (const float*)d_in[18];
  const float* l2br       = (const float*)d_in[19];
  const float* l2wi       = (const float*)d_in[20];
  const float* l2bi       = (const float*)d_in[21];
  const float* n1_gr      = (const float*)d_in[22];
  const float* n1_br      = (const float*)d_in[23];
  const float* n1_gi      = (const float*)d_in[24];
  const float* n1_bi      = (const float*)d_in[25];
  const float* n2_gr      = (const float*)d_in[26];
  const float* n2_br      = (const float*)d_in[27];
  const float* n2_gi      = (const float*)d_in[28];
  const float* n2_bi      = (const float*)d_in[29];

  // ---- workspace layout, all constexpr. kNeed = 188,922,816 (proven safe).
  constexpr long eTokF = (long)kBS * kD;    // fp32 out-proj/FFN out
  constexpr long eAout = (long)kBS * kDP;
  constexpr long eXs   = (long)kBS * kDP;
  constexpr long eQKb  = (long)kBS * kHDP;
  constexpr long eWb   = (long)kHD * kDP;
  // FFN padded buffers:
  constexpr long eAb   = (long)kMP * kDP2;   // 3456x2080
  constexpr long eW1p  = (long)kW1R * kDP2;  // 4224x2080
  constexpr long eW2p  = (long)kW2R * kNHP;  // 2176x4128
  constexpr long eHidp = (long)kMP * kNHP;   // 3456x4128

  constexpr size_t oT    = 0;
  constexpr size_t oAout = oT + 2 * eTokF * 4;          //  56,547,200
  constexpr size_t oXs   = oAout + 2 * eAout * 2;       //  84,903,552
  constexpr size_t oD    = oXs + 4 * eXs * 2;           // 141,616,256
  constexpr size_t kNeed = 188922816;
  constexpr size_t oTW   = kNeed - 8192;                // 188,914,624
  constexpr size_t oP    = oT + 7 * eQKb * 2;           //  49,816,704
  static_assert(oP + 3 * kS2P * 2 <= oAout, "P overflow");
  constexpr size_t oV    = oD;
  constexpr size_t oK8   = oV + 2 * eQKb * 2;
  constexpr size_t oW    = oK8 + eQKb * 2;
  static_assert(oW + 5 * eWb * 2 <= oTW, "W overflow");
  constexpr size_t oSS   = oW;
  static_assert(oSS + 8 * kS2 * 4 <= oTW, "sS overflow");
  // FFN overlays (attention dead):
  constexpr size_t oAb   = oAout;                       //  56,547,200
  constexpr size_t oWF   = oAb + 2 * eAb * 2;           //  85,301,120
  constexpr size_t oHid  = oWF + 2 * eW2p * 2;          // 121,231,232 (W2 > W1)
  static_assert(2 * eW1p * 2 <= 2 * eW2p * 2, "W slot sized by W2");
  static_assert(oHid + 2 * eHidp * 2 <= oTW, "hid overflow");

  char* wsb = (char*)d_ws;
  if (ws_size < kNeed) return;  // fail signature: out0 all-zero (2.578125)

  float* xr    = (float*)(wsb + oT);       // fp32 out-proj/FFN (post-attn)
  float* xi    = xr + eTokF;
  bf16*  Qrh = (bf16*)(wsb + oT);          // attention-phase T overlay
  bf16*  Qrl = Qrh + eQKb;
  bf16*  Qih = Qrl + eQKb;
  bf16*  Qil = Qih + eQKb;
  bf16*  Krh = Qil + eQKb;
  bf16*  Krl = Krh + eQKb;
  bf16*  Kih = Krl + eQKb;
  bf16*  Kil = (bf16*)(wsb + oK8);
  bf16*  Pbuf = (bf16*)(wsb + oP);
  bf16*  aoutR = (bf16*)(wsb + oAout);
  bf16*  aoutI = aoutR + eAout;
  bf16*  Xrh = (bf16*)(wsb + oXs);
  bf16*  Xrl = Xrh + eXs;
  bf16*  Xih = Xrl + eXs;
  bf16*  Xil = Xih + eXs;
  bf16*  Vr = (bf16*)(wsb + oV);
  bf16*  Vi = Vr + eQKb;
  bf16*  Wqh = (bf16*)(wsb + oW);
  bf16*  Wql = Wqh + eWb;
  bf16*  Wkh = Wql + eWb;
  bf16*  Wkl = Wkh + eWb;
  bf16*  Wvh = Wkl + eWb;
  float* sS = (float*)(wsb + oSS);
  bf16*  Wob = (bf16*)(wsb + oV);          // out-proj W (V dead)
  // FFN pointers:
  bf16*  AbR = (bf16*)(wsb + oAb);
  bf16*  AbI = AbR + eAb;
  bf16*  w1rH = (bf16*)(wsb + oWF);
  bf16*  w1iH = w1rH + eW1p;
  bf16*  w2rH = (bf16*)(wsb + oWF);
  bf16*  w2iH = w2rH + eW2p;
  bf16*  hidR = (bf16*)(wsb + oHid);
  bf16*  hidI = hidR + eHidp;
  float* frames = (float*)(wsb + oAout);
  float2* tw = (float2*)(wsb + oTW);

  float* out0 = (float*)d_out;
  float* spec = out0 + (long)kNSIG * kL;

  auto cvt2 = [&](const float* src, bf16* dst, int dstRows, int ldd,
                  int srows, int scols, int lds) {
    long total = (long)dstRows * ldd;
    k_cvt2<<<(int)((total + 255) / 256), 256, 0, stream>>>(src, dst, total,
                                                           ldd, srows, scols,
                                                           lds);
  };
  auto cvt2s = [&](const float* src, bf16* dh, bf16* dl, int dstRows, int ldd,
                   int srows, int scols, int lds) {
    long total = (long)dstRows * ldd;
    k_cvt2s<<<(int)((total + 255) / 256), 256, 0, stream>>>(
        src, dh, dl, total, ldd, srows, scols, lds);
  };

  // 0) zero workspace, twiddle table
  hipMemsetAsync(d_ws, 0, kNeed, stream);
  k_twiddle<<<4, 256, 0, stream>>>(tw);

  // 1) STFT -> spec (out1)
  k_stft<<<dim3(kT, kNSIG), 256, 0, stream>>>(mix, window, tw, spec);

  // 2) conv1 + pos-enc -> split-bf16 tokens
  long nct = (long)kB * 2 * kBINS * kT;
  k_conv1_pe<<<(nct + 255) / 256, 256, 0, stream>>>(spec, c1wr, c1br, c1wi,
                                                    c1bi, Xrh, Xrl, Xih, Xil);

  // 3) attention, per head (unchanged from round 11 — verified)
  for (int h = 0; h < 2; ++h) {
    const float* Wq = attn_in_w + (long)(h * kHD) * kD;
    const float* Wk = attn_in_w + (long)(kD + h * kHD) * kD;
    const float* Wv = attn_in_w + (long)(2 * kD + h * kHD) * kD;
    const float* bq = attn_in_b + h * kHD;
    const float* bk = attn_in_b + kD + h * kHD;
    const float* bv = attn_in_b + 2 * kD + h * kHD;
    cvt2s(Wq, Wqh, Wql, kHD, kDP, kHD, kD, kD);
    cvt2s(Wk, Wkh, Wkl, kHD, kDP, kHD, kD, kD);
    cvt2(Wv, Wvh, kHD, kDP, kHD, kD, kD);
    k_mfma2<bf16, bf16><<<dim3(9, 27), 256, 0, stream>>>(
        Xrh, Xih, Wvh, Vr, Vi, bv, 1.f, 1.f, kBS, kHD, kD, kDP, kDP, kHDP);
    k_mfma2s<<<dim3(9, 27), 256, 0, stream>>>(
        Xrh, Xrl, Xih, Xil, Wqh, Wql, Qrh, Qrl, Qih, Qil, bq,
        kBS, kHD, kD, kDP, kDP, kHDP);
    k_mfma2s<<<dim3(9, 27), 256, 0, stream>>>(
        Xrh, Xrl, Xih, Xil, Wkh, Wkl, Krh, Krl, Kih, Kil, bk,
        kBS, kHD, kD, kDP, kDP, kHDP);
    for (int bp = 0; bp < 2; ++bp) {
      k_qkt<<<dim3(7, 7, 4), 256, 0, stream>>>(Qrh, Qrl, Qih, Qil,
                                               Krh, Krl, Kih, Kil, sS, bp);
      for (int bl = 0; bl < 2; ++bl) {
        int b = bp * 2 + bl;
        k_smf<<<kT, 256, 0, stream>>>(sS + (long)bl * 4 * kS2, Pbuf);
        k_pv<<<dim3(9, 7), 256, 0, stream>>>(
            Pbuf, Vr + (long)b * kT * kHDP, Vi + (long)b * kT * kHDP,
            aoutR + (long)b * kT * kDP + h * kHD,
            aoutI + (long)b * kT * kDP + h * kHD,
            kT, kHD, kT, kTP, kHDP, kDP);
      }
    }
  }

  // 4) output projection -> fp32 xr, xi (T arena)
  cvt2(attn_out_w, Wob, kD, kDP, kD, kD, kD);
  k_mfma2<bf16, float><<<dim3(17, 27), 256, 0, stream>>>(
      aoutR, aoutI, Wob, xr, xi, attn_out_b, 0.f, 2.f,
      kBS, kD, kD, kDP, kDP, kD);

  // 5) LN1
  k_ln<<<kBS, 256, 0, stream>>>(xr, n1_gr, n1_br, kD);
  k_ln<<<kBS, 256, 0, stream>>>(xi, n1_gi, n1_bi, kD);

  // 6) FFN (complex-fused, full-M, N/K-halved, global_load_lds staging)
  cvt2(xr, AbR, kMP, kDP2, kBS, kD, kD);
  cvt2(xi, AbI, kMP, kDP2, kBS, kD, kD);
  for (int nh = 0; nh < 2; ++nh) {
    int srows = (nh ? kDFF - kNH : kNH);   // 4096 : 4104
    // FFN1 half: hid = relu(complex(A @ W1[nh]^T) + bias)
    cvt2(l1wr + (long)nh * kNH * kD, w1rH, kW1R, kDP2, srows, kD, kD);
    cvt2(l1wi + (long)nh * kNH * kD, w1iH, kW1R, kDP2, srows, kD, kD);
    k_cgemm<bf16><<<dim3(33, 27), 256, 0, stream>>>(
        AbR, AbI, w1rH, w1iH, hidR, hidI,
        l1br + nh * kNH, l1bi + nh * kNH, 1.f, 0, 1, srows,
        kBS, kNHP, kDP2, kDP2, kDP2, kNHP);
    // FFN2 partial: x (+)= complex(hid @ W2[:, nh]^T) + bias (nh=0 only)
    cvt2(l2wr + nh * kNH, w2rH, kW2R, kNHP, kD, srows, kDFF);
    cvt2(l2wi + nh * kNH, w2iH, kW2R, kNHP, kD, srows, kDFF);
    k_cgemm<float><<<dim3(17, 27), 256, 0, stream>>>(
        hidR, hidI, w2rH, w2iH, xr, xi,
        l2br, l2bi, (nh == 0 ? 1.f : 0.f), nh, 0, kD,
        kBS, kD, kNHP, kNHP, kNHP, kD);
  }

  // 7) LN2
  k_ln<<<kBS, 256, 0, stream>>>(xr, n2_gr, n2_br, kD);
  k_ln<<<kBS, 256, 0, stream>>>(xi, n2_gi, n2_bi, kD);

  // 8) mask + gate spec in place
  k_mask<<<(nct + 255) / 256, 256, 0, stream>>>(xr, xi, c2wr, c2br, c2wi,
                                                c2bi, spec);

  // 9) iSTFT + overlap-add
  k_istft<<<dim3(kT, kNSIG), 256, 0, stream>>>(spec, window, tw, frames);
  k_gather<<<(int)(((long)kNSIG * kL + 255) / 256), 256, 0, stream>>>(
      frames, window, out0);
}

// Round 13
// 6669.633 us; speedup vs baseline: 3.3907x; 1.0431x over previous
//
#include <hip/hip_runtime.h>
#include <hip/hip_bf16.h>
#include <math.h>

#ifndef M_PIf
#define M_PIf 3.14159265358979323846f
#endif

static constexpr int kNFFT = 2048;
static constexpr int kHOP  = 512;
static constexpr int kBINS = 1025;
static constexpr int kT    = 862;
static constexpr int kL    = 441000;
static constexpr int kB    = 4;
static constexpr int kNSIG = 8;
static constexpr int kD    = 2050;
static constexpr int kHD   = 1025;
static constexpr int kDFF  = 8200;
static constexpr int kBS   = kB * kT;   // 3448
static constexpr float kAttnScale = 0.031234752377721214f; // 1/sqrt(1025)
static constexpr long kS2  = (long)kT * kT;    // 743,044
static constexpr int kTP   = 864;
static constexpr long kS2P = (long)kT * kTP;   // 744,768
static constexpr int kDP   = 2056;   // padded row (bf16, 16B aligned)
static constexpr int kHDP  = 1032;
static constexpr int kNH   = 4104;   // FFN N/K half (original slicing)
// FFN padded geometry (for unpredicated global_load_lds staging):
static constexpr int kDP2  = 2080;   // K padded to 32-mult (2050 -> 2080)
static constexpr int kNHP  = 4128;   // N/K half padded to 32-mult
static constexpr int kMP   = 3456;   // M padded to 128-mult (27 blocks)
static constexpr int kW1R  = 4224;   // W1 rows padded to 128-mult (33 blocks)
static constexpr int kW2R  = 2176;   // W2 rows padded to 128-mult (17 blocks)

using bf16 = __hip_bfloat16;
typedef __attribute__((ext_vector_type(4))) float f32x4;
typedef __attribute__((ext_vector_type(8))) short bf16x8;

__device__ __forceinline__ float ldf(const float* p, long i) { return p[i]; }
__device__ __forceinline__ float ldf(const bf16* p, long i) {
  return __bfloat162float(p[i]);
}
__device__ __forceinline__ void sto(float* p, long i, float v) { p[i] = v; }
__device__ __forceinline__ void sto(bf16* p, long i, float v) {
  p[i] = __float2bfloat16(v);
}
__device__ __forceinline__ void load16(const float* src, bf16* dst) {
#pragma unroll
  for (int e = 0; e < 16; ++e) dst[e] = __float2bfloat16(src[e]);
}
__device__ __forceinline__ void load16(const bf16* src, bf16* dst) {
  *(bf16x8*)(dst)     = *(const bf16x8*)(src);
  *(bf16x8*)(dst + 8) = *(const bf16x8*)(src + 8);
}

// Direct global->LDS 16B async copy. LDS dest must be wave-uniform base
// (HW adds lane*16); global src is per-lane.
__device__ __forceinline__ void glds16(const bf16* g, bf16* l) {
  __builtin_amdgcn_global_load_lds(
      (const __attribute__((address_space(1))) unsigned int*)g,
      (__attribute__((address_space(3))) unsigned int*)l, 16, 0, 0);
}

// Stage one 16-element bf16 chunk of a row-major matrix into LDS row.
template <typename T>
__device__ __forceinline__ void stage_row16(const T* S, int grow, int glim,
                                            int lda, int k0sk, int K,
                                            bf16* dst) {
  bf16 tmp[16];
  if (grow < glim && k0sk + 16 <= K) {
    load16(S + (long)grow * lda + k0sk, tmp);
  } else {
#pragma unroll
    for (int e = 0; e < 16; ++e) {
      int gk = k0sk + e;
      tmp[e] = __float2bfloat16(
          (grow < glim && gk < K) ? ldf(S, (long)grow * lda + gk) : 0.f);
    }
  }
  *(bf16x8*)(dst)     = *(bf16x8*)&tmp[0];
  *(bf16x8*)(dst + 8) = *(bf16x8*)&tmp[8];
}

// ---------------------------------------------------------------------------
__global__ void k_twiddle(float2* __restrict__ tw) {
  int m = blockIdx.x * 256 + threadIdx.x;
  if (m < 1024) {
    float s, c;
    sincosf(M_PIf * (float)m / 1024.f, &s, &c);
    tw[m] = make_float2(c, s);
  }
}

__device__ __forceinline__ void fft2048_lds(float*& sr, float*& si,
                                            float* dr, float* di, int tid,
                                            float dir,
                                            const float2* __restrict__ tw) {
  int s = 0;
  for (int Ns = 1; Ns < 2048; Ns <<= 1, ++s) {
#pragma unroll
    for (int q = 0; q < 4; ++q) {
      int j = tid + q * 256;
      int base = j & (Ns - 1);
      int grp = j >> s;
      float2 t = tw[base << (10 - s)];
      float c = t.x, sn = dir * t.y;
      float ar = sr[j],        ai = si[j];
      float br = sr[j + 1024], bi = si[j + 1024];
      float tbr = br * c - bi * sn;
      float tbi = br * sn + bi * c;
      int o = (grp << (s + 1)) + base;
      dr[o]      = ar + tbr;  di[o]      = ai + tbi;
      dr[o + Ns] = ar - tbr;  di[o + Ns] = ai - tbi;
    }
    __syncthreads();
    float* t0 = sr; sr = dr; dr = t0;
    float* t1 = si; si = di; di = t1;
  }
}

__global__ __launch_bounds__(256) void k_stft(const float* __restrict__ mix,
                                              const float* __restrict__ win,
                                              const float2* __restrict__ tw,
                                              float* __restrict__ spec) {
  __shared__ float b0r[2048], b0i[2048], b1r[2048], b1i[2048];
  int t = blockIdx.x, sig = blockIdx.y, tid = threadIdx.x;
  const float* x = mix + (long)sig * kL;
  for (int i = tid; i < 2048; i += 256) {
    int src = t * kHOP + i - 1024;
    if (src < 0) src = -src;
    if (src >= kL) src = 2 * kL - 2 - src;
    b0r[i] = x[src] * win[i];
    b0i[i] = 0.f;
  }
  __syncthreads();
  float* sr = b0r; float* si = b0i;
  fft2048_lds(sr, si, b1r, b1i, tid, -1.f, tw);
  for (int k = tid; k < kBINS; k += 256) {
    long o = ((long)sig * kBINS + k) * kT + t;
    spec[o * 2]     = sr[k];
    spec[o * 2 + 1] = si[k];
  }
}

__global__ __launch_bounds__(256) void k_istft(const float* __restrict__ spec,
                                               const float* __restrict__ win,
                                               const float2* __restrict__ tw,
                                               float* __restrict__ frames) {
  __shared__ float b0r[2048], b0i[2048], b1r[2048], b1i[2048];
  int t = blockIdx.x, sig = blockIdx.y, tid = threadIdx.x;
  for (int k = tid; k < kBINS; k += 256) {
    long o = ((long)sig * kBINS + k) * kT + t;
    b0r[k] = spec[o * 2];
    b0i[k] = spec[o * 2 + 1];
  }
  __syncthreads();
  for (int k = 1025 + tid; k < 2048; k += 256) {
    b0r[k] = b0r[2048 - k];
    b0i[k] = -b0i[2048 - k];
  }
  __syncthreads();
  float* sr = b0r; float* si = b0i;
  fft2048_lds(sr, si, b1r, b1i, tid, +1.f, tw);
  const float scale = 1.f / 2048.f;
  float* fo = frames + ((long)sig * kT + t) * 2048;
  for (int n = tid; n < 2048; n += 256) fo[n] = sr[n] * scale * win[n];
}

__global__ void k_gather(const float* __restrict__ frames,
                         const float* __restrict__ win,
                         float* __restrict__ out0) {
  long idx = (long)blockIdx.x * 256 + threadIdx.x;
  long total = (long)kNSIG * kL;
  if (idx >= total) return;
  int sig = (int)(idx / kL);
  int l = (int)(idx % kL);
  int j = l + 1024;
  int tmax = j >> 9; if (tmax > kT - 1) tmax = kT - 1;
  int v = j - 1536;
  int tmin = v > 0 ? (v >> 9) : 0;
  float acc = 0.f, w2 = 0.f;
  for (int t = tmin; t <= tmax; ++t) {
    int n = j - (t << 9);
    float w = win[n];
    acc += frames[((long)sig * kT + t) * 2048 + n];
    w2 = fmaf(w, w, w2);
  }
  out0[idx] = acc / (w2 > 1e-11f ? w2 : 1.f);
}

// conv1x1 + pos-enc -> tokens written DIRECTLY as bf16 hi/lo split pairs.
__global__ void k_conv1_pe(const float* __restrict__ spec,
                           const float* __restrict__ c1wr, const float* __restrict__ c1br,
                           const float* __restrict__ c1wi, const float* __restrict__ c1bi,
                           bf16* __restrict__ xrh, bf16* __restrict__ xrl,
                           bf16* __restrict__ xih, bf16* __restrict__ xil) {
  long idx = (long)blockIdx.x * 256 + threadIdx.x;
  long total = (long)kB * 2 * kBINS * kT;
  if (idx >= total) return;
  int t = (int)(idx % kT);
  long r0 = idx / kT;
  int bin = (int)(r0 % kBINS);
  long r1 = r0 / kBINS;
  int ch = (int)(r1 % 2);
  int b = (int)(r1 / 2);
  float re = spec[idx * 2], im = spec[idx * 2 + 1];
  float wr = c1wr[ch], br = c1br[ch], wi = c1wi[ch], bi = c1bi[ch];
  float nr = (re * wr + br) - (im * wi + bi);
  float ni = (im * wr + br) + (re * wi + bi);
  int d = bin * 2 + ch;
  int k = d >> 1;
  float dv = expf((float)k * (-9.210340371976184f / 1025.0f));
  float arg = (float)t * dv;
  float pe = (d & 1) ? cosf(arg) : sinf(arg);
  long ro = ((long)(b * kT + t)) * kDP + d;
  float vr = nr + pe, vi = ni + pe;
  bf16 hr = __float2bfloat16(vr);
  bf16 hi = __float2bfloat16(vi);
  xrh[ro] = hr; xrl[ro] = __float2bfloat16(vr - __bfloat162float(hr));
  xih[ro] = hi; xil[ro] = __float2bfloat16(vi - __bfloat162float(hi));
}

// fp32 -> bf16 convert, zero-fill outside (srows x scols).
__global__ void k_cvt2(const float* __restrict__ src, bf16* __restrict__ dst,
                       long total, int ldd, int srows, int scols, int lds) {
  long idx = (long)blockIdx.x * 256 + threadIdx.x;
  if (idx >= total) return;
  int r = (int)(idx / ldd), c = (int)(idx % ldd);
  float v = (r < srows && c < scols) ? src[(long)r * lds + c] : 0.f;
  dst[idx] = __float2bfloat16(v);
}

// fp32 -> split bf16 (hi + lo), zero-fill outside.
__global__ void k_cvt2s(const float* __restrict__ src, bf16* __restrict__ dh,
                        bf16* __restrict__ dl, long total, int ldd, int srows,
                        int scols, int lds) {
  long idx = (long)blockIdx.x * 256 + threadIdx.x;
  if (idx >= total) return;
  int r = (int)(idx / ldd), c = (int)(idx % ldd);
  float v = (r < srows && c < scols) ? src[(long)r * lds + c] : 0.f;
  bf16 h = __float2bfloat16(v);
  dh[idx] = h;
  dl[idx] = __float2bfloat16(v - __bfloat162float(h));
}

// ---------------------------------------------------------------------------
// MFMA, 2 A's sharing one B (bf16 NxK): C1 = A1*B^T + bs1*bias,
// C2 = A2*B^T + bs2*bias. 128x128 tile, BK=32, 4 waves. Register staging.
// ---------------------------------------------------------------------------
template <typename TA, typename TC>
__global__ __launch_bounds__(256) void k_mfma2(
    const TA* __restrict__ A1, const TA* __restrict__ A2,
    const bf16* __restrict__ B, TC* __restrict__ C1, TC* __restrict__ C2,
    const float* __restrict__ bias, float bs1, float bs2,
    int M, int N, int K, int lda, int ldb, int ldc) {
  __shared__ __align__(16) bf16 As1[128][40];
  __shared__ __align__(16) bf16 As2[128][40];
  __shared__ __align__(16) bf16 Bs[128][40];
  int tid = threadIdx.x;
  int bm = blockIdx.y * 128, bn = blockIdx.x * 128;
  int lane = tid & 63, w = tid >> 6;
  int wr = (w >> 1) * 64, wc = (w & 1) * 64;
  int fr = lane & 15, fq = lane >> 4;
  f32x4 ac1[4][4] = {}, ac2[4][4] = {};
  int sr = tid >> 1, sk = (tid & 1) * 16;
  for (int k0 = 0; k0 < K; k0 += 32) {
    stage_row16(A1, bm + sr, M, lda, k0 + sk, K, &As1[sr][sk]);
    stage_row16(A2, bm + sr, M, lda, k0 + sk, K, &As2[sr][sk]);
    stage_row16(B,  bn + sr, N, ldb, k0 + sk, K, &Bs[sr][sk]);
    __syncthreads();
    bf16x8 a1[4], a2[4], b[4];
#pragma unroll
    for (int i = 0; i < 4; ++i) {
      a1[i] = *(const bf16x8*)&As1[wr + i * 16 + fr][fq * 8];
      a2[i] = *(const bf16x8*)&As2[wr + i * 16 + fr][fq * 8];
      b[i]  = *(const bf16x8*)&Bs[wc + i * 16 + fr][fq * 8];
    }
#pragma unroll
    for (int i = 0; i < 4; ++i)
#pragma unroll
      for (int j = 0; j < 4; ++j) {
        ac1[i][j] = __builtin_amdgcn_mfma_f32_16x16x32_bf16(a1[i], b[j], ac1[i][j], 0, 0, 0);
        ac2[i][j] = __builtin_amdgcn_mfma_f32_16x16x32_bf16(a2[i], b[j], ac2[i][j], 0, 0, 0);
      }
    __syncthreads();
  }
#pragma unroll
  for (int i = 0; i < 4; ++i)
#pragma unroll
    for (int j = 0; j < 4; ++j) {
      int gn = bn + wc + j * 16 + fr;
      if (gn >= N) continue;
      float bv = bias ? bias[gn] : 0.f;
#pragma unroll
      for (int r = 0; r < 4; ++r) {
        int gm = bm + wr + i * 16 + fq * 4 + r;
        if (gm >= M) continue;
        long co = (long)gm * ldc + gn;
        sto(C1, co, ac1[i][j][r] + bs1 * bv);
        sto(C2, co, ac2[i][j][r] + bs2 * bv);
      }
    }
}

// ---------------------------------------------------------------------------
// Split-precision projection: Or = (Arh+Arl)@(Bh+Bl)^T + bias (3 products,
// drops l@l), Oi likewise. Outputs re-split into hi/lo bf16 pairs.
// ---------------------------------------------------------------------------
__global__ __launch_bounds__(256) void k_mfma2s(
    const bf16* __restrict__ Arh, const bf16* __restrict__ Arl,
    const bf16* __restrict__ Aih, const bf16* __restrict__ Ail,
    const bf16* __restrict__ Bh, const bf16* __restrict__ Bl,
    bf16* __restrict__ Crh, bf16* __restrict__ Crl,
    bf16* __restrict__ Cih, bf16* __restrict__ Cil,
    const float* __restrict__ bias,
    int M, int N, int K, int lda, int ldb, int ldc) {
  __shared__ __align__(16) bf16 Sarh[128][40];
  __shared__ __align__(16) bf16 Sarl[128][40];
  __shared__ __align__(16) bf16 Saih[128][40];
  __shared__ __align__(16) bf16 Sail[128][40];
  __shared__ __align__(16) bf16 Sbh[128][40];
  __shared__ __align__(16) bf16 Sbl[128][40];
  int tid = threadIdx.x;
  int bm = blockIdx.y * 128, bn = blockIdx.x * 128;
  int lane = tid & 63, w = tid >> 6;
  int wr = (w >> 1) * 64, wc = (w & 1) * 64;
  int fr = lane & 15, fq = lane >> 4;
  f32x4 acR[4][4] = {}, acI[4][4] = {};
  int sr = tid >> 1, sk = (tid & 1) * 16;
  for (int k0 = 0; k0 < K; k0 += 32) {
    stage_row16(Arh, bm + sr, M, lda, k0 + sk, K, &Sarh[sr][sk]);
    stage_row16(Arl, bm + sr, M, lda, k0 + sk, K, &Sarl[sr][sk]);
    stage_row16(Aih, bm + sr, M, lda, k0 + sk, K, &Saih[sr][sk]);
    stage_row16(Ail, bm + sr, M, lda, k0 + sk, K, &Sail[sr][sk]);
    stage_row16(Bh,  bn + sr, N, ldb, k0 + sk, K, &Sbh[sr][sk]);
    stage_row16(Bl,  bn + sr, N, ldb, k0 + sk, K, &Sbl[sr][sk]);
    __syncthreads();
    bf16x8 bh[4], bl[4];
#pragma unroll
    for (int j = 0; j < 4; ++j) {
      bh[j] = *(const bf16x8*)&Sbh[wc + j * 16 + fr][fq * 8];
      bl[j] = *(const bf16x8*)&Sbl[wc + j * 16 + fr][fq * 8];
    }
#pragma unroll
    for (int i = 0; i < 4; ++i) {
      bf16x8 arh = *(const bf16x8*)&Sarh[wr + i * 16 + fr][fq * 8];
      bf16x8 arl = *(const bf16x8*)&Sarl[wr + i * 16 + fr][fq * 8];
      bf16x8 aih = *(const bf16x8*)&Saih[wr + i * 16 + fr][fq * 8];
      bf16x8 ail = *(const bf16x8*)&Sail[wr + i * 16 + fr][fq * 8];
#pragma unroll
      for (int j = 0; j < 4; ++j) {
        acR[i][j] = __builtin_amdgcn_mfma_f32_16x16x32_bf16(arh, bh[j], acR[i][j], 0, 0, 0);
        acR[i][j] = __builtin_amdgcn_mfma_f32_16x16x32_bf16(arh, bl[j], acR[i][j], 0, 0, 0);
        acR[i][j] = __builtin_amdgcn_mfma_f32_16x16x32_bf16(arl, bh[j], acR[i][j], 0, 0, 0);
        acI[i][j] = __builtin_amdgcn_mfma_f32_16x16x32_bf16(aih, bh[j], acI[i][j], 0, 0, 0);
        acI[i][j] = __builtin_amdgcn_mfma_f32_16x16x32_bf16(aih, bl[j], acI[i][j], 0, 0, 0);
        acI[i][j] = __builtin_amdgcn_mfma_f32_16x16x32_bf16(ail, bh[j], acI[i][j], 0, 0, 0);
      }
    }
    __syncthreads();
  }
#pragma unroll
  for (int i = 0; i < 4; ++i)
#pragma unroll
    for (int j = 0; j < 4; ++j) {
      int gn = bn + wc + j * 16 + fr;
      if (gn >= N) continue;
      float bv = bias[gn];
#pragma unroll
      for (int r = 0; r < 4; ++r) {
        int gm = bm + wr + i * 16 + fq * 4 + r;
        if (gm >= M) continue;
        long co = (long)gm * ldc + gn;
        float vR = acR[i][j][r] + bv;
        float vI = acI[i][j][r] + bv;
        bf16 hR = __float2bfloat16(vR);
        bf16 hI = __float2bfloat16(vI);
        Crh[co] = hR; Crl[co] = __float2bfloat16(vR - __bfloat162float(hR));
        Cih[co] = hI; Cil[co] = __float2bfloat16(vI - __bfloat162float(hI));
      }
    }
}

// ---------------------------------------------------------------------------
// Split-precision QK^T scores. z = bLocal*2 + qsel (2 batches per launch).
// ---------------------------------------------------------------------------
__global__ __launch_bounds__(256) void k_qkt(
    const bf16* __restrict__ Qrh, const bf16* __restrict__ Qrl,
    const bf16* __restrict__ Qih, const bf16* __restrict__ Qil,
    const bf16* __restrict__ Krh, const bf16* __restrict__ Krl,
    const bf16* __restrict__ Kih, const bf16* __restrict__ Kil,
    float* __restrict__ S, int bp) {
  int bl = blockIdx.z >> 1, qsel = blockIdx.z & 1;
  long roff = (long)(bp * 2 + bl) * kT * kHDP;
  const bf16* qh = (qsel ? Qih : Qrh) + roff;
  const bf16* ql = (qsel ? Qil : Qrl) + roff;
  const bf16* krh = Krh + roff;
  const bf16* krl = Krl + roff;
  const bf16* kih = Kih + roff;
  const bf16* kil = Kil + roff;
  float* S0 = S + ((long)bl * 4 + qsel * 2) * kS2;
  float* S1 = S0 + kS2;
  __shared__ __align__(16) bf16 Sqh[128][40];
  __shared__ __align__(16) bf16 Sql[128][40];
  __shared__ __align__(16) bf16 Skrh[128][40];
  __shared__ __align__(16) bf16 Skrl[128][40];
  __shared__ __align__(16) bf16 Skih[128][40];
  __shared__ __align__(16) bf16 Skil[128][40];
  int tid = threadIdx.x;
  int bm = blockIdx.y * 128, bn = blockIdx.x * 128;
  int lane = tid & 63, w = tid >> 6;
  int wr = (w >> 1) * 64, wc = (w & 1) * 64;
  int fr = lane & 15, fq = lane >> 4;
  f32x4 ac0[4][4] = {}, ac1[4][4] = {};
  int sr = tid >> 1, sk = (tid & 1) * 16;
  for (int k0 = 0; k0 < kHD; k0 += 32) {
    stage_row16(qh,  bm + sr, kT, kHDP, k0 + sk, kHD, &Sqh[sr][sk]);
    stage_row16(ql,  bm + sr, kT, kHDP, k0 + sk, kHD, &Sql[sr][sk]);
    stage_row16(krh, bn + sr, kT, kHDP, k0 + sk, kHD, &Skrh[sr][sk]);
    stage_row16(krl, bn + sr, kT, kHDP, k0 + sk, kHD, &Skrl[sr][sk]);
    stage_row16(kih, bn + sr, kT, kHDP, k0 + sk, kHD, &Skih[sr][sk]);
    stage_row16(kil, bn + sr, kT, kHDP, k0 + sk, kHD, &Skil[sr][sk]);
    __syncthreads();
    bf16x8 q_h[4], q_l[4];
#pragma unroll
    for (int i = 0; i < 4; ++i) {
      q_h[i] = *(const bf16x8*)&Sqh[wr + i * 16 + fr][fq * 8];
      q_l[i] = *(const bf16x8*)&Sql[wr + i * 16 + fr][fq * 8];
    }
#pragma unroll
    for (int j = 0; j < 4; ++j) {
      bf16x8 k_rh = *(const bf16x8*)&Skrh[wc + j * 16 + fr][fq * 8];
      bf16x8 k_rl = *(const bf16x8*)&Skrl[wc + j * 16 + fr][fq * 8];
      bf16x8 k_ih = *(const bf16x8*)&Skih[wc + j * 16 + fr][fq * 8];
      bf16x8 k_il = *(const bf16x8*)&Skil[wc + j * 16 + fr][fq * 8];
#pragma unroll
      for (int i = 0; i < 4; ++i) {
        ac0[i][j] = __builtin_amdgcn_mfma_f32_16x16x32_bf16(q_h[i], k_rh, ac0[i][j], 0, 0, 0);
        ac0[i][j] = __builtin_amdgcn_mfma_f32_16x16x32_bf16(q_h[i], k_rl, ac0[i][j], 0, 0, 0);
        ac0[i][j] = __builtin_amdgcn_mfma_f32_16x16x32_bf16(q_l[i], k_rh, ac0[i][j], 0, 0, 0);
        ac1[i][j] = __builtin_amdgcn_mfma_f32_16x16x32_bf16(q_h[i], k_ih, ac1[i][j], 0, 0, 0);
        ac1[i][j] = __builtin_amdgcn_mfma_f32_16x16x32_bf16(q_h[i], k_il, ac1[i][j], 0, 0, 0);
        ac1[i][j] = __builtin_amdgcn_mfma_f32_16x16x32_bf16(q_l[i], k_ih, ac1[i][j], 0, 0, 0);
      }
    }
    __syncthreads();
  }
#pragma unroll
  for (int i = 0; i < 4; ++i)
#pragma unroll
    for (int j = 0; j < 4; ++j) {
      int gn = bn + wc + j * 16 + fr;
      if (gn >= kT) continue;
#pragma unroll
      for (int r = 0; r < 4; ++r) {
        int gm = bm + wr + i * 16 + fq * 4 + r;
        if (gm >= kT) continue;
        long co = (long)gm * kT + gn;
        S0[co] = ac0[i][j][r];
        S1[co] = ac1[i][j][r];
      }
    }
}

// ---------------------------------------------------------------------------
// Complex-fused MFMA GEMM (FFN): 2-phase double-buffered global_load_lds
// pipeline + bijective XCD-aware block swizzle. Requirements as round 12
// (padded bf16 operands, K mult of 32, grid-rounded row allocations).
// ---------------------------------------------------------------------------
template <typename TC>
__global__ __launch_bounds__(256) void k_cgemm(
    const bf16* __restrict__ Ar, const bf16* __restrict__ Ai,
    const bf16* __restrict__ Br, const bf16* __restrict__ Bi,
    TC* __restrict__ Cr, TC* __restrict__ Ci,
    const float* __restrict__ biasR, const float* __restrict__ biasI,
    float bscale, int accum, int relu, int Nreal,
    int M, int N, int K, int lda, int ldb, int ldc) {
  __shared__ __align__(16) bf16 Asr[2][128][32];
  __shared__ __align__(16) bf16 Asi[2][128][32];
  __shared__ __align__(16) bf16 Bsr[2][128][32];
  __shared__ __align__(16) bf16 Bsi[2][128][32];
  // bijective XCD-aware swizzle (m204): contiguous wg chunks per XCD.
  int nwg = gridDim.x * gridDim.y;
  int orig = blockIdx.y * gridDim.x + blockIdx.x;
  int qq = nwg >> 3, rr = nwg & 7;
  int xcd = orig & 7, loc = orig >> 3;
  int wg = (xcd < rr ? xcd * (qq + 1) : rr * (qq + 1) + (xcd - rr) * qq) + loc;
  int bx = wg % gridDim.x, by = wg / gridDim.x;
  int bm = by * 128, bn = bx * 128;
  int tid = threadIdx.x;
  int lane = tid & 63, w = tid >> 6;
  int wr = (w >> 1) * 64, wc = (w & 1) * 64;
  int fr = lane & 15, fq = lane >> 4;
  f32x4 acR[4][4] = {}, acI[4][4] = {};
  // staging geometry: wave w, call c: lane l -> row w*32+c*16+(l>>2),
  // col (l&3)*8; LDS element base = w*1024 + c*512 (wave-uniform).
  int srow = w * 32 + (lane >> 2);
  int scol = (lane & 3) * 8;
  const bf16* pA[2][2];  // [r/i][c]
  const bf16* pB[2][2];
#pragma unroll
  for (int c = 0; c < 2; ++c) {
    long ga = (long)(bm + srow + c * 16) * lda + scol;
    long gb = (long)(bn + srow + c * 16) * ldb + scol;
    pA[0][c] = Ar + ga; pA[1][c] = Ai + ga;
    pB[0][c] = Br + gb; pB[1][c] = Bi + gb;
  }
  // prologue: stage t=0 into buffer 0
#pragma unroll
  for (int c = 0; c < 2; ++c) {
    int lb = w * 1024 + c * 512;
    glds16(pA[0][c], &Asr[0][0][0] + lb);
    glds16(pA[1][c], &Asi[0][0][0] + lb);
    glds16(pB[0][c], &Bsr[0][0][0] + lb);
    glds16(pB[1][c], &Bsi[0][0][0] + lb);
  }
  __syncthreads();  // compiler drains vmcnt(0) before s_barrier
  const short ks = (short)0x8000;
  const bf16x8 sgn = {ks, ks, ks, ks, ks, ks, ks, ks};
  int nt = K >> 5;
  long koff = 32;
  for (int t = 0; t < nt; ++t) {
    int p = t & 1;
    // issue prefetch of t+1 into the other buffer BEFORE compute of t
    if (t + 1 < nt) {
      int pb = (p ^ 1) * 4096;
#pragma unroll
      for (int c = 0; c < 2; ++c) {
        int lb = pb + w * 1024 + c * 512;
        glds16(pA[0][c] + koff, &Asr[0][0][0] + lb);
        glds16(pA[1][c] + koff, &Asi[0][0][0] + lb);
        glds16(pB[0][c] + koff, &Bsr[0][0][0] + lb);
        glds16(pB[1][c] + koff, &Bsi[0][0][0] + lb);
      }
      koff += 32;
    }
    bf16x8 ar[4], ai[4], nai[4], br[4], bi[4];
#pragma unroll
    for (int i = 0; i < 4; ++i) {
      ar[i] = *(const bf16x8*)&Asr[p][wr + i * 16 + fr][fq * 8];
      ai[i] = *(const bf16x8*)&Asi[p][wr + i * 16 + fr][fq * 8];
      nai[i] = ai[i] ^ sgn;
      br[i] = *(const bf16x8*)&Bsr[p][wc + i * 16 + fr][fq * 8];
      bi[i] = *(const bf16x8*)&Bsi[p][wc + i * 16 + fr][fq * 8];
    }
#pragma unroll
    for (int i = 0; i < 4; ++i)
#pragma unroll
      for (int j = 0; j < 4; ++j) {
        acR[i][j] = __builtin_amdgcn_mfma_f32_16x16x32_bf16(ar[i],  br[j], acR[i][j], 0, 0, 0);
        acR[i][j] = __builtin_amdgcn_mfma_f32_16x16x32_bf16(nai[i], bi[j], acR[i][j], 0, 0, 0);
        acI[i][j] = __builtin_amdgcn_mfma_f32_16x16x32_bf16(ai[i],  br[j], acI[i][j], 0, 0, 0);
        acI[i][j] = __builtin_amdgcn_mfma_f32_16x16x32_bf16(ar[i],  bi[j], acI[i][j], 0, 0, 0);
      }
    __syncthreads();  // drains vmcnt(0): prefetched tile landed; reads done
  }
#pragma unroll
  for (int i = 0; i < 4; ++i)
#pragma unroll
    for (int j = 0; j < 4; ++j) {
      int gn = bn + wc + j * 16 + fr;
      if (gn >= N) continue;
      float br_ = 0.f, bi_ = 0.f;
      if (gn < Nreal) { br_ = biasR[gn]; bi_ = biasI[gn]; }
#pragma unroll
      for (int r = 0; r < 4; ++r) {
        int gm = bm + wr + i * 16 + fq * 4 + r;
        if (gm >= M) continue;
        long co = (long)gm * ldc + gn;
        float vR = acR[i][j][r] + bscale * (br_ - bi_);
        float vI = acI[i][j][r] + bscale * (br_ + bi_);
        if (accum) { vR += ldf(Cr, co); vI += ldf(Ci, co); }
        if (relu) { vR = fmaxf(vR, 0.f); vI = fmaxf(vI, 0.f); }
        sto(Cr, co, vR);
        sto(Ci, co, vI);
      }
    }
}

// ---------------------------------------------------------------------------
// Fused PV: Cr = P0@Vr + P2@Vi ; Ci = P0@Vi + P1@Vr. B is KxN (single batch).
// ---------------------------------------------------------------------------
__global__ __launch_bounds__(256) void k_pv(
    const bf16* __restrict__ P, const bf16* __restrict__ Vr,
    const bf16* __restrict__ Vi, bf16* __restrict__ Cr,
    bf16* __restrict__ Ci, int M, int N, int K, int ldp, int ldv, int ldc) {
  __shared__ __align__(16) bf16 Ps0[128][40];
  __shared__ __align__(16) bf16 Ps1[128][40];
  __shared__ __align__(16) bf16 Ps2[128][40];
  __shared__ __align__(16) bf16 Vsr[128][40];
  __shared__ __align__(16) bf16 Vsi[128][40];
  int tid = threadIdx.x;
  int bm = blockIdx.y * 128, bn = blockIdx.x * 128;
  int lane = tid & 63, w = tid >> 6;
  int wr = (w >> 1) * 64, wc = (w & 1) * 64;
  int fr = lane & 15, fq = lane >> 4;
  f32x4 acR[4][4] = {}, acI[4][4] = {};
  int sr = tid >> 1, sk = (tid & 1) * 16;
  int kk = tid >> 3, nq = (tid & 7) * 16;
  for (int k0 = 0; k0 < K; k0 += 32) {
    stage_row16(P,            bm + sr, M, ldp, k0 + sk, K, &Ps0[sr][sk]);
    stage_row16(P + kS2P,     bm + sr, M, ldp, k0 + sk, K, &Ps1[sr][sk]);
    stage_row16(P + 2 * kS2P, bm + sr, M, ldp, k0 + sk, K, &Ps2[sr][sk]);
    {
      int gk = k0 + kk;
      bf16 t0[16], t1[16];
      if (gk < K && bn + nq + 16 <= N) {
        load16(Vr + (long)gk * ldv + bn + nq, t0);
        load16(Vi + (long)gk * ldv + bn + nq, t1);
      } else {
#pragma unroll
        for (int e = 0; e < 16; ++e) {
          int gn = bn + nq + e;
          bool ok = (gk < K && gn < N);
          t0[e] = __float2bfloat16(ok ? ldf(Vr, (long)gk * ldv + gn) : 0.f);
          t1[e] = __float2bfloat16(ok ? ldf(Vi, (long)gk * ldv + gn) : 0.f);
        }
      }
#pragma unroll
      for (int e = 0; e < 16; ++e) {
        Vsr[nq + e][kk] = t0[e];
        Vsi[nq + e][kk] = t1[e];
      }
    }
    __syncthreads();
    bf16x8 p0[4], p1[4], p2[4], vr[4], vi[4];
#pragma unroll
    for (int i = 0; i < 4; ++i) {
      p0[i] = *(const bf16x8*)&Ps0[wr + i * 16 + fr][fq * 8];
      p1[i] = *(const bf16x8*)&Ps1[wr + i * 16 + fr][fq * 8];
      p2[i] = *(const bf16x8*)&Ps2[wr + i * 16 + fr][fq * 8];
      vr[i] = *(const bf16x8*)&Vsr[wc + i * 16 + fr][fq * 8];
      vi[i] = *(const bf16x8*)&Vsi[wc + i * 16 + fr][fq * 8];
    }
#pragma unroll
    for (int i = 0; i < 4; ++i)
#pragma unroll
      for (int j = 0; j < 4; ++j) {
        acR[i][j] = __builtin_amdgcn_mfma_f32_16x16x32_bf16(p0[i], vr[j], acR[i][j], 0, 0, 0);
        acR[i][j] = __builtin_amdgcn_mfma_f32_16x16x32_bf16(p2[i], vi[j], acR[i][j], 0, 0, 0);
        acI[i][j] = __builtin_amdgcn_mfma_f32_16x16x32_bf16(p0[i], vi[j], acI[i][j], 0, 0, 0);
        acI[i][j] = __builtin_amdgcn_mfma_f32_16x16x32_bf16(p1[i], vr[j], acI[i][j], 0, 0, 0);
      }
    __syncthreads();
  }
#pragma unroll
  for (int i = 0; i < 4; ++i)
#pragma unroll
    for (int j = 0; j < 4; ++j) {
      int gn = bn + wc + j * 16 + fr;
      if (gn >= N) continue;
#pragma unroll
      for (int r = 0; r < 4; ++r) {
        int gm = bm + wr + i * 16 + fq * 4 + r;
        if (gm >= M) continue;
        long co = (long)gm * ldc + gn;
        Cr[co] = __float2bfloat16(acR[i][j][r]);
        Ci[co] = __float2bfloat16(acI[i][j][r]);
      }
    }
}

// Fused softmax over 4 fp32 score mats + fold to 3 bf16 P mats (stride kS2P).
__global__ __launch_bounds__(256) void k_smf(const float* __restrict__ S,
                                             bf16* __restrict__ P) {
  long rbase = (long)blockIdx.x * kT;
  long pbase = (long)blockIdx.x * kTP;
  int tid = threadIdx.x;
  int lane = tid & 63, w = tid >> 6;
  float v[4][4];
  float mx[4] = {-3.4e38f, -3.4e38f, -3.4e38f, -3.4e38f};
#pragma unroll
  for (int c = 0; c < 4; ++c) {
    const float* row = S + c * kS2 + rbase;
#pragma unroll
    for (int q = 0; q < 4; ++q) {
      int i = tid + q * 256;
      v[c][q] = (i < kT) ? row[i] : -3.4e38f;
      mx[c] = fmaxf(mx[c], v[c][q]);
    }
  }
  __shared__ float redm[4][4];
  for (int o = 32; o > 0; o >>= 1)
#pragma unroll
    for (int c = 0; c < 4; ++c) mx[c] = fmaxf(mx[c], __shfl_down(mx[c], o));
  if (lane == 0)
#pragma unroll
    for (int c = 0; c < 4; ++c) redm[w][c] = mx[c];
  __syncthreads();
#pragma unroll
  for (int c = 0; c < 4; ++c)
    mx[c] = fmaxf(fmaxf(redm[0][c], redm[1][c]), fmaxf(redm[2][c], redm[3][c]));
  __syncthreads();
  float sm[4] = {0.f, 0.f, 0.f, 0.f};
#pragma unroll
  for (int c = 0; c < 4; ++c)
#pragma unroll
    for (int q = 0; q < 4; ++q) {
      int i = tid + q * 256;
      if (i < kT) {
        v[c][q] = expf(kAttnScale * (v[c][q] - mx[c]));
        sm[c] += v[c][q];
      }
    }
  __shared__ float reds[4][4];
  for (int o = 32; o > 0; o >>= 1)
#pragma unroll
    for (int c = 0; c < 4; ++c) sm[c] += __shfl_down(sm[c], o);
  if (lane == 0)
#pragma unroll
    for (int c = 0; c < 4; ++c) reds[w][c] = sm[c];
  __syncthreads();
  float inv[4];
#pragma unroll
  for (int c = 0; c < 4; ++c)
    inv[c] = 1.f / (reds[0][c] + reds[1][c] + reds[2][c] + reds[3][c]);
  bf16* p0 = P + pbase;
  bf16* p1 = P + kS2P + pbase;
  bf16* p2 = P + 2 * kS2P + pbase;
#pragma unroll
  for (int q = 0; q < 4; ++q) {
    int i = tid + q * 256;
    if (i >= kT) continue;
    float a0 = v[0][q] * inv[0], a1 = v[1][q] * inv[1];
    float a2 = v[2][q] * inv[2], a3 = v[3][q] * inv[3];
    p0[i] = __float2bfloat16(a0 - a3);
    p1[i] = __float2bfloat16(a1 + a2);
    p2[i] = __float2bfloat16(a1 - a2);
  }
}

__global__ __launch_bounds__(256) void k_ln(float* __restrict__ X,
                                            const float* __restrict__ g,
                                            const float* __restrict__ b, int d) {
  long row = blockIdx.x;
  float* x = X + row * d;
  int tid = threadIdx.x;
  float s = 0.f, s2 = 0.f;
  for (int i = tid; i < d; i += 256) {
    float v = x[i];
    s += v;
    s2 = fmaf(v, v, s2);
  }
  __shared__ float rs[4], rs2[4];
  for (int o = 32; o > 0; o >>= 1) {
    s += __shfl_down(s, o);
    s2 += __shfl_down(s2, o);
  }
  int lane = tid & 63, w = tid >> 6;
  if (lane == 0) { rs[w] = s; rs2[w] = s2; }
  __syncthreads();
  float st = rs[0] + rs[1] + rs[2] + rs[3];
  float s2t = rs2[0] + rs2[1] + rs2[2] + rs2[3];
  float m = st / d;
  float var = s2t / d - m * m;
  float inv = rsqrtf(var + 1e-5f);
  for (int i = tid; i < d; i += 256) x[i] = (x[i] - m) * inv * g[i] + b[i];
}

__global__ void k_mask(const float* __restrict__ gr_, const float* __restrict__ gi_,
                       const float* __restrict__ c2wr, const float* __restrict__ c2br,
                       const float* __restrict__ c2wi, const float* __restrict__ c2bi,
                       float* __restrict__ spec) {
  long idx = (long)blockIdx.x * 256 + threadIdx.x;
  long total = (long)kB * 2 * kBINS * kT;
  if (idx >= total) return;
  int t = (int)(idx % kT);
  long r0 = idx / kT;
  int bin = (int)(r0 % kBINS);
  long r1 = r0 / kBINS;
  int ch = (int)(r1 % 2);
  int b = (int)(r1 / 2);
  long ro = ((long)(b * kT + t)) * kD + (bin * 2 + ch);
  float gr = gr_[ro], gi = gi_[ro];
  float wr = c2wr[ch], br = c2br[ch], wi = c2wi[ch], bi = c2bi[ch];
  float mr = (gr * wr + br) - (gi * wi + bi);
  float mi = (gi * wr + br) + (gr * wi + bi);
  float re = spec[idx * 2], im = spec[idx * 2 + 1];
  spec[idx * 2]     = re / (1.f + expf(-mr));
  spec[idx * 2 + 1] = im / (1.f + expf(-mi));
}

extern "C" void kernel_launch(void* const* d_in, const int* in_sizes, int n_in,
                              void* d_out, int out_size, void* d_ws, size_t ws_size,
                              hipStream_t stream) {
  const float* mix        = (const float*)d_in[0];
  const float* window     = (const float*)d_in[1];
  const float* c1wr       = (const float*)d_in[2];
  const float* c1br       = (const float*)d_in[3];
  const float* c1wi       = (const float*)d_in[4];
  const float* c1bi       = (const float*)d_in[5];
  const float* c2wr       = (const float*)d_in[6];
  const float* c2br       = (const float*)d_in[7];
  const float* c2wi       = (const float*)d_in[8];
  const float* c2bi       = (const float*)d_in[9];
  const float* attn_in_w  = (const float*)d_in[10];
  const float* attn_in_b  = (const float*)d_in[11];
  const float* attn_out_w = (const float*)d_in[12];
  const float* attn_out_b = (const float*)d_in[13];
  const float* l1wr       = (const float*)d_in[14];
  const float* l1br       = (const float*)d_in[15];
  const float* l1wi       = (const float*)d_in[16];
  const float* l1bi       = (const float*)d_in[17];
  const float* l2wr       = (const float*)d_in[18];
  const float* l2br       = (const float*)d_in[19];
  const float* l2wi       = (const float*)d_in[20];
  const float* l2bi       = (const float*)d_in[21];
  const float* n1_gr      = (const float*)d_in[22];
  const float* n1_br      = (const float*)d_in[23];
  const float* n1_gi      = (const float*)d_in[24];
  const float* n1_bi      = (const float*)d_in[25];
  const float* n2_gr      = (const float*)d_in[26];
  const float* n2_br      = (const float*)d_in[27];
  const float* n2_gi      = (const float*)d_in[28];
  const float* n2_bi      = (const float*)d_in[29];

  // ---- workspace layout, all constexpr. kNeed = 188,922,816 (proven safe).
  constexpr long eTokF = (long)kBS * kD;    // fp32 out-proj/FFN out
  constexpr long eAout = (long)kBS * kDP;
  constexpr long eXs   = (long)kBS * kDP;
  constexpr long eQKb  = (long)kBS * kHDP;
  constexpr long eWb   = (long)kHD * kDP;
  // FFN padded buffers:
  constexpr long eAb   = (long)kMP * kDP2;   // 3456x2080
  constexpr long eW1p  = (long)kW1R * kDP2;  // 4224x2080
  constexpr long eW2p  = (long)kW2R * kNHP;  // 2176x4128
  constexpr long eHidp = (long)kMP * kNHP;   // 3456x4128

  constexpr size_t oT    = 0;
  constexpr size_t oAout = oT + 2 * eTokF * 4;          //  56,547,200
  constexpr size_t oXs   = oAout + 2 * eAout * 2;       //  84,903,552
  constexpr size_t oD    = oXs + 4 * eXs * 2;           // 141,616,256
  constexpr size_t kNeed = 188922816;
  constexpr size_t oTW   = kNeed - 8192;                // 188,914,624
  constexpr size_t oP    = oT + 7 * eQKb * 2;           //  49,816,704
  static_assert(oP + 3 * kS2P * 2 <= oAout, "P overflow");
  constexpr size_t oV    = oD;
  constexpr size_t oK8   = oV + 2 * eQKb * 2;
  constexpr size_t oW    = oK8 + eQKb * 2;
  static_assert(oW + 5 * eWb * 2 <= oTW, "W overflow");
  constexpr size_t oSS   = oW;
  static_assert(oSS + 8 * kS2 * 4 <= oTW, "sS overflow");
  // FFN overlays (attention dead):
  constexpr size_t oAb   = oAout;                       //  56,547,200
  constexpr size_t oWF   = oAb + 2 * eAb * 2;           //  85,301,120
  constexpr size_t oHid  = oWF + 2 * eW2p * 2;          // 121,231,232 (W2 > W1)
  static_assert(2 * eW1p * 2 <= 2 * eW2p * 2, "W slot sized by W2");
  static_assert(oHid + 2 * eHidp * 2 <= oTW, "hid overflow");

  char* wsb = (char*)d_ws;
  if (ws_size < kNeed) return;  // fail signature: out0 all-zero (2.578125)

  float* xr    = (float*)(wsb + oT);       // fp32 out-proj/FFN (post-attn)
  float* xi    = xr + eTokF;
  bf16*  Qrh = (bf16*)(wsb + oT);          // attention-phase T overlay
  bf16*  Qrl = Qrh + eQKb;
  bf16*  Qih = Qrl + eQKb;
  bf16*  Qil = Qih + eQKb;
  bf16*  Krh = Qil + eQKb;
  bf16*  Krl = Krh + eQKb;
  bf16*  Kih = Krl + eQKb;
  bf16*  Kil = (bf16*)(wsb + oK8);
  bf16*  Pbuf = (bf16*)(wsb + oP);
  bf16*  aoutR = (bf16*)(wsb + oAout);
  bf16*  aoutI = aoutR + eAout;
  bf16*  Xrh = (bf16*)(wsb + oXs);
  bf16*  Xrl = Xrh + eXs;
  bf16*  Xih = Xrl + eXs;
  bf16*  Xil = Xih + eXs;
  bf16*  Vr = (bf16*)(wsb + oV);
  bf16*  Vi = Vr + eQKb;
  bf16*  Wqh = (bf16*)(wsb + oW);
  bf16*  Wql = Wqh + eWb;
  bf16*  Wkh = Wql + eWb;
  bf16*  Wkl = Wkh + eWb;
  bf16*  Wvh = Wkl + eWb;
  float* sS = (float*)(wsb + oSS);
  bf16*  Wob = (bf16*)(wsb + oV);          // out-proj W (V dead)
  // FFN pointers:
  bf16*  AbR = (bf16*)(wsb + oAb);
  bf16*  AbI = AbR + eAb;
  bf16*  w1rH = (bf16*)(wsb + oWF);
  bf16*  w1iH = w1rH + eW1p;
  bf16*  w2rH = (bf16*)(wsb + oWF);
  bf16*  w2iH = w2rH + eW2p;
  bf16*  hidR = (bf16*)(wsb + oHid);
  bf16*  hidI = hidR + eHidp;
  float* frames = (float*)(wsb + oAout);
  float2* tw = (float2*)(wsb + oTW);

  float* out0 = (float*)d_out;
  float* spec = out0 + (long)kNSIG * kL;

  auto cvt2 = [&](const float* src, bf16* dst, int dstRows, int ldd,
                  int srows, int scols, int lds) {
    long total = (long)dstRows * ldd;
    k_cvt2<<<(int)((total + 255) / 256), 256, 0, stream>>>(src, dst, total,
                                                           ldd, srows, scols,
                                                           lds);
  };
  auto cvt2s = [&](const float* src, bf16* dh, bf16* dl, int dstRows, int ldd,
                   int srows, int scols, int lds) {
    long total = (long)dstRows * ldd;
    k_cvt2s<<<(int)((total + 255) / 256), 256, 0, stream>>>(
        src, dh, dl, total, ldd, srows, scols, lds);
  };

  // 0) zero workspace, twiddle table
  hipMemsetAsync(d_ws, 0, kNeed, stream);
  k_twiddle<<<4, 256, 0, stream>>>(tw);

  // 1) STFT -> spec (out1)
  k_stft<<<dim3(kT, kNSIG), 256, 0, stream>>>(mix, window, tw, spec);

  // 2) conv1 + pos-enc -> split-bf16 tokens
  long nct = (long)kB * 2 * kBINS * kT;
  k_conv1_pe<<<(nct + 255) / 256, 256, 0, stream>>>(spec, c1wr, c1br, c1wi,
                                                    c1bi, Xrh, Xrl, Xih, Xil);

  // 3) attention, per head (unchanged — verified)
  for (int h = 0; h < 2; ++h) {
    const float* Wq = attn_in_w + (long)(h * kHD) * kD;
    const float* Wk = attn_in_w + (long)(kD + h * kHD) * kD;
    const float* Wv = attn_in_w + (long)(2 * kD + h * kHD) * kD;
    const float* bq = attn_in_b + h * kHD;
    const float* bk = attn_in_b + kD + h * kHD;
    const float* bv = attn_in_b + 2 * kD + h * kHD;
    cvt2s(Wq, Wqh, Wql, kHD, kDP, kHD, kD, kD);
    cvt2s(Wk, Wkh, Wkl, kHD, kDP, kHD, kD, kD);
    cvt2(Wv, Wvh, kHD, kDP, kHD, kD, kD);
    k_mfma2<bf16, bf16><<<dim3(9, 27), 256, 0, stream>>>(
        Xrh, Xih, Wvh, Vr, Vi, bv, 1.f, 1.f, kBS, kHD, kD, kDP, kDP, kHDP);
    k_mfma2s<<<dim3(9, 27), 256, 0, stream>>>(
        Xrh, Xrl, Xih, Xil, Wqh, Wql, Qrh, Qrl, Qih, Qil, bq,
        kBS, kHD, kD, kDP, kDP, kHDP);
    k_mfma2s<<<dim3(9, 27), 256, 0, stream>>>(
        Xrh, Xrl, Xih, Xil, Wkh, Wkl, Krh, Krl, Kih, Kil, bk,
        kBS, kHD, kD, kDP, kDP, kHDP);
    for (int bp = 0; bp < 2; ++bp) {
      k_qkt<<<dim3(7, 7, 4), 256, 0, stream>>>(Qrh, Qrl, Qih, Qil,
                                               Krh, Krl, Kih, Kil, sS, bp);
      for (int bl = 0; bl < 2; ++bl) {
        int b = bp * 2 + bl;
        k_smf<<<kT, 256, 0, stream>>>(sS + (long)bl * 4 * kS2, Pbuf);
        k_pv<<<dim3(9, 7), 256, 0, stream>>>(
            Pbuf, Vr + (long)b * kT * kHDP, Vi + (long)b * kT * kHDP,
            aoutR + (long)b * kT * kDP + h * kHD,
            aoutI + (long)b * kT * kDP + h * kHD,
            kT, kHD, kT, kTP, kHDP, kDP);
      }
    }
  }

  // 4) output projection -> fp32 xr, xi (T arena)
  cvt2(attn_out_w, Wob, kD, kDP, kD, kD, kD);
  k_mfma2<bf16, float><<<dim3(17, 27), 256, 0, stream>>>(
      aoutR, aoutI, Wob, xr, xi, attn_out_b, 0.f, 2.f,
      kBS, kD, kD, kDP, kDP, kD);

  // 5) LN1
  k_ln<<<kBS, 256, 0, stream>>>(xr, n1_gr, n1_br, kD);
  k_ln<<<kBS, 256, 0, stream>>>(xi, n1_gi, n1_bi, kD);

  // 6) FFN (complex-fused, full-M, N/K-halved, 2-phase glds pipeline)
  cvt2(xr, AbR, kMP, kDP2, kBS, kD, kD);
  cvt2(xi, AbI, kMP, kDP2, kBS, kD, kD);
  for (int nh = 0; nh < 2; ++nh) {
    int srows = (nh ? kDFF - kNH : kNH);   // 4096 : 4104
    // FFN1 half: hid = relu(complex(A @ W1[nh]^T) + bias)
    cvt2(l1wr + (long)nh * kNH * kD, w1rH, kW1R, kDP2, srows, kD, kD);
    cvt2(l1wi + (long)nh * kNH * kD, w1iH, kW1R, kDP2, srows, kD, kD);
    k_cgemm<bf16><<<dim3(33, 27), 256, 0, stream>>>(
        AbR, AbI, w1rH, w1iH, hidR, hidI,
        l1br + nh * kNH, l1bi + nh * kNH, 1.f, 0, 1, srows,
        kBS, kNHP, kDP2, kDP2, kDP2, kNHP);
    // FFN2 partial: x (+)= complex(hid @ W2[:, nh]^T) + bias (nh=0 only)
    cvt2(l2wr + nh * kNH, w2rH, kW2R, kNHP, kD, srows, kDFF);
    cvt2(l2wi + nh * kNH, w2iH, kW2R, kNHP, kD, srows, kDFF);
    k_cgemm<float><<<dim3(17, 27), 256, 0, stream>>>(
        hidR, hidI, w2rH, w2iH, xr, xi,
        l2br, l2bi, (nh == 0 ? 1.f : 0.f), nh, 0, kD,
        kBS, kD, kNHP, kNHP, kNHP, kD);
  }

  // 7) LN2
  k_ln<<<kBS, 256, 0, stream>>>(xr, n2_gr, n2_br, kD);
  k_ln<<<kBS, 256, 0, stream>>>(xi, n2_gi, n2_bi, kD);

  // 8) mask + gate spec in place
  k_mask<<<(nct + 255) / 256, 256, 0, stream>>>(xr, xi, c2wr, c2br, c2wi,
                                                c2bi, spec);

  // 9) iSTFT + overlap-add
  k_istft<<<dim3(kT, kNSIG), 256, 0, stream>>>(spec, window, tw, frames);
  k_gather<<<(int)(((long)kNSIG * kL + 255) / 256), 256, 0, stream>>>(
      frames, window, out0);
}

// Round 14
// 5623.362 us; speedup vs baseline: 4.0215x; 1.1861x over previous
//
#include <hip/hip_runtime.h>
#include <hip/hip_bf16.h>
#include <math.h>

#ifndef M_PIf
#define M_PIf 3.14159265358979323846f
#endif

static constexpr int kNFFT = 2048;
static constexpr int kHOP  = 512;
static constexpr int kBINS = 1025;
static constexpr int kT    = 862;
static constexpr int kL    = 441000;
static constexpr int kB    = 4;
static constexpr int kNSIG = 8;
static constexpr int kD    = 2050;
static constexpr int kHD   = 1025;
static constexpr int kDFF  = 8200;
static constexpr int kBS   = kB * kT;   // 3448
static constexpr float kAttnScale = 0.031234752377721214f; // 1/sqrt(1025)
static constexpr long kS2  = (long)kT * kT;    // 743,044
static constexpr int kTP   = 864;
static constexpr long kS2P = (long)kT * kTP;   // 744,768
static constexpr int kDP   = 2056;   // aout row stride (16B aligned)
static constexpr int kHDP  = 1032;   // V row stride
static constexpr int kHDP2 = 1056;   // Q/K row stride (32-mult, glds)
static constexpr int kQKr  = 3488;   // Q/K rows (covers 3*862+895)
static constexpr int kWr   = 1152;   // W rows (9 blocks x 128)
static constexpr int kNH   = 4104;   // FFN N/K half
static constexpr int kDP2  = 2080;   // K padded to 32-mult
static constexpr int kNHP  = 4128;
static constexpr int kMP   = 3456;   // M padded (27 blocks)
static constexpr int kW1R  = 4224;
static constexpr int kW2R  = 2176;

using bf16 = __hip_bfloat16;
typedef __attribute__((ext_vector_type(4))) float f32x4;
typedef __attribute__((ext_vector_type(8))) short bf16x8;

__device__ __forceinline__ float ldf(const float* p, long i) { return p[i]; }
__device__ __forceinline__ float ldf(const bf16* p, long i) {
  return __bfloat162float(p[i]);
}
__device__ __forceinline__ void sto(float* p, long i, float v) { p[i] = v; }
__device__ __forceinline__ void sto(bf16* p, long i, float v) {
  p[i] = __float2bfloat16(v);
}
__device__ __forceinline__ void load16(const float* src, bf16* dst) {
#pragma unroll
  for (int e = 0; e < 16; ++e) dst[e] = __float2bfloat16(src[e]);
}
__device__ __forceinline__ void load16(const bf16* src, bf16* dst) {
  *(bf16x8*)(dst)     = *(const bf16x8*)(src);
  *(bf16x8*)(dst + 8) = *(const bf16x8*)(src + 8);
}

// Direct global->LDS 16B async copy (wave-uniform LDS base, per-lane src).
__device__ __forceinline__ void glds16(const bf16* g, bf16* l) {
  __builtin_amdgcn_global_load_lds(
      (const __attribute__((address_space(1))) unsigned int*)g,
      (__attribute__((address_space(3))) unsigned int*)l, 16, 0, 0);
}

// Bijective XCD-aware block swizzle (m204).
__device__ __forceinline__ void xcd_swizzle(int& bx, int& by) {
  int nwg = gridDim.x * gridDim.y;
  int orig = by * gridDim.x + bx;
  int qq = nwg >> 3, rr = nwg & 7;
  int xcd = orig & 7, loc = orig >> 3;
  int wg = (xcd < rr ? xcd * (qq + 1) : rr * (qq + 1) + (xcd - rr) * qq) + loc;
  bx = wg % gridDim.x;
  by = wg / gridDim.x;
}

// Register-path staging of one 16-elem bf16 chunk into an LDS row.
template <typename T>
__device__ __forceinline__ void stage_row16(const T* S, int grow, int glim,
                                            int lda, int k0sk, int K,
                                            bf16* dst) {
  bf16 tmp[16];
  if (grow < glim && k0sk + 16 <= K) {
    load16(S + (long)grow * lda + k0sk, tmp);
  } else {
#pragma unroll
    for (int e = 0; e < 16; ++e) {
      int gk = k0sk + e;
      tmp[e] = __float2bfloat16(
          (grow < glim && gk < K) ? ldf(S, (long)grow * lda + gk) : 0.f);
    }
  }
  *(bf16x8*)(dst)     = *(bf16x8*)&tmp[0];
  *(bf16x8*)(dst + 8) = *(bf16x8*)&tmp[8];
}

// ---------------------------------------------------------------------------
__global__ void k_twiddle(float2* __restrict__ tw) {
  int m = blockIdx.x * 256 + threadIdx.x;
  if (m < 1024) {
    float s, c;
    sincosf(M_PIf * (float)m / 1024.f, &s, &c);
    tw[m] = make_float2(c, s);
  }
}

__device__ __forceinline__ void fft2048_lds(float*& sr, float*& si,
                                            float* dr, float* di, int tid,
                                            float dir,
                                            const float2* __restrict__ tw) {
  int s = 0;
  for (int Ns = 1; Ns < 2048; Ns <<= 1, ++s) {
#pragma unroll
    for (int q = 0; q < 4; ++q) {
      int j = tid + q * 256;
      int base = j & (Ns - 1);
      int grp = j >> s;
      float2 t = tw[base << (10 - s)];
      float c = t.x, sn = dir * t.y;
      float ar = sr[j],        ai = si[j];
      float br = sr[j + 1024], bi = si[j + 1024];
      float tbr = br * c - bi * sn;
      float tbi = br * sn + bi * c;
      int o = (grp << (s + 1)) + base;
      dr[o]      = ar + tbr;  di[o]      = ai + tbi;
      dr[o + Ns] = ar - tbr;  di[o + Ns] = ai - tbi;
    }
    __syncthreads();
    float* t0 = sr; sr = dr; dr = t0;
    float* t1 = si; si = di; di = t1;
  }
}

__global__ __launch_bounds__(256) void k_stft(const float* __restrict__ mix,
                                              const float* __restrict__ win,
                                              const float2* __restrict__ tw,
                                              float* __restrict__ spec) {
  __shared__ float b0r[2048], b0i[2048], b1r[2048], b1i[2048];
  int t = blockIdx.x, sig = blockIdx.y, tid = threadIdx.x;
  const float* x = mix + (long)sig * kL;
  for (int i = tid; i < 2048; i += 256) {
    int src = t * kHOP + i - 1024;
    if (src < 0) src = -src;
    if (src >= kL) src = 2 * kL - 2 - src;
    b0r[i] = x[src] * win[i];
    b0i[i] = 0.f;
  }
  __syncthreads();
  float* sr = b0r; float* si = b0i;
  fft2048_lds(sr, si, b1r, b1i, tid, -1.f, tw);
  for (int k = tid; k < kBINS; k += 256) {
    long o = ((long)sig * kBINS + k) * kT + t;
    spec[o * 2]     = sr[k];
    spec[o * 2 + 1] = si[k];
  }
}

__global__ __launch_bounds__(256) void k_istft(const float* __restrict__ spec,
                                               const float* __restrict__ win,
                                               const float2* __restrict__ tw,
                                               float* __restrict__ frames) {
  __shared__ float b0r[2048], b0i[2048], b1r[2048], b1i[2048];
  int t = blockIdx.x, sig = blockIdx.y, tid = threadIdx.x;
  for (int k = tid; k < kBINS; k += 256) {
    long o = ((long)sig * kBINS + k) * kT + t;
    b0r[k] = spec[o * 2];
    b0i[k] = spec[o * 2 + 1];
  }
  __syncthreads();
  for (int k = 1025 + tid; k < 2048; k += 256) {
    b0r[k] = b0r[2048 - k];
    b0i[k] = -b0i[2048 - k];
  }
  __syncthreads();
  float* sr = b0r; float* si = b0i;
  fft2048_lds(sr, si, b1r, b1i, tid, +1.f, tw);
  const float scale = 1.f / 2048.f;
  float* fo = frames + ((long)sig * kT + t) * 2048;
  for (int n = tid; n < 2048; n += 256) fo[n] = sr[n] * scale * win[n];
}

__global__ void k_gather(const float* __restrict__ frames,
                         const float* __restrict__ win,
                         float* __restrict__ out0) {
  long idx = (long)blockIdx.x * 256 + threadIdx.x;
  long total = (long)kNSIG * kL;
  if (idx >= total) return;
  int sig = (int)(idx / kL);
  int l = (int)(idx % kL);
  int j = l + 1024;
  int tmax = j >> 9; if (tmax > kT - 1) tmax = kT - 1;
  int v = j - 1536;
  int tmin = v > 0 ? (v >> 9) : 0;
  float acc = 0.f, w2 = 0.f;
  for (int t = tmin; t <= tmax; ++t) {
    int n = j - (t << 9);
    float w = win[n];
    acc += frames[((long)sig * kT + t) * 2048 + n];
    w2 = fmaf(w, w, w2);
  }
  out0[idx] = acc / (w2 > 1e-11f ? w2 : 1.f);
}

// conv1x1 + pos-enc -> bf16 hi/lo split tokens (row stride kDP2).
__global__ void k_conv1_pe(const float* __restrict__ spec,
                           const float* __restrict__ c1wr, const float* __restrict__ c1br,
                           const float* __restrict__ c1wi, const float* __restrict__ c1bi,
                           bf16* __restrict__ xrh, bf16* __restrict__ xrl,
                           bf16* __restrict__ xih, bf16* __restrict__ xil) {
  long idx = (long)blockIdx.x * 256 + threadIdx.x;
  long total = (long)kB * 2 * kBINS * kT;
  if (idx >= total) return;
  int t = (int)(idx % kT);
  long r0 = idx / kT;
  int bin = (int)(r0 % kBINS);
  long r1 = r0 / kBINS;
  int ch = (int)(r1 % 2);
  int b = (int)(r1 / 2);
  float re = spec[idx * 2], im = spec[idx * 2 + 1];
  float wr = c1wr[ch], br = c1br[ch], wi = c1wi[ch], bi = c1bi[ch];
  float nr = (re * wr + br) - (im * wi + bi);
  float ni = (im * wr + br) + (re * wi + bi);
  int d = bin * 2 + ch;
  int k = d >> 1;
  float dv = expf((float)k * (-9.210340371976184f / 1025.0f));
  float arg = (float)t * dv;
  float pe = (d & 1) ? cosf(arg) : sinf(arg);
  long ro = ((long)(b * kT + t)) * kDP2 + d;
  float vr = nr + pe, vi = ni + pe;
  bf16 hr = __float2bfloat16(vr);
  bf16 hi = __float2bfloat16(vi);
  xrh[ro] = hr; xrl[ro] = __float2bfloat16(vr - __bfloat162float(hr));
  xih[ro] = hi; xil[ro] = __float2bfloat16(vi - __bfloat162float(hi));
}

// fp32 -> bf16 convert, zero-fill outside (srows x scols).
__global__ void k_cvt2(const float* __restrict__ src, bf16* __restrict__ dst,
                       long total, int ldd, int srows, int scols, int lds) {
  long idx = (long)blockIdx.x * 256 + threadIdx.x;
  if (idx >= total) return;
  int r = (int)(idx / ldd), c = (int)(idx % ldd);
  float v = (r < srows && c < scols) ? src[(long)r * lds + c] : 0.f;
  dst[idx] = __float2bfloat16(v);
}

// fp32 -> split bf16 (hi + lo), zero-fill outside.
__global__ void k_cvt2s(const float* __restrict__ src, bf16* __restrict__ dh,
                        bf16* __restrict__ dl, long total, int ldd, int srows,
                        int scols, int lds) {
  long idx = (long)blockIdx.x * 256 + threadIdx.x;
  if (idx >= total) return;
  int r = (int)(idx / ldd), c = (int)(idx % ldd);
  float v = (r < srows && c < scols) ? src[(long)r * lds + c] : 0.f;
  bf16 h = __float2bfloat16(v);
  dh[idx] = h;
  dl[idx] = __float2bfloat16(v - __bfloat162float(h));
}

// ---------------------------------------------------------------------------
// MFMA, 2 A's sharing one B (register staging; V-proj / out-proj).
// ---------------------------------------------------------------------------
template <typename TA, typename TC>
__global__ __launch_bounds__(256) void k_mfma2(
    const TA* __restrict__ A1, const TA* __restrict__ A2,
    const bf16* __restrict__ B, TC* __restrict__ C1, TC* __restrict__ C2,
    const float* __restrict__ bias, float bs1, float bs2,
    int M, int N, int K, int lda, int ldb, int ldc) {
  __shared__ __align__(16) bf16 As1[128][40];
  __shared__ __align__(16) bf16 As2[128][40];
  __shared__ __align__(16) bf16 Bs[128][40];
  int tid = threadIdx.x;
  int bm = blockIdx.y * 128, bn = blockIdx.x * 128;
  int lane = tid & 63, w = tid >> 6;
  int wr = (w >> 1) * 64, wc = (w & 1) * 64;
  int fr = lane & 15, fq = lane >> 4;
  f32x4 ac1[4][4] = {}, ac2[4][4] = {};
  int sr = tid >> 1, sk = (tid & 1) * 16;
  for (int k0 = 0; k0 < K; k0 += 32) {
    stage_row16(A1, bm + sr, M, lda, k0 + sk, K, &As1[sr][sk]);
    stage_row16(A2, bm + sr, M, lda, k0 + sk, K, &As2[sr][sk]);
    stage_row16(B,  bn + sr, N, ldb, k0 + sk, K, &Bs[sr][sk]);
    __syncthreads();
    bf16x8 a1[4], a2[4], b[4];
#pragma unroll
    for (int i = 0; i < 4; ++i) {
      a1[i] = *(const bf16x8*)&As1[wr + i * 16 + fr][fq * 8];
      a2[i] = *(const bf16x8*)&As2[wr + i * 16 + fr][fq * 8];
      b[i]  = *(const bf16x8*)&Bs[wc + i * 16 + fr][fq * 8];
    }
#pragma unroll
    for (int i = 0; i < 4; ++i)
#pragma unroll
      for (int j = 0; j < 4; ++j) {
        ac1[i][j] = __builtin_amdgcn_mfma_f32_16x16x32_bf16(a1[i], b[j], ac1[i][j], 0, 0, 0);
        ac2[i][j] = __builtin_amdgcn_mfma_f32_16x16x32_bf16(a2[i], b[j], ac2[i][j], 0, 0, 0);
      }
    __syncthreads();
  }
#pragma unroll
  for (int i = 0; i < 4; ++i)
#pragma unroll
    for (int j = 0; j < 4; ++j) {
      int gn = bn + wc + j * 16 + fr;
      if (gn >= N) continue;
      float bv = bias ? bias[gn] : 0.f;
#pragma unroll
      for (int r = 0; r < 4; ++r) {
        int gm = bm + wr + i * 16 + fq * 4 + r;
        if (gm >= M) continue;
        long co = (long)gm * ldc + gn;
        sto(C1, co, ac1[i][j][r] + bs1 * bv);
        sto(C2, co, ac2[i][j][r] + bs2 * bv);
      }
    }
}

// ---------------------------------------------------------------------------
// Split-precision projection, glds 2-phase + XCD swizzle.
// C = (Ah+Al)@(Bh+Bl)^T + bias (3 products), output re-split hi/lo.
// Requirements: unpredicated glds -> A rows >= grid*128, B rows >= grid*128,
// lda/ldb == K (32-mult, zero-padded). Writes guarded by M/N.
// ---------------------------------------------------------------------------
__global__ __launch_bounds__(256) void k_gemm3s(
    const bf16* __restrict__ Ah, const bf16* __restrict__ Al,
    const bf16* __restrict__ Bh, const bf16* __restrict__ Bl,
    bf16* __restrict__ Ch, bf16* __restrict__ Cl,
    const float* __restrict__ bias,
    int M, int N, int K, int lda, int ldb, int ldc) {
  __shared__ __align__(16) bf16 Sah[2][128][32];
  __shared__ __align__(16) bf16 Sal[2][128][32];
  __shared__ __align__(16) bf16 Sbh[2][128][32];
  __shared__ __align__(16) bf16 Sbl[2][128][32];
  int bx = blockIdx.x, by = blockIdx.y;
  xcd_swizzle(bx, by);
  int bm = by * 128, bn = bx * 128;
  int tid = threadIdx.x;
  int lane = tid & 63, w = tid >> 6;
  int wr = (w >> 1) * 64, wc = (w & 1) * 64;
  int fr = lane & 15, fq = lane >> 4;
  f32x4 acc[4][4] = {};
  int srow = w * 32 + (lane >> 2);
  int scol = (lane & 3) * 8;
  const bf16* pAh[2]; const bf16* pAl[2];
  const bf16* pBh[2]; const bf16* pBl[2];
#pragma unroll
  for (int c = 0; c < 2; ++c) {
    long ga = (long)(bm + srow + c * 16) * lda + scol;
    long gb = (long)(bn + srow + c * 16) * ldb + scol;
    pAh[c] = Ah + ga; pAl[c] = Al + ga;
    pBh[c] = Bh + gb; pBl[c] = Bl + gb;
  }
#pragma unroll
  for (int c = 0; c < 2; ++c) {
    int lb = w * 1024 + c * 512;
    glds16(pAh[c], &Sah[0][0][0] + lb);
    glds16(pAl[c], &Sal[0][0][0] + lb);
    glds16(pBh[c], &Sbh[0][0][0] + lb);
    glds16(pBl[c], &Sbl[0][0][0] + lb);
  }
  __syncthreads();
  int nt = K >> 5;
  long koff = 32;
  for (int t = 0; t < nt; ++t) {
    int p = t & 1;
    if (t + 1 < nt) {
      int pb = (p ^ 1) * 4096;
#pragma unroll
      for (int c = 0; c < 2; ++c) {
        int lb = pb + w * 1024 + c * 512;
        glds16(pAh[c] + koff, &Sah[0][0][0] + lb);
        glds16(pAl[c] + koff, &Sal[0][0][0] + lb);
        glds16(pBh[c] + koff, &Sbh[0][0][0] + lb);
        glds16(pBl[c] + koff, &Sbl[0][0][0] + lb);
      }
      koff += 32;
    }
    bf16x8 ah[4], al[4], bh[4], bl[4];
#pragma unroll
    for (int i = 0; i < 4; ++i) {
      ah[i] = *(const bf16x8*)&Sah[p][wr + i * 16 + fr][fq * 8];
      al[i] = *(const bf16x8*)&Sal[p][wr + i * 16 + fr][fq * 8];
      bh[i] = *(const bf16x8*)&Sbh[p][wc + i * 16 + fr][fq * 8];
      bl[i] = *(const bf16x8*)&Sbl[p][wc + i * 16 + fr][fq * 8];
    }
#pragma unroll
    for (int i = 0; i < 4; ++i)
#pragma unroll
      for (int j = 0; j < 4; ++j) {
        acc[i][j] = __builtin_amdgcn_mfma_f32_16x16x32_bf16(ah[i], bh[j], acc[i][j], 0, 0, 0);
        acc[i][j] = __builtin_amdgcn_mfma_f32_16x16x32_bf16(ah[i], bl[j], acc[i][j], 0, 0, 0);
        acc[i][j] = __builtin_amdgcn_mfma_f32_16x16x32_bf16(al[i], bh[j], acc[i][j], 0, 0, 0);
      }
    __syncthreads();
  }
#pragma unroll
  for (int i = 0; i < 4; ++i)
#pragma unroll
    for (int j = 0; j < 4; ++j) {
      int gn = bn + wc + j * 16 + fr;
      if (gn >= N) continue;
      float bv = bias[gn];
#pragma unroll
      for (int r = 0; r < 4; ++r) {
        int gm = bm + wr + i * 16 + fq * 4 + r;
        if (gm >= M) continue;
        long co = (long)gm * ldc + gn;
        float v = acc[i][j][r] + bv;
        bf16 h = __float2bfloat16(v);
        Ch[co] = h;
        Cl[co] = __float2bfloat16(v - __bfloat162float(h));
      }
    }
}

// ---------------------------------------------------------------------------
// Split-precision QK^T, glds 2-phase. z = bl*4 + combo (combo: qsel*2+ksel).
// S slot (bl*4+combo). Per-batch row offset b*862 within 3488-row buffers;
// over-reads hit other batches / zero pad -> only write-guarded outputs.
// ---------------------------------------------------------------------------
__global__ __launch_bounds__(256) void k_qkt3(
    const bf16* __restrict__ Qrh, const bf16* __restrict__ Qrl,
    const bf16* __restrict__ Qih, const bf16* __restrict__ Qil,
    const bf16* __restrict__ Krh, const bf16* __restrict__ Krl,
    const bf16* __restrict__ Kih, const bf16* __restrict__ Kil,
    float* __restrict__ S, int bp) {
  __shared__ __align__(16) bf16 Sqh[2][128][32];
  __shared__ __align__(16) bf16 Sql[2][128][32];
  __shared__ __align__(16) bf16 Skh[2][128][32];
  __shared__ __align__(16) bf16 Skl[2][128][32];
  int bl = blockIdx.z >> 2, c = blockIdx.z & 3;
  int b = bp * 2 + bl;
  long roff = (long)b * kT * kHDP2;
  const bf16* qh = ((c >> 1) ? Qih : Qrh) + roff;
  const bf16* ql = ((c >> 1) ? Qil : Qrl) + roff;
  const bf16* kh = ((c & 1) ? Kih : Krh) + roff;
  const bf16* kl = ((c & 1) ? Kil : Krl) + roff;
  float* So = S + ((long)bl * 4 + c) * kS2;
  int bx = blockIdx.x, by = blockIdx.y;
  xcd_swizzle(bx, by);
  int bm = by * 128, bn = bx * 128;
  int tid = threadIdx.x;
  int lane = tid & 63, w = tid >> 6;
  int wr = (w >> 1) * 64, wc = (w & 1) * 64;
  int fr = lane & 15, fq = lane >> 4;
  f32x4 acc[4][4] = {};
  int srow = w * 32 + (lane >> 2);
  int scol = (lane & 3) * 8;
  const bf16* pQh[2]; const bf16* pQl[2];
  const bf16* pKh[2]; const bf16* pKl[2];
#pragma unroll
  for (int cc = 0; cc < 2; ++cc) {
    long ga = (long)(bm + srow + cc * 16) * kHDP2 + scol;
    long gb = (long)(bn + srow + cc * 16) * kHDP2 + scol;
    pQh[cc] = qh + ga; pQl[cc] = ql + ga;
    pKh[cc] = kh + gb; pKl[cc] = kl + gb;
  }
#pragma unroll
  for (int cc = 0; cc < 2; ++cc) {
    int lb = w * 1024 + cc * 512;
    glds16(pQh[cc], &Sqh[0][0][0] + lb);
    glds16(pQl[cc], &Sql[0][0][0] + lb);
    glds16(pKh[cc], &Skh[0][0][0] + lb);
    glds16(pKl[cc], &Skl[0][0][0] + lb);
  }
  __syncthreads();
  int nt = kHDP2 >> 5;
  long koff = 32;
  for (int t = 0; t < nt; ++t) {
    int p = t & 1;
    if (t + 1 < nt) {
      int pb = (p ^ 1) * 4096;
#pragma unroll
      for (int cc = 0; cc < 2; ++cc) {
        int lb = pb + w * 1024 + cc * 512;
        glds16(pQh[cc] + koff, &Sqh[0][0][0] + lb);
        glds16(pQl[cc] + koff, &Sql[0][0][0] + lb);
        glds16(pKh[cc] + koff, &Skh[0][0][0] + lb);
        glds16(pKl[cc] + koff, &Skl[0][0][0] + lb);
      }
      koff += 32;
    }
    bf16x8 ah[4], al[4], bh[4], blv[4];
#pragma unroll
    for (int i = 0; i < 4; ++i) {
      ah[i]  = *(const bf16x8*)&Sqh[p][wr + i * 16 + fr][fq * 8];
      al[i]  = *(const bf16x8*)&Sql[p][wr + i * 16 + fr][fq * 8];
      bh[i]  = *(const bf16x8*)&Skh[p][wc + i * 16 + fr][fq * 8];
      blv[i] = *(const bf16x8*)&Skl[p][wc + i * 16 + fr][fq * 8];
    }
#pragma unroll
    for (int i = 0; i < 4; ++i)
#pragma unroll
      for (int j = 0; j < 4; ++j) {
        acc[i][j] = __builtin_amdgcn_mfma_f32_16x16x32_bf16(ah[i], bh[j],  acc[i][j], 0, 0, 0);
        acc[i][j] = __builtin_amdgcn_mfma_f32_16x16x32_bf16(ah[i], blv[j], acc[i][j], 0, 0, 0);
        acc[i][j] = __builtin_amdgcn_mfma_f32_16x16x32_bf16(al[i], bh[j],  acc[i][j], 0, 0, 0);
      }
    __syncthreads();
  }
#pragma unroll
  for (int i = 0; i < 4; ++i)
#pragma unroll
    for (int j = 0; j < 4; ++j) {
      int gn = bn + wc + j * 16 + fr;
      if (gn >= kT) continue;
#pragma unroll
      for (int r = 0; r < 4; ++r) {
        int gm = bm + wr + i * 16 + fq * 4 + r;
        if (gm >= kT) continue;
        So[(long)gm * kT + gn] = acc[i][j][r];
      }
    }
}

// ---------------------------------------------------------------------------
// Complex-fused MFMA GEMM (FFN): 2-phase glds pipeline + XCD swizzle.
// ---------------------------------------------------------------------------
template <typename TC>
__global__ __launch_bounds__(256) void k_cgemm(
    const bf16* __restrict__ Ar, const bf16* __restrict__ Ai,
    const bf16* __restrict__ Br, const bf16* __restrict__ Bi,
    TC* __restrict__ Cr, TC* __restrict__ Ci,
    const float* __restrict__ biasR, const float* __restrict__ biasI,
    float bscale, int accum, int relu, int Nreal,
    int M, int N, int K, int lda, int ldb, int ldc) {
  __shared__ __align__(16) bf16 Asr[2][128][32];
  __shared__ __align__(16) bf16 Asi[2][128][32];
  __shared__ __align__(16) bf16 Bsr[2][128][32];
  __shared__ __align__(16) bf16 Bsi[2][128][32];
  int bx = blockIdx.x, by = blockIdx.y;
  xcd_swizzle(bx, by);
  int bm = by * 128, bn = bx * 128;
  int tid = threadIdx.x;
  int lane = tid & 63, w = tid >> 6;
  int wr = (w >> 1) * 64, wc = (w & 1) * 64;
  int fr = lane & 15, fq = lane >> 4;
  f32x4 acR[4][4] = {}, acI[4][4] = {};
  int srow = w * 32 + (lane >> 2);
  int scol = (lane & 3) * 8;
  const bf16* pA[2][2];
  const bf16* pB[2][2];
#pragma unroll
  for (int c = 0; c < 2; ++c) {
    long ga = (long)(bm + srow + c * 16) * lda + scol;
    long gb = (long)(bn + srow + c * 16) * ldb + scol;
    pA[0][c] = Ar + ga; pA[1][c] = Ai + ga;
    pB[0][c] = Br + gb; pB[1][c] = Bi + gb;
  }
#pragma unroll
  for (int c = 0; c < 2; ++c) {
    int lb = w * 1024 + c * 512;
    glds16(pA[0][c], &Asr[0][0][0] + lb);
    glds16(pA[1][c], &Asi[0][0][0] + lb);
    glds16(pB[0][c], &Bsr[0][0][0] + lb);
    glds16(pB[1][c], &Bsi[0][0][0] + lb);
  }
  __syncthreads();
  const short ks = (short)0x8000;
  const bf16x8 sgn = {ks, ks, ks, ks, ks, ks, ks, ks};
  int nt = K >> 5;
  long koff = 32;
  for (int t = 0; t < nt; ++t) {
    int p = t & 1;
    if (t + 1 < nt) {
      int pb = (p ^ 1) * 4096;
#pragma unroll
      for (int c = 0; c < 2; ++c) {
        int lb = pb + w * 1024 + c * 512;
        glds16(pA[0][c] + koff, &Asr[0][0][0] + lb);
        glds16(pA[1][c] + koff, &Asi[0][0][0] + lb);
        glds16(pB[0][c] + koff, &Bsr[0][0][0] + lb);
        glds16(pB[1][c] + koff, &Bsi[0][0][0] + lb);
      }
      koff += 32;
    }
    bf16x8 ar[4], ai[4], nai[4], br[4], bi[4];
#pragma unroll
    for (int i = 0; i < 4; ++i) {
      ar[i] = *(const bf16x8*)&Asr[p][wr + i * 16 + fr][fq * 8];
      ai[i] = *(const bf16x8*)&Asi[p][wr + i * 16 + fr][fq * 8];
      nai[i] = ai[i] ^ sgn;
      br[i] = *(const bf16x8*)&Bsr[p][wc + i * 16 + fr][fq * 8];
      bi[i] = *(const bf16x8*)&Bsi[p][wc + i * 16 + fr][fq * 8];
    }
#pragma unroll
    for (int i = 0; i < 4; ++i)
#pragma unroll
      for (int j = 0; j < 4; ++j) {
        acR[i][j] = __builtin_amdgcn_mfma_f32_16x16x32_bf16(ar[i],  br[j], acR[i][j], 0, 0, 0);
        acR[i][j] = __builtin_amdgcn_mfma_f32_16x16x32_bf16(nai[i], bi[j], acR[i][j], 0, 0, 0);
        acI[i][j] = __builtin_amdgcn_mfma_f32_16x16x32_bf16(ai[i],  br[j], acI[i][j], 0, 0, 0);
        acI[i][j] = __builtin_amdgcn_mfma_f32_16x16x32_bf16(ar[i],  bi[j], acI[i][j], 0, 0, 0);
      }
    __syncthreads();
  }
#pragma unroll
  for (int i = 0; i < 4; ++i)
#pragma unroll
    for (int j = 0; j < 4; ++j) {
      int gn = bn + wc + j * 16 + fr;
      if (gn >= N) continue;
      float br_ = 0.f, bi_ = 0.f;
      if (gn < Nreal) { br_ = biasR[gn]; bi_ = biasI[gn]; }
#pragma unroll
      for (int r = 0; r < 4; ++r) {
        int gm = bm + wr + i * 16 + fq * 4 + r;
        if (gm >= M) continue;
        long co = (long)gm * ldc + gn;
        float vR = acR[i][j][r] + bscale * (br_ - bi_);
        float vI = acI[i][j][r] + bscale * (br_ + bi_);
        if (accum) { vR += ldf(Cr, co); vI += ldf(Ci, co); }
        if (relu) { vR = fmaxf(vR, 0.f); vI = fmaxf(vI, 0.f); }
        sto(Cr, co, vR);
        sto(Ci, co, vI);
      }
    }
}

// ---------------------------------------------------------------------------
// Fused PV: Cr = P0@Vr + P2@Vi ; Ci = P0@Vi + P1@Vr. B is KxN (register path).
// ---------------------------------------------------------------------------
__global__ __launch_bounds__(256) void k_pv(
    const bf16* __restrict__ P, const bf16* __restrict__ Vr,
    const bf16* __restrict__ Vi, bf16* __restrict__ Cr,
    bf16* __restrict__ Ci, int M, int N, int K, int ldp, int ldv, int ldc) {
  __shared__ __align__(16) bf16 Ps0[128][40];
  __shared__ __align__(16) bf16 Ps1[128][40];
  __shared__ __align__(16) bf16 Ps2[128][40];
  __shared__ __align__(16) bf16 Vsr[128][40];
  __shared__ __align__(16) bf16 Vsi[128][40];
  int tid = threadIdx.x;
  int bm = blockIdx.y * 128, bn = blockIdx.x * 128;
  int lane = tid & 63, w = tid >> 6;
  int wr = (w >> 1) * 64, wc = (w & 1) * 64;
  int fr = lane & 15, fq = lane >> 4;
  f32x4 acR[4][4] = {}, acI[4][4] = {};
  int sr = tid >> 1, sk = (tid & 1) * 16;
  int kk = tid >> 3, nq = (tid & 7) * 16;
  for (int k0 = 0; k0 < K; k0 += 32) {
    stage_row16(P,            bm + sr, M, ldp, k0 + sk, K, &Ps0[sr][sk]);
    stage_row16(P + kS2P,     bm + sr, M, ldp, k0 + sk, K, &Ps1[sr][sk]);
    stage_row16(P + 2 * kS2P, bm + sr, M, ldp, k0 + sk, K, &Ps2[sr][sk]);
    {
      int gk = k0 + kk;
      bf16 t0[16], t1[16];
      if (gk < K && bn + nq + 16 <= N) {
        load16(Vr + (long)gk * ldv + bn + nq, t0);
        load16(Vi + (long)gk * ldv + bn + nq, t1);
      } else {
#pragma unroll
        for (int e = 0; e < 16; ++e) {
          int gn = bn + nq + e;
          bool ok = (gk < K && gn < N);
          t0[e] = __float2bfloat16(ok ? ldf(Vr, (long)gk * ldv + gn) : 0.f);
          t1[e] = __float2bfloat16(ok ? ldf(Vi, (long)gk * ldv + gn) : 0.f);
        }
      }
#pragma unroll
      for (int e = 0; e < 16; ++e) {
        Vsr[nq + e][kk] = t0[e];
        Vsi[nq + e][kk] = t1[e];
      }
    }
    __syncthreads();
    bf16x8 p0[4], p1[4], p2[4], vr[4], vi[4];
#pragma unroll
    for (int i = 0; i < 4; ++i) {
      p0[i] = *(const bf16x8*)&Ps0[wr + i * 16 + fr][fq * 8];
      p1[i] = *(const bf16x8*)&Ps1[wr + i * 16 + fr][fq * 8];
      p2[i] = *(const bf16x8*)&Ps2[wr + i * 16 + fr][fq * 8];
      vr[i] = *(const bf16x8*)&Vsr[wc + i * 16 + fr][fq * 8];
      vi[i] = *(const bf16x8*)&Vsi[wc + i * 16 + fr][fq * 8];
    }
#pragma unroll
    for (int i = 0; i < 4; ++i)
#pragma unroll
      for (int j = 0; j < 4; ++j) {
        acR[i][j] = __builtin_amdgcn_mfma_f32_16x16x32_bf16(p0[i], vr[j], acR[i][j], 0, 0, 0);
        acR[i][j] = __builtin_amdgcn_mfma_f32_16x16x32_bf16(p2[i], vi[j], acR[i][j], 0, 0, 0);
        acI[i][j] = __builtin_amdgcn_mfma_f32_16x16x32_bf16(p0[i], vi[j], acI[i][j], 0, 0, 0);
        acI[i][j] = __builtin_amdgcn_mfma_f32_16x16x32_bf16(p1[i], vr[j], acI[i][j], 0, 0, 0);
      }
    __syncthreads();
  }
#pragma unroll
  for (int i = 0; i < 4; ++i)
#pragma unroll
    for (int j = 0; j < 4; ++j) {
      int gn = bn + wc + j * 16 + fr;
      if (gn >= N) continue;
#pragma unroll
      for (int r = 0; r < 4; ++r) {
        int gm = bm + wr + i * 16 + fq * 4 + r;
        if (gm >= M) continue;
        long co = (long)gm * ldc + gn;
        Cr[co] = __float2bfloat16(acR[i][j][r]);
        Ci[co] = __float2bfloat16(acI[i][j][r]);
      }
    }
}

// Fused softmax over 4 fp32 score mats + fold to 3 bf16 P mats (stride kS2P).
__global__ __launch_bounds__(256) void k_smf(const float* __restrict__ S,
                                             bf16* __restrict__ P) {
  long rbase = (long)blockIdx.x * kT;
  long pbase = (long)blockIdx.x * kTP;
  int tid = threadIdx.x;
  int lane = tid & 63, w = tid >> 6;
  float v[4][4];
  float mx[4] = {-3.4e38f, -3.4e38f, -3.4e38f, -3.4e38f};
#pragma unroll
  for (int c = 0; c < 4; ++c) {
    const float* row = S + c * kS2 + rbase;
#pragma unroll
    for (int q = 0; q < 4; ++q) {
      int i = tid + q * 256;
      v[c][q] = (i < kT) ? row[i] : -3.4e38f;
      mx[c] = fmaxf(mx[c], v[c][q]);
    }
  }
  __shared__ float redm[4][4];
  for (int o = 32; o > 0; o >>= 1)
#pragma unroll
    for (int c = 0; c < 4; ++c) mx[c] = fmaxf(mx[c], __shfl_down(mx[c], o));
  if (lane == 0)
#pragma unroll
    for (int c = 0; c < 4; ++c) redm[w][c] = mx[c];
  __syncthreads();
#pragma unroll
  for (int c = 0; c < 4; ++c)
    mx[c] = fmaxf(fmaxf(redm[0][c], redm[1][c]), fmaxf(redm[2][c], redm[3][c]));
  __syncthreads();
  float sm[4] = {0.f, 0.f, 0.f, 0.f};
#pragma unroll
  for (int c = 0; c < 4; ++c)
#pragma unroll
    for (int q = 0; q < 4; ++q) {
      int i = tid + q * 256;
      if (i < kT) {
        v[c][q] = expf(kAttnScale * (v[c][q] - mx[c]));
        sm[c] += v[c][q];
      }
    }
  __shared__ float reds[4][4];
  for (int o = 32; o > 0; o >>= 1)
#pragma unroll
    for (int c = 0; c < 4; ++c) sm[c] += __shfl_down(sm[c], o);
  if (lane == 0)
#pragma unroll
    for (int c = 0; c < 4; ++c) reds[w][c] = sm[c];
  __syncthreads();
  float inv[4];
#pragma unroll
  for (int c = 0; c < 4; ++c)
    inv[c] = 1.f / (reds[0][c] + reds[1][c] + reds[2][c] + reds[3][c]);
  bf16* p0 = P + pbase;
  bf16* p1 = P + kS2P + pbase;
  bf16* p2 = P + 2 * kS2P + pbase;
#pragma unroll
  for (int q = 0; q < 4; ++q) {
    int i = tid + q * 256;
    if (i >= kT) continue;
    float a0 = v[0][q] * inv[0], a1 = v[1][q] * inv[1];
    float a2 = v[2][q] * inv[2], a3 = v[3][q] * inv[3];
    p0[i] = __float2bfloat16(a0 - a3);
    p1[i] = __float2bfloat16(a1 + a2);
    p2[i] = __float2bfloat16(a1 - a2);
  }
}

__global__ __launch_bounds__(256) void k_ln(float* __restrict__ X,
                                            const float* __restrict__ g,
                                            const float* __restrict__ b, int d) {
  long row = blockIdx.x;
  float* x = X + row * d;
  int tid = threadIdx.x;
  float s = 0.f, s2 = 0.f;
  for (int i = tid; i < d; i += 256) {
    float v = x[i];
    s += v;
    s2 = fmaf(v, v, s2);
  }
  __shared__ float rs[4], rs2[4];
  for (int o = 32; o > 0; o >>= 1) {
    s += __shfl_down(s, o);
    s2 += __shfl_down(s2, o);
  }
  int lane = tid & 63, w = tid >> 6;
  if (lane == 0) { rs[w] = s; rs2[w] = s2; }
  __syncthreads();
  float st = rs[0] + rs[1] + rs[2] + rs[3];
  float s2t = rs2[0] + rs2[1] + rs2[2] + rs2[3];
  float m = st / d;
  float var = s2t / d - m * m;
  float inv = rsqrtf(var + 1e-5f);
  for (int i = tid; i < d; i += 256) x[i] = (x[i] - m) * inv * g[i] + b[i];
}

__global__ void k_mask(const float* __restrict__ gr_, const float* __restrict__ gi_,
                       const float* __restrict__ c2wr, const float* __restrict__ c2br,
                       const float* __restrict__ c2wi, const float* __restrict__ c2bi,
                       float* __restrict__ spec) {
  long idx = (long)blockIdx.x * 256 + threadIdx.x;
  long total = (long)kB * 2 * kBINS * kT;
  if (idx >= total) return;
  int t = (int)(idx % kT);
  long r0 = idx / kT;
  int bin = (int)(r0 % kBINS);
  long r1 = r0 / kBINS;
  int ch = (int)(r1 % 2);
  int b = (int)(r1 / 2);
  long ro = ((long)(b * kT + t)) * kD + (bin * 2 + ch);
  float gr = gr_[ro], gi = gi_[ro];
  float wr = c2wr[ch], br = c2br[ch], wi = c2wi[ch], bi = c2bi[ch];
  float mr = (gr * wr + br) - (gi * wi + bi);
  float mi = (gi * wr + br) + (gr * wi + bi);
  float re = spec[idx * 2], im = spec[idx * 2 + 1];
  spec[idx * 2]     = re / (1.f + expf(-mr));
  spec[idx * 2 + 1] = im / (1.f + expf(-mi));
}

extern "C" void kernel_launch(void* const* d_in, const int* in_sizes, int n_in,
                              void* d_out, int out_size, void* d_ws, size_t ws_size,
                              hipStream_t stream) {
  const float* mix        = (const float*)d_in[0];
  const float* window     = (const float*)d_in[1];
  const float* c1wr       = (const float*)d_in[2];
  const float* c1br       = (const float*)d_in[3];
  const float* c1wi       = (const float*)d_in[4];
  const float* c1bi       = (const float*)d_in[5];
  const float* c2wr       = (const float*)d_in[6];
  const float* c2br       = (const float*)d_in[7];
  const float* c2wi       = (const float*)d_in[8];
  const float* c2bi       = (const float*)d_in[9];
  const float* attn_in_w  = (const float*)d_in[10];
  const float* attn_in_b  = (const float*)d_in[11];
  const float* attn_out_w = (const float*)d_in[12];
  const float* attn_out_b = (const float*)d_in[13];
  const float* l1wr       = (const float*)d_in[14];
  const float* l1br       = (const float*)d_in[15];
  const float* l1wi       = (const float*)d_in[16];
  const float* l1bi       = (const float*)d_in[17];
  const float* l2wr       = (const float*)d_in[18];
  const float* l2br       = (const float*)d_in[19];
  const float* l2wi       = (const float*)d_in[20];
  const float* l2bi       = (const float*)d_in[21];
  const float* n1_gr      = (const float*)d_in[22];
  const float* n1_br      = (const float*)d_in[23];
  const float* n1_gi      = (const float*)d_in[24];
  const float* n1_bi      = (const float*)d_in[25];
  const float* n2_gr      = (const float*)d_in[26];
  const float* n2_br      = (const float*)d_in[27];
  const float* n2_gi      = (const float*)d_in[28];
  const float* n2_bi      = (const float*)d_in[29];

  // ---- workspace layout (bytes), all constexpr. kNeed = 188,922,816.
  constexpr long eX    = (long)kMP * kDP2;     // 7,188,480
  constexpr long eQK2  = (long)kQKr * kHDP2;   // 3,683,328
  constexpr long eAout = (long)kBS * kDP;      // 7,089,088
  constexpr long eV    = (long)kBS * kHDP;     // 3,558,336
  constexpr long eWp   = (long)kWr * kDP2;     // 2,396,160
  constexpr long eHidp = (long)kMP * kNHP;
  constexpr long eW1p  = (long)kW1R * kDP2;
  constexpr long eW2p  = (long)kW2R * kNHP;

  constexpr size_t oX    = 0;
  constexpr size_t oQK   = oX + 4 * eX * 2;            //  57,507,840
  constexpr size_t oAout = oQK + 8 * eQK2 * 2;         // 116,441,088
  constexpr size_t oV    = oAout + 2 * eAout * 2;      // 144,797,440
  constexpr size_t oW    = oV + 2 * eV * 2;            // 159,030,784
  constexpr size_t oP    = oW + 5 * eWp * 2;           // 182,992,384
  constexpr size_t oTW   = oP + 3 * kS2P * 2;          // 187,460,992
  constexpr size_t kNeed = 188922816;
  static_assert(oTW + 8192 <= kNeed, "tw overflow");
  constexpr size_t oSS = oW;                           // scores overlay W
  static_assert(oSS + 8 * kS2 * 4 <= oP, "sS overflow");
  static_assert(2 * (long)kBS * kD * 4 <= (long)oQK, "xr/xi overlay");
  static_assert((long)kD * kDP * 2 <= (long)(oW - oV), "Wob overlay");
  // FFN overlays (attention dead):
  constexpr size_t oAb  = oQK;
  constexpr size_t oWF  = oAb + 2 * eX * 2;            //  86,261,760
  constexpr size_t oHid = oWF + 2 * eW2p * 2;          // 122,191,872
  static_assert(2 * eW1p * 2 <= 2 * eW2p * 2, "W slot sized by W2");
  static_assert(oHid + 2 * eHidp * 2 <= oTW, "hid overflow");
  static_assert((long)kNSIG * kT * 2048 * 4 <= (long)(oTW - oAb), "frames");

  char* wsb = (char*)d_ws;
  if (ws_size < kNeed) return;  // fail signature: out0 all-zero (2.578125)

  bf16*  Xrh = (bf16*)(wsb + oX);
  bf16*  Xrl = Xrh + eX;
  bf16*  Xih = Xrl + eX;
  bf16*  Xil = Xih + eX;
  bf16*  Qrh = (bf16*)(wsb + oQK);
  bf16*  Qrl = Qrh + eQK2;
  bf16*  Qih = Qrl + eQK2;
  bf16*  Qil = Qih + eQK2;
  bf16*  Krh = Qil + eQK2;
  bf16*  Krl = Krh + eQK2;
  bf16*  Kih = Krl + eQK2;
  bf16*  Kil = Kih + eQK2;
  bf16*  aoutR = (bf16*)(wsb + oAout);
  bf16*  aoutI = aoutR + eAout;
  bf16*  Vr = (bf16*)(wsb + oV);
  bf16*  Vi = Vr + eV;
  bf16*  Wqh = (bf16*)(wsb + oW);
  bf16*  Wql = Wqh + eWp;
  bf16*  Wkh = Wql + eWp;
  bf16*  Wkl = Wkh + eWp;
  bf16*  Wvh = Wkl + eWp;
  float* sS = (float*)(wsb + oSS);
  bf16*  Pbuf = (bf16*)(wsb + oP);
  bf16*  Wob = (bf16*)(wsb + oV);          // out-proj W (V dead)
  float* xr = (float*)(wsb + oX);          // post-attn fp32 (X dead)
  float* xi = xr + (long)kBS * kD;
  // FFN pointers:
  bf16*  AbR = (bf16*)(wsb + oAb);
  bf16*  AbI = AbR + eX;
  bf16*  w1rH = (bf16*)(wsb + oWF);
  bf16*  w1iH = w1rH + eW1p;
  bf16*  w2rH = (bf16*)(wsb + oWF);
  bf16*  w2iH = w2rH + eW2p;
  bf16*  hidR = (bf16*)(wsb + oHid);
  bf16*  hidI = hidR + eHidp;
  float* frames = (float*)(wsb + oAb);
  float2* tw = (float2*)(wsb + oTW);

  float* out0 = (float*)d_out;
  float* spec = out0 + (long)kNSIG * kL;

  auto cvt2 = [&](const float* src, bf16* dst, int dstRows, int ldd,
                  int srows, int scols, int lds) {
    long total = (long)dstRows * ldd;
    k_cvt2<<<(int)((total + 255) / 256), 256, 0, stream>>>(src, dst, total,
                                                           ldd, srows, scols,
                                                           lds);
  };
  auto cvt2s = [&](const float* src, bf16* dh, bf16* dl, int dstRows, int ldd,
                   int srows, int scols, int lds) {
    long total = (long)dstRows * ldd;
    k_cvt2s<<<(int)((total + 255) / 256), 256, 0, stream>>>(
        src, dh, dl, total, ldd, srows, scols, lds);
  };

  // 0) zero workspace (pads must be zero for glds paths), twiddle table
  hipMemsetAsync(d_ws, 0, kNeed, stream);
  k_twiddle<<<4, 256, 0, stream>>>(tw);

  // 1) STFT -> spec (out1)
  k_stft<<<dim3(kT, kNSIG), 256, 0, stream>>>(mix, window, tw, spec);

  // 2) conv1 + pos-enc -> split-bf16 tokens (stride kDP2)
  long nct = (long)kB * 2 * kBINS * kT;
  k_conv1_pe<<<(nct + 255) / 256, 256, 0, stream>>>(spec, c1wr, c1br, c1wi,
                                                    c1bi, Xrh, Xrl, Xih, Xil);

  // 3) attention, per head
  for (int h = 0; h < 2; ++h) {
    const float* Wq = attn_in_w + (long)(h * kHD) * kD;
    const float* Wk = attn_in_w + (long)(kD + h * kHD) * kD;
    const float* Wv = attn_in_w + (long)(2 * kD + h * kHD) * kD;
    const float* bq = attn_in_b + h * kHD;
    const float* bk = attn_in_b + kD + h * kHD;
    const float* bv = attn_in_b + 2 * kD + h * kHD;
    cvt2s(Wq, Wqh, Wql, kWr, kDP2, kHD, kD, kD);
    cvt2s(Wk, Wkh, Wkl, kWr, kDP2, kHD, kD, kD);
    cvt2(Wv, Wvh, kWr, kDP2, kHD, kD, kD);
    // V projection (register path; A = X hi)
    k_mfma2<bf16, bf16><<<dim3(9, 27), 256, 0, stream>>>(
        Xrh, Xih, Wvh, Vr, Vi, bv, 1.f, 1.f, kBS, kHD, kD, kDP2, kDP2, kHDP);
    // Q, K projections (glds 2-phase split-precision)
    k_gemm3s<<<dim3(9, 27), 256, 0, stream>>>(
        Xrh, Xrl, Wqh, Wql, Qrh, Qrl, bq, kBS, kHD, kDP2, kDP2, kDP2, kHDP2);
    k_gemm3s<<<dim3(9, 27), 256, 0, stream>>>(
        Xih, Xil, Wqh, Wql, Qih, Qil, bq, kBS, kHD, kDP2, kDP2, kDP2, kHDP2);
    k_gemm3s<<<dim3(9, 27), 256, 0, stream>>>(
        Xrh, Xrl, Wkh, Wkl, Krh, Krl, bk, kBS, kHD, kDP2, kDP2, kDP2, kHDP2);
    k_gemm3s<<<dim3(9, 27), 256, 0, stream>>>(
        Xih, Xil, Wkh, Wkl, Kih, Kil, bk, kBS, kHD, kDP2, kDP2, kDP2, kHDP2);
    for (int bp = 0; bp < 2; ++bp) {
      // scores for 2 batches x 4 combos (glds 2-phase; sS overlays W arena)
      k_qkt3<<<dim3(7, 7, 8), 256, 0, stream>>>(Qrh, Qrl, Qih, Qil,
                                                Krh, Krl, Kih, Kil, sS, bp);
      for (int bl = 0; bl < 2; ++bl) {
        int b = bp * 2 + bl;
        k_smf<<<kT, 256, 0, stream>>>(sS + (long)bl * 4 * kS2, Pbuf);
        k_pv<<<dim3(9, 7), 256, 0, stream>>>(
            Pbuf, Vr + (long)b * kT * kHDP, Vi + (long)b * kT * kHDP,
            aoutR + (long)b * kT * kDP + h * kHD,
            aoutI + (long)b * kT * kDP + h * kHD,
            kT, kHD, kT, kTP, kHDP, kDP);
      }
    }
  }

  // 4) output projection (register path) -> fp32 xr, xi (X arena; X dead)
  cvt2(attn_out_w, Wob, kD, kDP, kD, kD, kD);
  k_mfma2<bf16, float><<<dim3(17, 27), 256, 0, stream>>>(
      aoutR, aoutI, Wob, xr, xi, attn_out_b, 0.f, 2.f,
      kBS, kD, kD, kDP, kDP, kD);

  // 5) LN1
  k_ln<<<kBS, 256, 0, stream>>>(xr, n1_gr, n1_br, kD);
  k_ln<<<kBS, 256, 0, stream>>>(xi, n1_gi, n1_bi, kD);

  // 6) FFN (complex-fused, full-M, N/K-halved, 2-phase glds pipeline)
  cvt2(xr, AbR, kMP, kDP2, kBS, kD, kD);
  cvt2(xi, AbI, kMP, kDP2, kBS, kD, kD);
  for (int nh = 0; nh < 2; ++nh) {
    int srows = (nh ? kDFF - kNH : kNH);   // 4096 : 4104
    cvt2(l1wr + (long)nh * kNH * kD, w1rH, kW1R, kDP2, srows, kD, kD);
    cvt2(l1wi + (long)nh * kNH * kD, w1iH, kW1R, kDP2, srows, kD, kD);
    k_cgemm<bf16><<<dim3(33, 27), 256, 0, stream>>>(
        AbR, AbI, w1rH, w1iH, hidR, hidI,
        l1br + nh * kNH, l1bi + nh * kNH, 1.f, 0, 1, srows,
        kBS, kNHP, kDP2, kDP2, kDP2, kNHP);
    cvt2(l2wr + nh * kNH, w2rH, kW2R, kNHP, kD, srows, kDFF);
    cvt2(l2wi + nh * kNH, w2iH, kW2R, kNHP, kD, srows, kDFF);
    k_cgemm<float><<<dim3(17, 27), 256, 0, stream>>>(
        hidR, hidI, w2rH, w2iH, xr, xi,
        l2br, l2bi, (nh == 0 ? 1.f : 0.f), nh, 0, kD,
        kBS, kD, kNHP, kNHP, kNHP, kD);
  }

  // 7) LN2
  k_ln<<<kBS, 256, 0, stream>>>(xr, n2_gr, n2_br, kD);
  k_ln<<<kBS, 256, 0, stream>>>(xi, n2_gi, n2_bi, kD);

  // 8) mask + gate spec in place
  k_mask<<<(nct + 255) / 256, 256, 0, stream>>>(xr, xi, c2wr, c2br, c2wi,
                                                c2bi, spec);

  // 9) iSTFT + overlap-add
  k_istft<<<dim3(kT, kNSIG), 256, 0, stream>>>(spec, window, tw, frames);
  k_gather<<<(int)(((long)kNSIG * kL + 255) / 256), 256, 0, stream>>>(
      frames, window, out0);
}

// Round 15
// 5491.985 us; speedup vs baseline: 4.1177x; 1.0239x over previous
//
#include <hip/hip_runtime.h>
#include <hip/hip_bf16.h>
#include <math.h>

#ifndef M_PIf
#define M_PIf 3.14159265358979323846f
#endif

static constexpr int kNFFT = 2048;
static constexpr int kHOP  = 512;
static constexpr int kBINS = 1025;
static constexpr int kT    = 862;
static constexpr int kL    = 441000;
static constexpr int kB    = 4;
static constexpr int kNSIG = 8;
static constexpr int kD    = 2050;
static constexpr int kHD   = 1025;
static constexpr int kDFF  = 8200;
static constexpr int kBS   = kB * kT;   // 3448
static constexpr float kAttnScale = 0.031234752377721214f; // 1/sqrt(1025)
static constexpr long kS2  = (long)kT * kT;    // 743,044
static constexpr int kTP   = 864;
static constexpr long kS2P = (long)kT * kTP;   // 744,768
static constexpr int kDP   = 2056;   // aout row stride (16B aligned)
static constexpr int kHDP  = 1032;   // V row stride
static constexpr int kHDP2 = 1056;   // Q/K row stride (32-mult, glds)
static constexpr int kQKr  = 3488;   // Q/K rows
static constexpr int kWr   = 1152;   // W rows (9 blocks x 128)
static constexpr int kNH   = 4104;   // FFN N/K half
static constexpr int kDP2  = 2080;   // K padded to 32-mult
static constexpr int kNHP  = 4128;
static constexpr int kMP   = 3456;   // M padded (27 blocks)
static constexpr int kW1R  = 4224;
static constexpr int kW2R  = 2176;

using bf16 = __hip_bfloat16;
typedef __attribute__((ext_vector_type(4))) float f32x4;
typedef __attribute__((ext_vector_type(8))) short bf16x8;

__device__ __forceinline__ float ldf(const float* p, long i) { return p[i]; }
__device__ __forceinline__ float ldf(const bf16* p, long i) {
  return __bfloat162float(p[i]);
}
__device__ __forceinline__ void sto(float* p, long i, float v) { p[i] = v; }
__device__ __forceinline__ void sto(bf16* p, long i, float v) {
  p[i] = __float2bfloat16(v);
}
__device__ __forceinline__ void load16(const float* src, bf16* dst) {
#pragma unroll
  for (int e = 0; e < 16; ++e) dst[e] = __float2bfloat16(src[e]);
}
__device__ __forceinline__ void load16(const bf16* src, bf16* dst) {
  *(bf16x8*)(dst)     = *(const bf16x8*)(src);
  *(bf16x8*)(dst + 8) = *(const bf16x8*)(src + 8);
}

// Direct global->LDS 16B async copy (wave-uniform LDS base, per-lane src).
__device__ __forceinline__ void glds16(const bf16* g, bf16* l) {
  __builtin_amdgcn_global_load_lds(
      (const __attribute__((address_space(1))) unsigned int*)g,
      (__attribute__((address_space(3))) unsigned int*)l, 16, 0, 0);
}

// Bijective XCD-aware block swizzle (m204).
__device__ __forceinline__ void xcd_swizzle(int& bx, int& by) {
  int nwg = gridDim.x * gridDim.y;
  int orig = by * gridDim.x + bx;
  int qq = nwg >> 3, rr = nwg & 7;
  int xcd = orig & 7, loc = orig >> 3;
  int wg = (xcd < rr ? xcd * (qq + 1) : rr * (qq + 1) + (xcd - rr) * qq) + loc;
  bx = wg % gridDim.x;
  by = wg / gridDim.x;
}

// Counted-vmcnt pipeline fences (T4). Each wave waits for its OWN loads
// BEFORE the barrier, so at barrier-exit the whole tile is resident.
__device__ __forceinline__ void pipe_wait8() {
  asm volatile("s_waitcnt vmcnt(8)" ::: "memory");
  __builtin_amdgcn_sched_barrier(0);
  __builtin_amdgcn_s_barrier();
  __builtin_amdgcn_sched_barrier(0);
}
__device__ __forceinline__ void pipe_wait0() {
  asm volatile("s_waitcnt vmcnt(0)" ::: "memory");
  __builtin_amdgcn_sched_barrier(0);
  __builtin_amdgcn_s_barrier();
  __builtin_amdgcn_sched_barrier(0);
}
__device__ __forceinline__ void pipe_readdone() {
  __builtin_amdgcn_sched_barrier(0);
  __builtin_amdgcn_s_barrier();
  __builtin_amdgcn_sched_barrier(0);
}

// Register-path staging of one 16-elem bf16 chunk into an LDS row.
template <typename T>
__device__ __forceinline__ void stage_row16(const T* S, int grow, int glim,
                                            int lda, int k0sk, int K,
                                            bf16* dst) {
  bf16 tmp[16];
  if (grow < glim && k0sk + 16 <= K) {
    load16(S + (long)grow * lda + k0sk, tmp);
  } else {
#pragma unroll
    for (int e = 0; e < 16; ++e) {
      int gk = k0sk + e;
      tmp[e] = __float2bfloat16(
          (grow < glim && gk < K) ? ldf(S, (long)grow * lda + gk) : 0.f);
    }
  }
  *(bf16x8*)(dst)     = *(bf16x8*)&tmp[0];
  *(bf16x8*)(dst + 8) = *(bf16x8*)&tmp[8];
}

// ---------------------------------------------------------------------------
__global__ void k_twiddle(float2* __restrict__ tw) {
  int m = blockIdx.x * 256 + threadIdx.x;
  if (m < 1024) {
    float s, c;
    sincosf(M_PIf * (float)m / 1024.f, &s, &c);
    tw[m] = make_float2(c, s);
  }
}

__device__ __forceinline__ void fft2048_lds(float*& sr, float*& si,
                                            float* dr, float* di, int tid,
                                            float dir,
                                            const float2* __restrict__ tw) {
  int s = 0;
  for (int Ns = 1; Ns < 2048; Ns <<= 1, ++s) {
#pragma unroll
    for (int q = 0; q < 4; ++q) {
      int j = tid + q * 256;
      int base = j & (Ns - 1);
      int grp = j >> s;
      float2 t = tw[base << (10 - s)];
      float c = t.x, sn = dir * t.y;
      float ar = sr[j],        ai = si[j];
      float br = sr[j + 1024], bi = si[j + 1024];
      float tbr = br * c - bi * sn;
      float tbi = br * sn + bi * c;
      int o = (grp << (s + 1)) + base;
      dr[o]      = ar + tbr;  di[o]      = ai + tbi;
      dr[o + Ns] = ar - tbr;  di[o + Ns] = ai - tbi;
    }
    __syncthreads();
    float* t0 = sr; sr = dr; dr = t0;
    float* t1 = si; si = di; di = t1;
  }
}

__global__ __launch_bounds__(256) void k_stft(const float* __restrict__ mix,
                                              const float* __restrict__ win,
                                              const float2* __restrict__ tw,
                                              float* __restrict__ spec) {
  __shared__ float b0r[2048], b0i[2048], b1r[2048], b1i[2048];
  int t = blockIdx.x, sig = blockIdx.y, tid = threadIdx.x;
  const float* x = mix + (long)sig * kL;
  for (int i = tid; i < 2048; i += 256) {
    int src = t * kHOP + i - 1024;
    if (src < 0) src = -src;
    if (src >= kL) src = 2 * kL - 2 - src;
    b0r[i] = x[src] * win[i];
    b0i[i] = 0.f;
  }
  __syncthreads();
  float* sr = b0r; float* si = b0i;
  fft2048_lds(sr, si, b1r, b1i, tid, -1.f, tw);
  for (int k = tid; k < kBINS; k += 256) {
    long o = ((long)sig * kBINS + k) * kT + t;
    spec[o * 2]     = sr[k];
    spec[o * 2 + 1] = si[k];
  }
}

__global__ __launch_bounds__(256) void k_istft(const float* __restrict__ spec,
                                               const float* __restrict__ win,
                                               const float2* __restrict__ tw,
                                               float* __restrict__ frames) {
  __shared__ float b0r[2048], b0i[2048], b1r[2048], b1i[2048];
  int t = blockIdx.x, sig = blockIdx.y, tid = threadIdx.x;
  for (int k = tid; k < kBINS; k += 256) {
    long o = ((long)sig * kBINS + k) * kT + t;
    b0r[k] = spec[o * 2];
    b0i[k] = spec[o * 2 + 1];
  }
  __syncthreads();
  for (int k = 1025 + tid; k < 2048; k += 256) {
    b0r[k] = b0r[2048 - k];
    b0i[k] = -b0i[2048 - k];
  }
  __syncthreads();
  float* sr = b0r; float* si = b0i;
  fft2048_lds(sr, si, b1r, b1i, tid, +1.f, tw);
  const float scale = 1.f / 2048.f;
  float* fo = frames + ((long)sig * kT + t) * 2048;
  for (int n = tid; n < 2048; n += 256) fo[n] = sr[n] * scale * win[n];
}

__global__ void k_gather(const float* __restrict__ frames,
                         const float* __restrict__ win,
                         float* __restrict__ out0) {
  long idx = (long)blockIdx.x * 256 + threadIdx.x;
  long total = (long)kNSIG * kL;
  if (idx >= total) return;
  int sig = (int)(idx / kL);
  int l = (int)(idx % kL);
  int j = l + 1024;
  int tmax = j >> 9; if (tmax > kT - 1) tmax = kT - 1;
  int v = j - 1536;
  int tmin = v > 0 ? (v >> 9) : 0;
  float acc = 0.f, w2 = 0.f;
  for (int t = tmin; t <= tmax; ++t) {
    int n = j - (t << 9);
    float w = win[n];
    acc += frames[((long)sig * kT + t) * 2048 + n];
    w2 = fmaf(w, w, w2);
  }
  out0[idx] = acc / (w2 > 1e-11f ? w2 : 1.f);
}

// conv1x1 + pos-enc -> bf16 hi/lo split tokens (row stride kDP2).
__global__ void k_conv1_pe(const float* __restrict__ spec,
                           const float* __restrict__ c1wr, const float* __restrict__ c1br,
                           const float* __restrict__ c1wi, const float* __restrict__ c1bi,
                           bf16* __restrict__ xrh, bf16* __restrict__ xrl,
                           bf16* __restrict__ xih, bf16* __restrict__ xil) {
  long idx = (long)blockIdx.x * 256 + threadIdx.x;
  long total = (long)kB * 2 * kBINS * kT;
  if (idx >= total) return;
  int t = (int)(idx % kT);
  long r0 = idx / kT;
  int bin = (int)(r0 % kBINS);
  long r1 = r0 / kBINS;
  int ch = (int)(r1 % 2);
  int b = (int)(r1 / 2);
  float re = spec[idx * 2], im = spec[idx * 2 + 1];
  float wr = c1wr[ch], br = c1br[ch], wi = c1wi[ch], bi = c1bi[ch];
  float nr = (re * wr + br) - (im * wi + bi);
  float ni = (im * wr + br) + (re * wi + bi);
  int d = bin * 2 + ch;
  int k = d >> 1;
  float dv = expf((float)k * (-9.210340371976184f / 1025.0f));
  float arg = (float)t * dv;
  float pe = (d & 1) ? cosf(arg) : sinf(arg);
  long ro = ((long)(b * kT + t)) * kDP2 + d;
  float vr = nr + pe, vi = ni + pe;
  bf16 hr = __float2bfloat16(vr);
  bf16 hi = __float2bfloat16(vi);
  xrh[ro] = hr; xrl[ro] = __float2bfloat16(vr - __bfloat162float(hr));
  xih[ro] = hi; xil[ro] = __float2bfloat16(vi - __bfloat162float(hi));
}

// fp32 -> bf16 convert, zero-fill outside (srows x scols).
__global__ void k_cvt2(const float* __restrict__ src, bf16* __restrict__ dst,
                       long total, int ldd, int srows, int scols, int lds) {
  long idx = (long)blockIdx.x * 256 + threadIdx.x;
  if (idx >= total) return;
  int r = (int)(idx / ldd), c = (int)(idx % ldd);
  float v = (r < srows && c < scols) ? src[(long)r * lds + c] : 0.f;
  dst[idx] = __float2bfloat16(v);
}

// fp32 -> split bf16 (hi + lo), zero-fill outside.
__global__ void k_cvt2s(const float* __restrict__ src, bf16* __restrict__ dh,
                        bf16* __restrict__ dl, long total, int ldd, int srows,
                        int scols, int lds) {
  long idx = (long)blockIdx.x * 256 + threadIdx.x;
  if (idx >= total) return;
  int r = (int)(idx / ldd), c = (int)(idx % ldd);
  float v = (r < srows && c < scols) ? src[(long)r * lds + c] : 0.f;
  bf16 h = __float2bfloat16(v);
  dh[idx] = h;
  dl[idx] = __float2bfloat16(v - __bfloat162float(h));
}

// ---------------------------------------------------------------------------
// MFMA, 2 A's sharing one B (register staging; V-proj / out-proj).
// ---------------------------------------------------------------------------
template <typename TA, typename TC>
__global__ __launch_bounds__(256) void k_mfma2(
    const TA* __restrict__ A1, const TA* __restrict__ A2,
    const bf16* __restrict__ B, TC* __restrict__ C1, TC* __restrict__ C2,
    const float* __restrict__ bias, float bs1, float bs2,
    int M, int N, int K, int lda, int ldb, int ldc) {
  __shared__ __align__(16) bf16 As1[128][40];
  __shared__ __align__(16) bf16 As2[128][40];
  __shared__ __align__(16) bf16 Bs[128][40];
  int tid = threadIdx.x;
  int bm = blockIdx.y * 128, bn = blockIdx.x * 128;
  int lane = tid & 63, w = tid >> 6;
  int wr = (w >> 1) * 64, wc = (w & 1) * 64;
  int fr = lane & 15, fq = lane >> 4;
  f32x4 ac1[4][4] = {}, ac2[4][4] = {};
  int sr = tid >> 1, sk = (tid & 1) * 16;
  for (int k0 = 0; k0 < K; k0 += 32) {
    stage_row16(A1, bm + sr, M, lda, k0 + sk, K, &As1[sr][sk]);
    stage_row16(A2, bm + sr, M, lda, k0 + sk, K, &As2[sr][sk]);
    stage_row16(B,  bn + sr, N, ldb, k0 + sk, K, &Bs[sr][sk]);
    __syncthreads();
    bf16x8 a1[4], a2[4], b[4];
#pragma unroll
    for (int i = 0; i < 4; ++i) {
      a1[i] = *(const bf16x8*)&As1[wr + i * 16 + fr][fq * 8];
      a2[i] = *(const bf16x8*)&As2[wr + i * 16 + fr][fq * 8];
      b[i]  = *(const bf16x8*)&Bs[wc + i * 16 + fr][fq * 8];
    }
#pragma unroll
    for (int i = 0; i < 4; ++i)
#pragma unroll
      for (int j = 0; j < 4; ++j) {
        ac1[i][j] = __builtin_amdgcn_mfma_f32_16x16x32_bf16(a1[i], b[j], ac1[i][j], 0, 0, 0);
        ac2[i][j] = __builtin_amdgcn_mfma_f32_16x16x32_bf16(a2[i], b[j], ac2[i][j], 0, 0, 0);
      }
    __syncthreads();
  }
#pragma unroll
  for (int i = 0; i < 4; ++i)
#pragma unroll
    for (int j = 0; j < 4; ++j) {
      int gn = bn + wc + j * 16 + fr;
      if (gn >= N) continue;
      float bv = bias ? bias[gn] : 0.f;
#pragma unroll
      for (int r = 0; r < 4; ++r) {
        int gm = bm + wr + i * 16 + fq * 4 + r;
        if (gm >= M) continue;
        long co = (long)gm * ldc + gn;
        sto(C1, co, ac1[i][j][r] + bs1 * bv);
        sto(C2, co, ac2[i][j][r] + bs2 * bv);
      }
    }
}

// ---------------------------------------------------------------------------
// Split-precision projection, glds + counted-vmcnt 2-phase + XCD swizzle.
// ---------------------------------------------------------------------------
__global__ __launch_bounds__(256) void k_gemm3s(
    const bf16* __restrict__ Ah, const bf16* __restrict__ Al,
    const bf16* __restrict__ Bh, const bf16* __restrict__ Bl,
    bf16* __restrict__ Ch, bf16* __restrict__ Cl,
    const float* __restrict__ bias,
    int M, int N, int K, int lda, int ldb, int ldc) {
  __shared__ __align__(16) bf16 Sah[2][128][32];
  __shared__ __align__(16) bf16 Sal[2][128][32];
  __shared__ __align__(16) bf16 Sbh[2][128][32];
  __shared__ __align__(16) bf16 Sbl[2][128][32];
  int bx = blockIdx.x, by = blockIdx.y;
  xcd_swizzle(bx, by);
  int bm = by * 128, bn = bx * 128;
  int tid = threadIdx.x;
  int lane = tid & 63, w = tid >> 6;
  int wr = (w >> 1) * 64, wc = (w & 1) * 64;
  int fr = lane & 15, fq = lane >> 4;
  f32x4 acc[4][4] = {};
  int srow = w * 32 + (lane >> 2);
  int scol = (lane & 3) * 8;
  const bf16* pAh[2]; const bf16* pAl[2];
  const bf16* pBh[2]; const bf16* pBl[2];
#pragma unroll
  for (int c = 0; c < 2; ++c) {
    long ga = (long)(bm + srow + c * 16) * lda + scol;
    long gb = (long)(bn + srow + c * 16) * ldb + scol;
    pAh[c] = Ah + ga; pAl[c] = Al + ga;
    pBh[c] = Bh + gb; pBl[c] = Bl + gb;
  }
  int nt = K >> 5;
  // prologue: stage t=0 (buf0) and t=1 (buf1)
#pragma unroll
  for (int c = 0; c < 2; ++c) {
    int lb = w * 1024 + c * 512;
    glds16(pAh[c], &Sah[0][0][0] + lb);
    glds16(pAl[c], &Sal[0][0][0] + lb);
    glds16(pBh[c], &Sbh[0][0][0] + lb);
    glds16(pBl[c], &Sbl[0][0][0] + lb);
  }
  if (nt > 1) {
#pragma unroll
    for (int c = 0; c < 2; ++c) {
      int lb = 4096 + w * 1024 + c * 512;
      glds16(pAh[c] + 32, &Sah[0][0][0] + lb);
      glds16(pAl[c] + 32, &Sal[0][0][0] + lb);
      glds16(pBh[c] + 32, &Sbh[0][0][0] + lb);
      glds16(pBl[c] + 32, &Sbl[0][0][0] + lb);
    }
  }
  long koff = 64;
  for (int t = 0; t < nt; ++t) {
    int p = t & 1;
    if (t + 1 < nt) pipe_wait8(); else pipe_wait0();
    bf16x8 ah[4], al[4], bh[4], bl[4];
#pragma unroll
    for (int i = 0; i < 4; ++i) {
      ah[i] = *(const bf16x8*)&Sah[p][wr + i * 16 + fr][fq * 8];
      al[i] = *(const bf16x8*)&Sal[p][wr + i * 16 + fr][fq * 8];
      bh[i] = *(const bf16x8*)&Sbh[p][wc + i * 16 + fr][fq * 8];
      bl[i] = *(const bf16x8*)&Sbl[p][wc + i * 16 + fr][fq * 8];
    }
#pragma unroll
    for (int i = 0; i < 4; ++i)
#pragma unroll
      for (int j = 0; j < 4; ++j) {
        acc[i][j] = __builtin_amdgcn_mfma_f32_16x16x32_bf16(ah[i], bh[j], acc[i][j], 0, 0, 0);
        acc[i][j] = __builtin_amdgcn_mfma_f32_16x16x32_bf16(ah[i], bl[j], acc[i][j], 0, 0, 0);
        acc[i][j] = __builtin_amdgcn_mfma_f32_16x16x32_bf16(al[i], bh[j], acc[i][j], 0, 0, 0);
      }
    pipe_readdone();
    if (t + 2 < nt) {
      int pb = p * 4096;
#pragma unroll
      for (int c = 0; c < 2; ++c) {
        int lb = pb + w * 1024 + c * 512;
        glds16(pAh[c] + koff, &Sah[0][0][0] + lb);
        glds16(pAl[c] + koff, &Sal[0][0][0] + lb);
        glds16(pBh[c] + koff, &Sbh[0][0][0] + lb);
        glds16(pBl[c] + koff, &Sbl[0][0][0] + lb);
      }
      koff += 32;
    }
  }
#pragma unroll
  for (int i = 0; i < 4; ++i)
#pragma unroll
    for (int j = 0; j < 4; ++j) {
      int gn = bn + wc + j * 16 + fr;
      if (gn >= N) continue;
      float bv = bias[gn];
#pragma unroll
      for (int r = 0; r < 4; ++r) {
        int gm = bm + wr + i * 16 + fq * 4 + r;
        if (gm >= M) continue;
        long co = (long)gm * ldc + gn;
        float v = acc[i][j][r] + bv;
        bf16 h = __float2bfloat16(v);
        Ch[co] = h;
        Cl[co] = __float2bfloat16(v - __bfloat162float(h));
      }
    }
}

// ---------------------------------------------------------------------------
// Split-precision QK^T, glds counted-vmcnt 2-phase. z = bl*4 + combo.
// ---------------------------------------------------------------------------
__global__ __launch_bounds__(256) void k_qkt3(
    const bf16* __restrict__ Qrh, const bf16* __restrict__ Qrl,
    const bf16* __restrict__ Qih, const bf16* __restrict__ Qil,
    const bf16* __restrict__ Krh, const bf16* __restrict__ Krl,
    const bf16* __restrict__ Kih, const bf16* __restrict__ Kil,
    float* __restrict__ S, int bp) {
  __shared__ __align__(16) bf16 Sqh[2][128][32];
  __shared__ __align__(16) bf16 Sql[2][128][32];
  __shared__ __align__(16) bf16 Skh[2][128][32];
  __shared__ __align__(16) bf16 Skl[2][128][32];
  int bl = blockIdx.z >> 2, c = blockIdx.z & 3;
  int b = bp * 2 + bl;
  long roff = (long)b * kT * kHDP2;
  const bf16* qh = ((c >> 1) ? Qih : Qrh) + roff;
  const bf16* ql = ((c >> 1) ? Qil : Qrl) + roff;
  const bf16* kh = ((c & 1) ? Kih : Krh) + roff;
  const bf16* kl = ((c & 1) ? Kil : Krl) + roff;
  float* So = S + ((long)bl * 4 + c) * kS2;
  int bx = blockIdx.x, by = blockIdx.y;
  xcd_swizzle(bx, by);
  int bm = by * 128, bn = bx * 128;
  int tid = threadIdx.x;
  int lane = tid & 63, w = tid >> 6;
  int wr = (w >> 1) * 64, wc = (w & 1) * 64;
  int fr = lane & 15, fq = lane >> 4;
  f32x4 acc[4][4] = {};
  int srow = w * 32 + (lane >> 2);
  int scol = (lane & 3) * 8;
  const bf16* pQh[2]; const bf16* pQl[2];
  const bf16* pKh[2]; const bf16* pKl[2];
#pragma unroll
  for (int cc = 0; cc < 2; ++cc) {
    long ga = (long)(bm + srow + cc * 16) * kHDP2 + scol;
    long gb = (long)(bn + srow + cc * 16) * kHDP2 + scol;
    pQh[cc] = qh + ga; pQl[cc] = ql + ga;
    pKh[cc] = kh + gb; pKl[cc] = kl + gb;
  }
  int nt = kHDP2 >> 5;
#pragma unroll
  for (int cc = 0; cc < 2; ++cc) {
    int lb = w * 1024 + cc * 512;
    glds16(pQh[cc], &Sqh[0][0][0] + lb);
    glds16(pQl[cc], &Sql[0][0][0] + lb);
    glds16(pKh[cc], &Skh[0][0][0] + lb);
    glds16(pKl[cc], &Skl[0][0][0] + lb);
  }
  if (nt > 1) {
#pragma unroll
    for (int cc = 0; cc < 2; ++cc) {
      int lb = 4096 + w * 1024 + cc * 512;
      glds16(pQh[cc] + 32, &Sqh[0][0][0] + lb);
      glds16(pQl[cc] + 32, &Sql[0][0][0] + lb);
      glds16(pKh[cc] + 32, &Skh[0][0][0] + lb);
      glds16(pKl[cc] + 32, &Skl[0][0][0] + lb);
    }
  }
  long koff = 64;
  for (int t = 0; t < nt; ++t) {
    int p = t & 1;
    if (t + 1 < nt) pipe_wait8(); else pipe_wait0();
    bf16x8 ah[4], al[4], bh[4], blv[4];
#pragma unroll
    for (int i = 0; i < 4; ++i) {
      ah[i]  = *(const bf16x8*)&Sqh[p][wr + i * 16 + fr][fq * 8];
      al[i]  = *(const bf16x8*)&Sql[p][wr + i * 16 + fr][fq * 8];
      bh[i]  = *(const bf16x8*)&Skh[p][wc + i * 16 + fr][fq * 8];
      blv[i] = *(const bf16x8*)&Skl[p][wc + i * 16 + fr][fq * 8];
    }
#pragma unroll
    for (int i = 0; i < 4; ++i)
#pragma unroll
      for (int j = 0; j < 4; ++j) {
        acc[i][j] = __builtin_amdgcn_mfma_f32_16x16x32_bf16(ah[i], bh[j],  acc[i][j], 0, 0, 0);
        acc[i][j] = __builtin_amdgcn_mfma_f32_16x16x32_bf16(ah[i], blv[j], acc[i][j], 0, 0, 0);
        acc[i][j] = __builtin_amdgcn_mfma_f32_16x16x32_bf16(al[i], bh[j],  acc[i][j], 0, 0, 0);
      }
    pipe_readdone();
    if (t + 2 < nt) {
      int pb = p * 4096;
#pragma unroll
      for (int cc = 0; cc < 2; ++cc) {
        int lb = pb + w * 1024 + cc * 512;
        glds16(pQh[cc] + koff, &Sqh[0][0][0] + lb);
        glds16(pQl[cc] + koff, &Sql[0][0][0] + lb);
        glds16(pKh[cc] + koff, &Skh[0][0][0] + lb);
        glds16(pKl[cc] + koff, &Skl[0][0][0] + lb);
      }
      koff += 32;
    }
  }
#pragma unroll
  for (int i = 0; i < 4; ++i)
#pragma unroll
    for (int j = 0; j < 4; ++j) {
      int gn = bn + wc + j * 16 + fr;
      if (gn >= kT) continue;
#pragma unroll
      for (int r = 0; r < 4; ++r) {
        int gm = bm + wr + i * 16 + fq * 4 + r;
        if (gm >= kT) continue;
        So[(long)gm * kT + gn] = acc[i][j][r];
      }
    }
}

// ---------------------------------------------------------------------------
// Complex-fused MFMA GEMM (FFN): glds counted-vmcnt 2-phase + XCD swizzle.
// ---------------------------------------------------------------------------
template <typename TC>
__global__ __launch_bounds__(256) void k_cgemm(
    const bf16* __restrict__ Ar, const bf16* __restrict__ Ai,
    const bf16* __restrict__ Br, const bf16* __restrict__ Bi,
    TC* __restrict__ Cr, TC* __restrict__ Ci,
    const float* __restrict__ biasR, const float* __restrict__ biasI,
    float bscale, int accum, int relu, int Nreal,
    int M, int N, int K, int lda, int ldb, int ldc) {
  __shared__ __align__(16) bf16 Asr[2][128][32];
  __shared__ __align__(16) bf16 Asi[2][128][32];
  __shared__ __align__(16) bf16 Bsr[2][128][32];
  __shared__ __align__(16) bf16 Bsi[2][128][32];
  int bx = blockIdx.x, by = blockIdx.y;
  xcd_swizzle(bx, by);
  int bm = by * 128, bn = bx * 128;
  int tid = threadIdx.x;
  int lane = tid & 63, w = tid >> 6;
  int wr = (w >> 1) * 64, wc = (w & 1) * 64;
  int fr = lane & 15, fq = lane >> 4;
  f32x4 acR[4][4] = {}, acI[4][4] = {};
  int srow = w * 32 + (lane >> 2);
  int scol = (lane & 3) * 8;
  const bf16* pA[2][2];
  const bf16* pB[2][2];
#pragma unroll
  for (int c = 0; c < 2; ++c) {
    long ga = (long)(bm + srow + c * 16) * lda + scol;
    long gb = (long)(bn + srow + c * 16) * ldb + scol;
    pA[0][c] = Ar + ga; pA[1][c] = Ai + ga;
    pB[0][c] = Br + gb; pB[1][c] = Bi + gb;
  }
  int nt = K >> 5;
#pragma unroll
  for (int c = 0; c < 2; ++c) {
    int lb = w * 1024 + c * 512;
    glds16(pA[0][c], &Asr[0][0][0] + lb);
    glds16(pA[1][c], &Asi[0][0][0] + lb);
    glds16(pB[0][c], &Bsr[0][0][0] + lb);
    glds16(pB[1][c], &Bsi[0][0][0] + lb);
  }
  if (nt > 1) {
#pragma unroll
    for (int c = 0; c < 2; ++c) {
      int lb = 4096 + w * 1024 + c * 512;
      glds16(pA[0][c] + 32, &Asr[0][0][0] + lb);
      glds16(pA[1][c] + 32, &Asi[0][0][0] + lb);
      glds16(pB[0][c] + 32, &Bsr[0][0][0] + lb);
      glds16(pB[1][c] + 32, &Bsi[0][0][0] + lb);
    }
  }
  const short ks = (short)0x8000;
  const bf16x8 sgn = {ks, ks, ks, ks, ks, ks, ks, ks};
  long koff = 64;
  for (int t = 0; t < nt; ++t) {
    int p = t & 1;
    if (t + 1 < nt) pipe_wait8(); else pipe_wait0();
    bf16x8 ar[4], ai[4], nai[4], br[4], bi[4];
#pragma unroll
    for (int i = 0; i < 4; ++i) {
      ar[i] = *(const bf16x8*)&Asr[p][wr + i * 16 + fr][fq * 8];
      ai[i] = *(const bf16x8*)&Asi[p][wr + i * 16 + fr][fq * 8];
      nai[i] = ai[i] ^ sgn;
      br[i] = *(const bf16x8*)&Bsr[p][wc + i * 16 + fr][fq * 8];
      bi[i] = *(const bf16x8*)&Bsi[p][wc + i * 16 + fr][fq * 8];
    }
#pragma unroll
    for (int i = 0; i < 4; ++i)
#pragma unroll
      for (int j = 0; j < 4; ++j) {
        acR[i][j] = __builtin_amdgcn_mfma_f32_16x16x32_bf16(ar[i],  br[j], acR[i][j], 0, 0, 0);
        acR[i][j] = __builtin_amdgcn_mfma_f32_16x16x32_bf16(nai[i], bi[j], acR[i][j], 0, 0, 0);
        acI[i][j] = __builtin_amdgcn_mfma_f32_16x16x32_bf16(ai[i],  br[j], acI[i][j], 0, 0, 0);
        acI[i][j] = __builtin_amdgcn_mfma_f32_16x16x32_bf16(ar[i],  bi[j], acI[i][j], 0, 0, 0);
      }
    pipe_readdone();
    if (t + 2 < nt) {
      int pb = p * 4096;
#pragma unroll
      for (int c = 0; c < 2; ++c) {
        int lb = pb + w * 1024 + c * 512;
        glds16(pA[0][c] + koff, &Asr[0][0][0] + lb);
        glds16(pA[1][c] + koff, &Asi[0][0][0] + lb);
        glds16(pB[0][c] + koff, &Bsr[0][0][0] + lb);
        glds16(pB[1][c] + koff, &Bsi[0][0][0] + lb);
      }
      koff += 32;
    }
  }
#pragma unroll
  for (int i = 0; i < 4; ++i)
#pragma unroll
    for (int j = 0; j < 4; ++j) {
      int gn = bn + wc + j * 16 + fr;
      if (gn >= N) continue;
      float br_ = 0.f, bi_ = 0.f;
      if (gn < Nreal) { br_ = biasR[gn]; bi_ = biasI[gn]; }
#pragma unroll
      for (int r = 0; r < 4; ++r) {
        int gm = bm + wr + i * 16 + fq * 4 + r;
        if (gm >= M) continue;
        long co = (long)gm * ldc + gn;
        float vR = acR[i][j][r] + bscale * (br_ - bi_);
        float vI = acI[i][j][r] + bscale * (br_ + bi_);
        if (accum) { vR += ldf(Cr, co); vI += ldf(Ci, co); }
        if (relu) { vR = fmaxf(vR, 0.f); vI = fmaxf(vI, 0.f); }
        sto(Cr, co, vR);
        sto(Ci, co, vI);
      }
    }
}

// ---------------------------------------------------------------------------
// Fused PV: Cr = P0@Vr + P2@Vi ; Ci = P0@Vi + P1@Vr. B is KxN (register path).
// ---------------------------------------------------------------------------
__global__ __launch_bounds__(256) void k_pv(
    const bf16* __restrict__ P, const bf16* __restrict__ Vr,
    const bf16* __restrict__ Vi, bf16* __restrict__ Cr,
    bf16* __restrict__ Ci, int M, int N, int K, int ldp, int ldv, int ldc) {
  __shared__ __align__(16) bf16 Ps0[128][40];
  __shared__ __align__(16) bf16 Ps1[128][40];
  __shared__ __align__(16) bf16 Ps2[128][40];
  __shared__ __align__(16) bf16 Vsr[128][40];
  __shared__ __align__(16) bf16 Vsi[128][40];
  int tid = threadIdx.x;
  int bm = blockIdx.y * 128, bn = blockIdx.x * 128;
  int lane = tid & 63, w = tid >> 6;
  int wr = (w >> 1) * 64, wc = (w & 1) * 64;
  int fr = lane & 15, fq = lane >> 4;
  f32x4 acR[4][4] = {}, acI[4][4] = {};
  int sr = tid >> 1, sk = (tid & 1) * 16;
  int kk = tid >> 3, nq = (tid & 7) * 16;
  for (int k0 = 0; k0 < K; k0 += 32) {
    stage_row16(P,            bm + sr, M, ldp, k0 + sk, K, &Ps0[sr][sk]);
    stage_row16(P + kS2P,     bm + sr, M, ldp, k0 + sk, K, &Ps1[sr][sk]);
    stage_row16(P + 2 * kS2P, bm + sr, M, ldp, k0 + sk, K, &Ps2[sr][sk]);
    {
      int gk = k0 + kk;
      bf16 t0[16], t1[16];
      if (gk < K && bn + nq + 16 <= N) {
        load16(Vr + (long)gk * ldv + bn + nq, t0);
        load16(Vi + (long)gk * ldv + bn + nq, t1);
      } else {
#pragma unroll
        for (int e = 0; e < 16; ++e) {
          int gn = bn + nq + e;
          bool ok = (gk < K && gn < N);
          t0[e] = __float2bfloat16(ok ? ldf(Vr, (long)gk * ldv + gn) : 0.f);
          t1[e] = __float2bfloat16(ok ? ldf(Vi, (long)gk * ldv + gn) : 0.f);
        }
      }
#pragma unroll
      for (int e = 0; e < 16; ++e) {
        Vsr[nq + e][kk] = t0[e];
        Vsi[nq + e][kk] = t1[e];
      }
    }
    __syncthreads();
    bf16x8 p0[4], p1[4], p2[4], vr[4], vi[4];
#pragma unroll
    for (int i = 0; i < 4; ++i) {
      p0[i] = *(const bf16x8*)&Ps0[wr + i * 16 + fr][fq * 8];
      p1[i] = *(const bf16x8*)&Ps1[wr + i * 16 + fr][fq * 8];
      p2[i] = *(const bf16x8*)&Ps2[wr + i * 16 + fr][fq * 8];
      vr[i] = *(const bf16x8*)&Vsr[wc + i * 16 + fr][fq * 8];
      vi[i] = *(const bf16x8*)&Vsi[wc + i * 16 + fr][fq * 8];
    }
#pragma unroll
    for (int i = 0; i < 4; ++i)
#pragma unroll
      for (int j = 0; j < 4; ++j) {
        acR[i][j] = __builtin_amdgcn_mfma_f32_16x16x32_bf16(p0[i], vr[j], acR[i][j], 0, 0, 0);
        acR[i][j] = __builtin_amdgcn_mfma_f32_16x16x32_bf16(p2[i], vi[j], acR[i][j], 0, 0, 0);
        acI[i][j] = __builtin_amdgcn_mfma_f32_16x16x32_bf16(p0[i], vi[j], acI[i][j], 0, 0, 0);
        acI[i][j] = __builtin_amdgcn_mfma_f32_16x16x32_bf16(p1[i], vr[j], acI[i][j], 0, 0, 0);
      }
    __syncthreads();
  }
#pragma unroll
  for (int i = 0; i < 4; ++i)
#pragma unroll
    for (int j = 0; j < 4; ++j) {
      int gn = bn + wc + j * 16 + fr;
      if (gn >= N) continue;
#pragma unroll
      for (int r = 0; r < 4; ++r) {
        int gm = bm + wr + i * 16 + fq * 4 + r;
        if (gm >= M) continue;
        long co = (long)gm * ldc + gn;
        Cr[co] = __float2bfloat16(acR[i][j][r]);
        Ci[co] = __float2bfloat16(acI[i][j][r]);
      }
    }
}

// Fused softmax over 4 fp32 score mats + fold to 3 bf16 P mats (stride kS2P).
__global__ __launch_bounds__(256) void k_smf(const float* __restrict__ S,
                                             bf16* __restrict__ P) {
  long rbase = (long)blockIdx.x * kT;
  long pbase = (long)blockIdx.x * kTP;
  int tid = threadIdx.x;
  int lane = tid & 63, w = tid >> 6;
  float v[4][4];
  float mx[4] = {-3.4e38f, -3.4e38f, -3.4e38f, -3.4e38f};
#pragma unroll
  for (int c = 0; c < 4; ++c) {
    const float* row = S + c * kS2 + rbase;
#pragma unroll
    for (int q = 0; q < 4; ++q) {
      int i = tid + q * 256;
      v[c][q] = (i < kT) ? row[i] : -3.4e38f;
      mx[c] = fmaxf(mx[c], v[c][q]);
    }
  }
  __shared__ float redm[4][4];
  for (int o = 32; o > 0; o >>= 1)
#pragma unroll
    for (int c = 0; c < 4; ++c) mx[c] = fmaxf(mx[c], __shfl_down(mx[c], o));
  if (lane == 0)
#pragma unroll
    for (int c = 0; c < 4; ++c) redm[w][c] = mx[c];
  __syncthreads();
#pragma unroll
  for (int c = 0; c < 4; ++c)
    mx[c] = fmaxf(fmaxf(redm[0][c], redm[1][c]), fmaxf(redm[2][c], redm[3][c]));
  __syncthreads();
  float sm[4] = {0.f, 0.f, 0.f, 0.f};
#pragma unroll
  for (int c = 0; c < 4; ++c)
#pragma unroll
    for (int q = 0; q < 4; ++q) {
      int i = tid + q * 256;
      if (i < kT) {
        v[c][q] = expf(kAttnScale * (v[c][q] - mx[c]));
        sm[c] += v[c][q];
      }
    }
  __shared__ float reds[4][4];
  for (int o = 32; o > 0; o >>= 1)
#pragma unroll
    for (int c = 0; c < 4; ++c) sm[c] += __shfl_down(sm[c], o);
  if (lane == 0)
#pragma unroll
    for (int c = 0; c < 4; ++c) reds[w][c] = sm[c];
  __syncthreads();
  float inv[4];
#pragma unroll
  for (int c = 0; c < 4; ++c)
    inv[c] = 1.f / (reds[0][c] + reds[1][c] + reds[2][c] + reds[3][c]);
  bf16* p0 = P + pbase;
  bf16* p1 = P + kS2P + pbase;
  bf16* p2 = P + 2 * kS2P + pbase;
#pragma unroll
  for (int q = 0; q < 4; ++q) {
    int i = tid + q * 256;
    if (i >= kT) continue;
    float a0 = v[0][q] * inv[0], a1 = v[1][q] * inv[1];
    float a2 = v[2][q] * inv[2], a3 = v[3][q] * inv[3];
    p0[i] = __float2bfloat16(a0 - a3);
    p1[i] = __float2bfloat16(a1 + a2);
    p2[i] = __float2bfloat16(a1 - a2);
  }
}

__global__ __launch_bounds__(256) void k_ln(float* __restrict__ X,
                                            const float* __restrict__ g,
                                            const float* __restrict__ b, int d) {
  long row = blockIdx.x;
  float* x = X + row * d;
  int tid = threadIdx.x;
  float s = 0.f, s2 = 0.f;
  for (int i = tid; i < d; i += 256) {
    float v = x[i];
    s += v;
    s2 = fmaf(v, v, s2);
  }
  __shared__ float rs[4], rs2[4];
  for (int o = 32; o > 0; o >>= 1) {
    s += __shfl_down(s, o);
    s2 += __shfl_down(s2, o);
  }
  int lane = tid & 63, w = tid >> 6;
  if (lane == 0) { rs[w] = s; rs2[w] = s2; }
  __syncthreads();
  float st = rs[0] + rs[1] + rs[2] + rs[3];
  float s2t = rs2[0] + rs2[1] + rs2[2] + rs2[3];
  float m = st / d;
  float var = s2t / d - m * m;
  float inv = rsqrtf(var + 1e-5f);
  for (int i = tid; i < d; i += 256) x[i] = (x[i] - m) * inv * g[i] + b[i];
}

__global__ void k_mask(const float* __restrict__ gr_, const float* __restrict__ gi_,
                       const float* __restrict__ c2wr, const float* __restrict__ c2br,
                       const float* __restrict__ c2wi, const float* __restrict__ c2bi,
                       float* __restrict__ spec) {
  long idx = (long)blockIdx.x * 256 + threadIdx.x;
  long total = (long)kB * 2 * kBINS * kT;
  if (idx >= total) return;
  int t = (int)(idx % kT);
  long r0 = idx / kT;
  int bin = (int)(r0 % kBINS);
  long r1 = r0 / kBINS;
  int ch = (int)(r1 % 2);
  int b = (int)(r1 / 2);
  long ro = ((long)(b * kT + t)) * kD + (bin * 2 + ch);
  float gr = gr_[ro], gi = gi_[ro];
  float wr = c2wr[ch], br = c2br[ch], wi = c2wi[ch], bi = c2bi[ch];
  float mr = (gr * wr + br) - (gi * wi + bi);
  float mi = (gi * wr + br) + (gr * wi + bi);
  float re = spec[idx * 2], im = spec[idx * 2 + 1];
  spec[idx * 2]     = re / (1.f + expf(-mr));
  spec[idx * 2 + 1] = im / (1.f + expf(-mi));
}

extern "C" void kernel_launch(void* const* d_in, const int* in_sizes, int n_in,
                              void* d_out, int out_size, void* d_ws, size_t ws_size,
                              hipStream_t stream) {
  const float* mix        = (const float*)d_in[0];
  const float* window     = (const float*)d_in[1];
  const float* c1wr       = (const float*)d_in[2];
  const float* c1br       = (const float*)d_in[3];
  const float* c1wi       = (const float*)d_in[4];
  const float* c1bi       = (const float*)d_in[5];
  const float* c2wr       = (const float*)d_in[6];
  const float* c2br       = (const float*)d_in[7];
  const float* c2wi       = (const float*)d_in[8];
  const float* c2bi       = (const float*)d_in[9];
  const float* attn_in_w  = (const float*)d_in[10];
  const float* attn_in_b  = (const float*)d_in[11];
  const float* attn_out_w = (const float*)d_in[12];
  const float* attn_out_b = (const float*)d_in[13];
  const float* l1wr       = (const float*)d_in[14];
  const float* l1br       = (const float*)d_in[15];
  const float* l1wi       = (const float*)d_in[16];
  const float* l1bi       = (const float*)d_in[17];
  const float* l2wr       = (const float*)d_in[18];
  const float* l2br       = (const float*)d_in[19];
  const float* l2wi       = (const float*)d_in[20];
  const float* l2bi       = (const float*)d_in[21];
  const float* n1_gr      = (const float*)d_in[22];
  const float* n1_br      = (const float*)d_in[23];
  const float* n1_gi      = (const float*)d_in[24];
  const float* n1_bi      = (const float*)d_in[25];
  const float* n2_gr      = (const float*)d_in[26];
  const float* n2_br      = (const float*)d_in[27];
  const float* n2_gi      = (const float*)d_in[28];
  const float* n2_bi      = (const float*)d_in[29];

  // ---- workspace layout (bytes), all constexpr. kNeed = 188,922,816.
  constexpr long eX    = (long)kMP * kDP2;     // 7,188,480
  constexpr long eQK2  = (long)kQKr * kHDP2;   // 3,683,328
  constexpr long eAout = (long)kBS * kDP;      // 7,089,088
  constexpr long eV    = (long)kBS * kHDP;     // 3,558,336
  constexpr long eWp   = (long)kWr * kDP2;     // 2,396,160
  constexpr long eHidp = (long)kMP * kNHP;
  constexpr long eW1p  = (long)kW1R * kDP2;
  constexpr long eW2p  = (long)kW2R * kNHP;

  constexpr size_t oX    = 0;
  constexpr size_t oQK   = oX + 4 * eX * 2;            //  57,507,840
  constexpr size_t oAout = oQK + 8 * eQK2 * 2;         // 116,441,088
  constexpr size_t oV    = oAout + 2 * eAout * 2;      // 144,797,440
  constexpr size_t oW    = oV + 2 * eV * 2;            // 159,030,784
  constexpr size_t oP    = oW + 5 * eWp * 2;           // 182,992,384
  constexpr size_t oTW   = oP + 3 * kS2P * 2;          // 187,460,992
  constexpr size_t kNeed = 188922816;
  static_assert(oTW + 8192 <= kNeed, "tw overflow");
  constexpr size_t oSS = oW;                           // scores overlay W
  static_assert(oSS + 8 * kS2 * 4 <= oP, "sS overflow");
  static_assert(2 * (long)kBS * kD * 4 <= (long)oQK, "xr/xi overlay");
  static_assert((long)kD * kDP * 2 <= (long)(oW - oV), "Wob overlay");
  // FFN overlays (attention dead):
  constexpr size_t oAb  = oQK;
  constexpr size_t oWF  = oAb + 2 * eX * 2;            //  86,261,760
  constexpr size_t oHid = oWF + 2 * eW2p * 2;          // 122,191,872
  static_assert(2 * eW1p * 2 <= 2 * eW2p * 2, "W slot sized by W2");
  static_assert(oHid + 2 * eHidp * 2 <= oTW, "hid overflow");
  static_assert((long)kNSIG * kT * 2048 * 4 <= (long)(oTW - oAb), "frames");

  char* wsb = (char*)d_ws;
  if (ws_size < kNeed) return;  // fail signature: out0 all-zero (2.578125)

  bf16*  Xrh = (bf16*)(wsb + oX);
  bf16*  Xrl = Xrh + eX;
  bf16*  Xih = Xrl + eX;
  bf16*  Xil = Xih + eX;
  bf16*  Qrh = (bf16*)(wsb + oQK);
  bf16*  Qrl = Qrh + eQK2;
  bf16*  Qih = Qrl + eQK2;
  bf16*  Qil = Qih + eQK2;
  bf16*  Krh = Qil + eQK2;
  bf16*  Krl = Krh + eQK2;
  bf16*  Kih = Krl + eQK2;
  bf16*  Kil = Kih + eQK2;
  bf16*  aoutR = (bf16*)(wsb + oAout);
  bf16*  aoutI = aoutR + eAout;
  bf16*  Vr = (bf16*)(wsb + oV);
  bf16*  Vi = Vr + eV;
  bf16*  Wqh = (bf16*)(wsb + oW);
  bf16*  Wql = Wqh + eWp;
  bf16*  Wkh = Wql + eWp;
  bf16*  Wkl = Wkh + eWp;
  bf16*  Wvh = Wkl + eWp;
  float* sS = (float*)(wsb + oSS);
  bf16*  Pbuf = (bf16*)(wsb + oP);
  bf16*  Wob = (bf16*)(wsb + oV);          // out-proj W (V dead)
  float* xr = (float*)(wsb + oX);          // post-attn fp32 (X dead)
  float* xi = xr + (long)kBS * kD;
  // FFN pointers:
  bf16*  AbR = (bf16*)(wsb + oAb);
  bf16*  AbI = AbR + eX;
  bf16*  w1rH = (bf16*)(wsb + oWF);
  bf16*  w1iH = w1rH + eW1p;
  bf16*  w2rH = (bf16*)(wsb + oWF);
  bf16*  w2iH = w2rH + eW2p;
  bf16*  hidR = (bf16*)(wsb + oHid);
  bf16*  hidI = hidR + eHidp;
  float* frames = (float*)(wsb + oAb);
  float2* tw = (float2*)(wsb + oTW);

  float* out0 = (float*)d_out;
  float* spec = out0 + (long)kNSIG * kL;

  auto cvt2 = [&](const float* src, bf16* dst, int dstRows, int ldd,
                  int srows, int scols, int lds) {
    long total = (long)dstRows * ldd;
    k_cvt2<<<(int)((total + 255) / 256), 256, 0, stream>>>(src, dst, total,
                                                           ldd, srows, scols,
                                                           lds);
  };
  auto cvt2s = [&](const float* src, bf16* dh, bf16* dl, int dstRows, int ldd,
                   int srows, int scols, int lds) {
    long total = (long)dstRows * ldd;
    k_cvt2s<<<(int)((total + 255) / 256), 256, 0, stream>>>(
        src, dh, dl, total, ldd, srows, scols, lds);
  };

  // 0) zero workspace (pads must be zero for glds paths), twiddle table
  hipMemsetAsync(d_ws, 0, kNeed, stream);
  k_twiddle<<<4, 256, 0, stream>>>(tw);

  // 1) STFT -> spec (out1)
  k_stft<<<dim3(kT, kNSIG), 256, 0, stream>>>(mix, window, tw, spec);

  // 2) conv1 + pos-enc -> split-bf16 tokens (stride kDP2)
  long nct = (long)kB * 2 * kBINS * kT;
  k_conv1_pe<<<(nct + 255) / 256, 256, 0, stream>>>(spec, c1wr, c1br, c1wi,
                                                    c1bi, Xrh, Xrl, Xih, Xil);

  // 3) attention, per head
  for (int h = 0; h < 2; ++h) {
    const float* Wq = attn_in_w + (long)(h * kHD) * kD;
    const float* Wk = attn_in_w + (long)(kD + h * kHD) * kD;
    const float* Wv = attn_in_w + (long)(2 * kD + h * kHD) * kD;
    const float* bq = attn_in_b + h * kHD;
    const float* bk = attn_in_b + kD + h * kHD;
    const float* bv = attn_in_b + 2 * kD + h * kHD;
    cvt2s(Wq, Wqh, Wql, kWr, kDP2, kHD, kD, kD);
    cvt2s(Wk, Wkh, Wkl, kWr, kDP2, kHD, kD, kD);
    cvt2(Wv, Wvh, kWr, kDP2, kHD, kD, kD);
    // V projection (register path; A = X hi)
    k_mfma2<bf16, bf16><<<dim3(9, 27), 256, 0, stream>>>(
        Xrh, Xih, Wvh, Vr, Vi, bv, 1.f, 1.f, kBS, kHD, kD, kDP2, kDP2, kHDP);
    // Q, K projections (glds counted-vmcnt split-precision)
    k_gemm3s<<<dim3(9, 27), 256, 0, stream>>>(
        Xrh, Xrl, Wqh, Wql, Qrh, Qrl, bq, kBS, kHD, kDP2, kDP2, kDP2, kHDP2);
    k_gemm3s<<<dim3(9, 27), 256, 0, stream>>>(
        Xih, Xil, Wqh, Wql, Qih, Qil, bq, kBS, kHD, kDP2, kDP2, kDP2, kHDP2);
    k_gemm3s<<<dim3(9, 27), 256, 0, stream>>>(
        Xrh, Xrl, Wkh, Wkl, Krh, Krl, bk, kBS, kHD, kDP2, kDP2, kDP2, kHDP2);
    k_gemm3s<<<dim3(9, 27), 256, 0, stream>>>(
        Xih, Xil, Wkh, Wkl, Kih, Kil, bk, kBS, kHD, kDP2, kDP2, kDP2, kHDP2);
    for (int bp = 0; bp < 2; ++bp) {
      k_qkt3<<<dim3(7, 7, 8), 256, 0, stream>>>(Qrh, Qrl, Qih, Qil,
                                                Krh, Krl, Kih, Kil, sS, bp);
      for (int bl = 0; bl < 2; ++bl) {
        int b = bp * 2 + bl;
        k_smf<<<kT, 256, 0, stream>>>(sS + (long)bl * 4 * kS2, Pbuf);
        k_pv<<<dim3(9, 7), 256, 0, stream>>>(
            Pbuf, Vr + (long)b * kT * kHDP, Vi + (long)b * kT * kHDP,
            aoutR + (long)b * kT * kDP + h * kHD,
            aoutI + (long)b * kT * kDP + h * kHD,
            kT, kHD, kT, kTP, kHDP, kDP);
      }
    }
  }

  // 4) output projection (register path) -> fp32 xr, xi (X arena; X dead)
  cvt2(attn_out_w, Wob, kD, kDP, kD, kD, kD);
  k_mfma2<bf16, float><<<dim3(17, 27), 256, 0, stream>>>(
      aoutR, aoutI, Wob, xr, xi, attn_out_b, 0.f, 2.f,
      kBS, kD, kD, kDP, kDP, kD);

  // 5) LN1
  k_ln<<<kBS, 256, 0, stream>>>(xr, n1_gr, n1_br, kD);
  k_ln<<<kBS, 256, 0, stream>>>(xi, n1_gi, n1_bi, kD);

  // 6) FFN (complex-fused, full-M, N/K-halved, counted-vmcnt glds pipeline)
  cvt2(xr, AbR, kMP, kDP2, kBS, kD, kD);
  cvt2(xi, AbI, kMP, kDP2, kBS, kD, kD);
  for (int nh = 0; nh < 2; ++nh) {
    int srows = (nh ? kDFF - kNH : kNH);   // 4096 : 4104
    cvt2(l1wr + (long)nh * kNH * kD, w1rH, kW1R, kDP2, srows, kD, kD);
    cvt2(l1wi + (long)nh * kNH * kD, w1iH, kW1R, kDP2, srows, kD, kD);
    k_cgemm<bf16><<<dim3(33, 27), 256, 0, stream>>>(
        AbR, AbI, w1rH, w1iH, hidR, hidI,
        l1br + nh * kNH, l1bi + nh * kNH, 1.f, 0, 1, srows,
        kBS, kNHP, kDP2, kDP2, kDP2, kNHP);
    cvt2(l2wr + nh * kNH, w2rH, kW2R, kNHP, kD, srows, kDFF);
    cvt2(l2wi + nh * kNH, w2iH, kW2R, kNHP, kD, srows, kDFF);
    k_cgemm<float><<<dim3(17, 27), 256, 0, stream>>>(
        hidR, hidI, w2rH, w2iH, xr, xi,
        l2br, l2bi, (nh == 0 ? 1.f : 0.f), nh, 0, kD,
        kBS, kD, kNHP, kNHP, kNHP, kD);
  }

  // 7) LN2
  k_ln<<<kBS, 256, 0, stream>>>(xr, n2_gr, n2_br, kD);
  k_ln<<<kBS, 256, 0, stream>>>(xi, n2_gi, n2_bi, kD);

  // 8) mask + gate spec in place
  k_mask<<<(nct + 255) / 256, 256, 0, stream>>>(xr, xi, c2wr, c2br, c2wi,
                                                c2bi, spec);

  // 9) iSTFT + overlap-add
  k_istft<<<dim3(kT, kNSIG), 256, 0, stream>>>(spec, window, tw, frames);
  k_gather<<<(int)(((long)kNSIG * kL + 255) / 256), 256, 0, stream>>>(
      frames, window, out0);
}

// Round 16
// 4941.138 us; speedup vs baseline: 4.5768x; 1.1115x over previous
//
#include <hip/hip_runtime.h>
#include <hip/hip_bf16.h>
#include <math.h>

#ifndef M_PIf
#define M_PIf 3.14159265358979323846f
#endif

static constexpr int kNFFT = 2048;
static constexpr int kHOP  = 512;
static constexpr int kBINS = 1025;
static constexpr int kT    = 862;
static constexpr int kL    = 441000;
static constexpr int kB    = 4;
static constexpr int kNSIG = 8;
static constexpr int kD    = 2050;
static constexpr int kHD   = 1025;
static constexpr int kDFF  = 8200;
static constexpr int kBS   = kB * kT;   // 3448
static constexpr float kAttnScale = 0.031234752377721214f; // 1/sqrt(1025)
static constexpr long kS2  = (long)kT * kT;    // 743,044
static constexpr int kTP   = 864;
static constexpr long kS2P = (long)kT * kTP;   // 744,768
static constexpr int kDP   = 2056;   // aout row stride (16B aligned)
static constexpr int kHDP  = 1032;   // V row stride
static constexpr int kHDP2 = 1056;   // Q/K row stride (32-mult, glds)
static constexpr int kQKr  = 3488;   // Q/K rows
static constexpr int kWr   = 1152;   // W rows (9 blocks x 128)
static constexpr int kNH   = 4104;   // FFN N/K half
static constexpr int kDP2  = 2080;   // K padded to 32-mult
static constexpr int kNHP  = 4128;   // hid row stride
static constexpr int kMP   = 3456;   // M padded (27 blocks)
static constexpr int kW1R  = 4352;   // W1 rows padded (17 blocks x 256)
static constexpr int kW2R  = 2304;   // W2 rows padded (9 blocks x 256)

using bf16 = __hip_bfloat16;
typedef __attribute__((ext_vector_type(4))) float f32x4;
typedef __attribute__((ext_vector_type(8))) short bf16x8;

__device__ __forceinline__ float ldf(const float* p, long i) { return p[i]; }
__device__ __forceinline__ float ldf(const bf16* p, long i) {
  return __bfloat162float(p[i]);
}
__device__ __forceinline__ void sto(float* p, long i, float v) { p[i] = v; }
__device__ __forceinline__ void sto(bf16* p, long i, float v) {
  p[i] = __float2bfloat16(v);
}
__device__ __forceinline__ void load16(const float* src, bf16* dst) {
#pragma unroll
  for (int e = 0; e < 16; ++e) dst[e] = __float2bfloat16(src[e]);
}
__device__ __forceinline__ void load16(const bf16* src, bf16* dst) {
  *(bf16x8*)(dst)     = *(const bf16x8*)(src);
  *(bf16x8*)(dst + 8) = *(const bf16x8*)(src + 8);
}

// Direct global->LDS 16B async copy (wave-uniform LDS base, per-lane src).
__device__ __forceinline__ void glds16(const bf16* g, bf16* l) {
  __builtin_amdgcn_global_load_lds(
      (const __attribute__((address_space(1))) unsigned int*)g,
      (__attribute__((address_space(3))) unsigned int*)l, 16, 0, 0);
}

// Bijective XCD-aware block swizzle (m204).
__device__ __forceinline__ void xcd_swizzle(int& bx, int& by) {
  int nwg = gridDim.x * gridDim.y;
  int orig = by * gridDim.x + bx;
  int qq = nwg >> 3, rr = nwg & 7;
  int xcd = orig & 7, loc = orig >> 3;
  int wg = (xcd < rr ? xcd * (qq + 1) : rr * (qq + 1) + (xcd - rr) * qq) + loc;
  bx = wg % gridDim.x;
  by = wg / gridDim.x;
}

// Counted-vmcnt pipeline fences (attention glds kernels).
__device__ __forceinline__ void pipe_wait8() {
  asm volatile("s_waitcnt vmcnt(8)" ::: "memory");
  __builtin_amdgcn_sched_barrier(0);
  __builtin_amdgcn_s_barrier();
  __builtin_amdgcn_sched_barrier(0);
}
__device__ __forceinline__ void pipe_wait0() {
  asm volatile("s_waitcnt vmcnt(0)" ::: "memory");
  __builtin_amdgcn_sched_barrier(0);
  __builtin_amdgcn_s_barrier();
  __builtin_amdgcn_sched_barrier(0);
}
__device__ __forceinline__ void pipe_readdone() {
  __builtin_amdgcn_sched_barrier(0);
  __builtin_amdgcn_s_barrier();
  __builtin_amdgcn_sched_barrier(0);
}

// Register-path staging of one 16-elem bf16 chunk into an LDS row.
template <typename T>
__device__ __forceinline__ void stage_row16(const T* S, int grow, int glim,
                                            int lda, int k0sk, int K,
                                            bf16* dst) {
  bf16 tmp[16];
  if (grow < glim && k0sk + 16 <= K) {
    load16(S + (long)grow * lda + k0sk, tmp);
  } else {
#pragma unroll
    for (int e = 0; e < 16; ++e) {
      int gk = k0sk + e;
      tmp[e] = __float2bfloat16(
          (grow < glim && gk < K) ? ldf(S, (long)grow * lda + gk) : 0.f);
    }
  }
  *(bf16x8*)(dst)     = *(bf16x8*)&tmp[0];
  *(bf16x8*)(dst + 8) = *(bf16x8*)&tmp[8];
}

// ---------------------------------------------------------------------------
__global__ void k_twiddle(float2* __restrict__ tw) {
  int m = blockIdx.x * 256 + threadIdx.x;
  if (m < 1024) {
    float s, c;
    sincosf(M_PIf * (float)m / 1024.f, &s, &c);
    tw[m] = make_float2(c, s);
  }
}

__device__ __forceinline__ void fft2048_lds(float*& sr, float*& si,
                                            float* dr, float* di, int tid,
                                            float dir,
                                            const float2* __restrict__ tw) {
  int s = 0;
  for (int Ns = 1; Ns < 2048; Ns <<= 1, ++s) {
#pragma unroll
    for (int q = 0; q < 4; ++q) {
      int j = tid + q * 256;
      int base = j & (Ns - 1);
      int grp = j >> s;
      float2 t = tw[base << (10 - s)];
      float c = t.x, sn = dir * t.y;
      float ar = sr[j],        ai = si[j];
      float br = sr[j + 1024], bi = si[j + 1024];
      float tbr = br * c - bi * sn;
      float tbi = br * sn + bi * c;
      int o = (grp << (s + 1)) + base;
      dr[o]      = ar + tbr;  di[o]      = ai + tbi;
      dr[o + Ns] = ar - tbr;  di[o + Ns] = ai - tbi;
    }
    __syncthreads();
    float* t0 = sr; sr = dr; dr = t0;
    float* t1 = si; si = di; di = t1;
  }
}

__global__ __launch_bounds__(256) void k_stft(const float* __restrict__ mix,
                                              const float* __restrict__ win,
                                              const float2* __restrict__ tw,
                                              float* __restrict__ spec) {
  __shared__ float b0r[2048], b0i[2048], b1r[2048], b1i[2048];
  int t = blockIdx.x, sig = blockIdx.y, tid = threadIdx.x;
  const float* x = mix + (long)sig * kL;
  for (int i = tid; i < 2048; i += 256) {
    int src = t * kHOP + i - 1024;
    if (src < 0) src = -src;
    if (src >= kL) src = 2 * kL - 2 - src;
    b0r[i] = x[src] * win[i];
    b0i[i] = 0.f;
  }
  __syncthreads();
  float* sr = b0r; float* si = b0i;
  fft2048_lds(sr, si, b1r, b1i, tid, -1.f, tw);
  for (int k = tid; k < kBINS; k += 256) {
    long o = ((long)sig * kBINS + k) * kT + t;
    spec[o * 2]     = sr[k];
    spec[o * 2 + 1] = si[k];
  }
}

__global__ __launch_bounds__(256) void k_istft(const float* __restrict__ spec,
                                               const float* __restrict__ win,
                                               const float2* __restrict__ tw,
                                               float* __restrict__ frames) {
  __shared__ float b0r[2048], b0i[2048], b1r[2048], b1i[2048];
  int t = blockIdx.x, sig = blockIdx.y, tid = threadIdx.x;
  for (int k = tid; k < kBINS; k += 256) {
    long o = ((long)sig * kBINS + k) * kT + t;
    b0r[k] = spec[o * 2];
    b0i[k] = spec[o * 2 + 1];
  }
  __syncthreads();
  for (int k = 1025 + tid; k < 2048; k += 256) {
    b0r[k] = b0r[2048 - k];
    b0i[k] = -b0i[2048 - k];
  }
  __syncthreads();
  float* sr = b0r; float* si = b0i;
  fft2048_lds(sr, si, b1r, b1i, tid, +1.f, tw);
  const float scale = 1.f / 2048.f;
  float* fo = frames + ((long)sig * kT + t) * 2048;
  for (int n = tid; n < 2048; n += 256) fo[n] = sr[n] * scale * win[n];
}

__global__ void k_gather(const float* __restrict__ frames,
                         const float* __restrict__ win,
                         float* __restrict__ out0) {
  long idx = (long)blockIdx.x * 256 + threadIdx.x;
  long total = (long)kNSIG * kL;
  if (idx >= total) return;
  int sig = (int)(idx / kL);
  int l = (int)(idx % kL);
  int j = l + 1024;
  int tmax = j >> 9; if (tmax > kT - 1) tmax = kT - 1;
  int v = j - 1536;
  int tmin = v > 0 ? (v >> 9) : 0;
  float acc = 0.f, w2 = 0.f;
  for (int t = tmin; t <= tmax; ++t) {
    int n = j - (t << 9);
    float w = win[n];
    acc += frames[((long)sig * kT + t) * 2048 + n];
    w2 = fmaf(w, w, w2);
  }
  out0[idx] = acc / (w2 > 1e-11f ? w2 : 1.f);
}

// conv1x1 + pos-enc -> bf16 hi/lo split tokens (row stride kDP2).
__global__ void k_conv1_pe(const float* __restrict__ spec,
                           const float* __restrict__ c1wr, const float* __restrict__ c1br,
                           const float* __restrict__ c1wi, const float* __restrict__ c1bi,
                           bf16* __restrict__ xrh, bf16* __restrict__ xrl,
                           bf16* __restrict__ xih, bf16* __restrict__ xil) {
  long idx = (long)blockIdx.x * 256 + threadIdx.x;
  long total = (long)kB * 2 * kBINS * kT;
  if (idx >= total) return;
  int t = (int)(idx % kT);
  long r0 = idx / kT;
  int bin = (int)(r0 % kBINS);
  long r1 = r0 / kBINS;
  int ch = (int)(r1 % 2);
  int b = (int)(r1 / 2);
  float re = spec[idx * 2], im = spec[idx * 2 + 1];
  float wr = c1wr[ch], br = c1br[ch], wi = c1wi[ch], bi = c1bi[ch];
  float nr = (re * wr + br) - (im * wi + bi);
  float ni = (im * wr + br) + (re * wi + bi);
  int d = bin * 2 + ch;
  int k = d >> 1;
  float dv = expf((float)k * (-9.210340371976184f / 1025.0f));
  float arg = (float)t * dv;
  float pe = (d & 1) ? cosf(arg) : sinf(arg);
  long ro = ((long)(b * kT + t)) * kDP2 + d;
  float vr = nr + pe, vi = ni + pe;
  bf16 hr = __float2bfloat16(vr);
  bf16 hi = __float2bfloat16(vi);
  xrh[ro] = hr; xrl[ro] = __float2bfloat16(vr - __bfloat162float(hr));
  xih[ro] = hi; xil[ro] = __float2bfloat16(vi - __bfloat162float(hi));
}

// fp32 -> bf16 convert, zero-fill outside (srows x scols).
__global__ void k_cvt2(const float* __restrict__ src, bf16* __restrict__ dst,
                       long total, int ldd, int srows, int scols, int lds) {
  long idx = (long)blockIdx.x * 256 + threadIdx.x;
  if (idx >= total) return;
  int r = (int)(idx / ldd), c = (int)(idx % ldd);
  float v = (r < srows && c < scols) ? src[(long)r * lds + c] : 0.f;
  dst[idx] = __float2bfloat16(v);
}

// fp32 -> split bf16 (hi + lo), zero-fill outside.
__global__ void k_cvt2s(const float* __restrict__ src, bf16* __restrict__ dh,
                        bf16* __restrict__ dl, long total, int ldd, int srows,
                        int scols, int lds) {
  long idx = (long)blockIdx.x * 256 + threadIdx.x;
  if (idx >= total) return;
  int r = (int)(idx / ldd), c = (int)(idx % ldd);
  float v = (r < srows && c < scols) ? src[(long)r * lds + c] : 0.f;
  bf16 h = __float2bfloat16(v);
  dh[idx] = h;
  dl[idx] = __float2bfloat16(v - __bfloat162float(h));
}

// ---------------------------------------------------------------------------
// MFMA, 2 A's sharing one B (register staging; V-proj / out-proj).
// ---------------------------------------------------------------------------
template <typename TA, typename TC>
__global__ __launch_bounds__(256) void k_mfma2(
    const TA* __restrict__ A1, const TA* __restrict__ A2,
    const bf16* __restrict__ B, TC* __restrict__ C1, TC* __restrict__ C2,
    const float* __restrict__ bias, float bs1, float bs2,
    int M, int N, int K, int lda, int ldb, int ldc) {
  __shared__ __align__(16) bf16 As1[128][40];
  __shared__ __align__(16) bf16 As2[128][40];
  __shared__ __align__(16) bf16 Bs[128][40];
  int tid = threadIdx.x;
  int bm = blockIdx.y * 128, bn = blockIdx.x * 128;
  int lane = tid & 63, w = tid >> 6;
  int wr = (w >> 1) * 64, wc = (w & 1) * 64;
  int fr = lane & 15, fq = lane >> 4;
  f32x4 ac1[4][4] = {}, ac2[4][4] = {};
  int sr = tid >> 1, sk = (tid & 1) * 16;
  for (int k0 = 0; k0 < K; k0 += 32) {
    stage_row16(A1, bm + sr, M, lda, k0 + sk, K, &As1[sr][sk]);
    stage_row16(A2, bm + sr, M, lda, k0 + sk, K, &As2[sr][sk]);
    stage_row16(B,  bn + sr, N, ldb, k0 + sk, K, &Bs[sr][sk]);
    __syncthreads();
    bf16x8 a1[4], a2[4], b[4];
#pragma unroll
    for (int i = 0; i < 4; ++i) {
      a1[i] = *(const bf16x8*)&As1[wr + i * 16 + fr][fq * 8];
      a2[i] = *(const bf16x8*)&As2[wr + i * 16 + fr][fq * 8];
      b[i]  = *(const bf16x8*)&Bs[wc + i * 16 + fr][fq * 8];
    }
#pragma unroll
    for (int i = 0; i < 4; ++i)
#pragma unroll
      for (int j = 0; j < 4; ++j) {
        ac1[i][j] = __builtin_amdgcn_mfma_f32_16x16x32_bf16(a1[i], b[j], ac1[i][j], 0, 0, 0);
        ac2[i][j] = __builtin_amdgcn_mfma_f32_16x16x32_bf16(a2[i], b[j], ac2[i][j], 0, 0, 0);
      }
    __syncthreads();
  }
#pragma unroll
  for (int i = 0; i < 4; ++i)
#pragma unroll
    for (int j = 0; j < 4; ++j) {
      int gn = bn + wc + j * 16 + fr;
      if (gn >= N) continue;
      float bv = bias ? bias[gn] : 0.f;
#pragma unroll
      for (int r = 0; r < 4; ++r) {
        int gm = bm + wr + i * 16 + fq * 4 + r;
        if (gm >= M) continue;
        long co = (long)gm * ldc + gn;
        sto(C1, co, ac1[i][j][r] + bs1 * bv);
        sto(C2, co, ac2[i][j][r] + bs2 * bv);
      }
    }
}

// ---------------------------------------------------------------------------
// Split-precision projection, glds + counted-vmcnt 2-phase + XCD swizzle.
// ---------------------------------------------------------------------------
__global__ __launch_bounds__(256) void k_gemm3s(
    const bf16* __restrict__ Ah, const bf16* __restrict__ Al,
    const bf16* __restrict__ Bh, const bf16* __restrict__ Bl,
    bf16* __restrict__ Ch, bf16* __restrict__ Cl,
    const float* __restrict__ bias,
    int M, int N, int K, int lda, int ldb, int ldc) {
  __shared__ __align__(16) bf16 Sah[2][128][32];
  __shared__ __align__(16) bf16 Sal[2][128][32];
  __shared__ __align__(16) bf16 Sbh[2][128][32];
  __shared__ __align__(16) bf16 Sbl[2][128][32];
  int bx = blockIdx.x, by = blockIdx.y;
  xcd_swizzle(bx, by);
  int bm = by * 128, bn = bx * 128;
  int tid = threadIdx.x;
  int lane = tid & 63, w = tid >> 6;
  int wr = (w >> 1) * 64, wc = (w & 1) * 64;
  int fr = lane & 15, fq = lane >> 4;
  f32x4 acc[4][4] = {};
  int srow = w * 32 + (lane >> 2);
  int scol = (lane & 3) * 8;
  const bf16* pAh[2]; const bf16* pAl[2];
  const bf16* pBh[2]; const bf16* pBl[2];
#pragma unroll
  for (int c = 0; c < 2; ++c) {
    long ga = (long)(bm + srow + c * 16) * lda + scol;
    long gb = (long)(bn + srow + c * 16) * ldb + scol;
    pAh[c] = Ah + ga; pAl[c] = Al + ga;
    pBh[c] = Bh + gb; pBl[c] = Bl + gb;
  }
  int nt = K >> 5;
#pragma unroll
  for (int c = 0; c < 2; ++c) {
    int lb = w * 1024 + c * 512;
    glds16(pAh[c], &Sah[0][0][0] + lb);
    glds16(pAl[c], &Sal[0][0][0] + lb);
    glds16(pBh[c], &Sbh[0][0][0] + lb);
    glds16(pBl[c], &Sbl[0][0][0] + lb);
  }
  if (nt > 1) {
#pragma unroll
    for (int c = 0; c < 2; ++c) {
      int lb = 4096 + w * 1024 + c * 512;
      glds16(pAh[c] + 32, &Sah[0][0][0] + lb);
      glds16(pAl[c] + 32, &Sal[0][0][0] + lb);
      glds16(pBh[c] + 32, &Sbh[0][0][0] + lb);
      glds16(pBl[c] + 32, &Sbl[0][0][0] + lb);
    }
  }
  long koff = 64;
  for (int t = 0; t < nt; ++t) {
    int p = t & 1;
    if (t + 1 < nt) pipe_wait8(); else pipe_wait0();
    bf16x8 ah[4], al[4], bh[4], bl[4];
#pragma unroll
    for (int i = 0; i < 4; ++i) {
      ah[i] = *(const bf16x8*)&Sah[p][wr + i * 16 + fr][fq * 8];
      al[i] = *(const bf16x8*)&Sal[p][wr + i * 16 + fr][fq * 8];
      bh[i] = *(const bf16x8*)&Sbh[p][wc + i * 16 + fr][fq * 8];
      bl[i] = *(const bf16x8*)&Sbl[p][wc + i * 16 + fr][fq * 8];
    }
#pragma unroll
    for (int i = 0; i < 4; ++i)
#pragma unroll
      for (int j = 0; j < 4; ++j) {
        acc[i][j] = __builtin_amdgcn_mfma_f32_16x16x32_bf16(ah[i], bh[j], acc[i][j], 0, 0, 0);
        acc[i][j] = __builtin_amdgcn_mfma_f32_16x16x32_bf16(ah[i], bl[j], acc[i][j], 0, 0, 0);
        acc[i][j] = __builtin_amdgcn_mfma_f32_16x16x32_bf16(al[i], bh[j], acc[i][j], 0, 0, 0);
      }
    pipe_readdone();
    if (t + 2 < nt) {
      int pb = p * 4096;
#pragma unroll
      for (int c = 0; c < 2; ++c) {
        int lb = pb + w * 1024 + c * 512;
        glds16(pAh[c] + koff, &Sah[0][0][0] + lb);
        glds16(pAl[c] + koff, &Sal[0][0][0] + lb);
        glds16(pBh[c] + koff, &Sbh[0][0][0] + lb);
        glds16(pBl[c] + koff, &Sbl[0][0][0] + lb);
      }
      koff += 32;
    }
  }
#pragma unroll
  for (int i = 0; i < 4; ++i)
#pragma unroll
    for (int j = 0; j < 4; ++j) {
      int gn = bn + wc + j * 16 + fr;
      if (gn >= N) continue;
      float bv = bias[gn];
#pragma unroll
      for (int r = 0; r < 4; ++r) {
        int gm = bm + wr + i * 16 + fq * 4 + r;
        if (gm >= M) continue;
        long co = (long)gm * ldc + gn;
        float v = acc[i][j][r] + bv;
        bf16 h = __float2bfloat16(v);
        Ch[co] = h;
        Cl[co] = __float2bfloat16(v - __bfloat162float(h));
      }
    }
}

// ---------------------------------------------------------------------------
// Split-precision QK^T, glds counted-vmcnt 2-phase. z = bl*4 + combo.
// ---------------------------------------------------------------------------
__global__ __launch_bounds__(256) void k_qkt3(
    const bf16* __restrict__ Qrh, const bf16* __restrict__ Qrl,
    const bf16* __restrict__ Qih, const bf16* __restrict__ Qil,
    const bf16* __restrict__ Krh, const bf16* __restrict__ Krl,
    const bf16* __restrict__ Kih, const bf16* __restrict__ Kil,
    float* __restrict__ S, int bp) {
  __shared__ __align__(16) bf16 Sqh[2][128][32];
  __shared__ __align__(16) bf16 Sql[2][128][32];
  __shared__ __align__(16) bf16 Skh[2][128][32];
  __shared__ __align__(16) bf16 Skl[2][128][32];
  int bl = blockIdx.z >> 2, c = blockIdx.z & 3;
  int b = bp * 2 + bl;
  long roff = (long)b * kT * kHDP2;
  const bf16* qh = ((c >> 1) ? Qih : Qrh) + roff;
  const bf16* ql = ((c >> 1) ? Qil : Qrl) + roff;
  const bf16* kh = ((c & 1) ? Kih : Krh) + roff;
  const bf16* kl = ((c & 1) ? Kil : Krl) + roff;
  float* So = S + ((long)bl * 4 + c) * kS2;
  int bx = blockIdx.x, by = blockIdx.y;
  xcd_swizzle(bx, by);
  int bm = by * 128, bn = bx * 128;
  int tid = threadIdx.x;
  int lane = tid & 63, w = tid >> 6;
  int wr = (w >> 1) * 64, wc = (w & 1) * 64;
  int fr = lane & 15, fq = lane >> 4;
  f32x4 acc[4][4] = {};
  int srow = w * 32 + (lane >> 2);
  int scol = (lane & 3) * 8;
  const bf16* pQh[2]; const bf16* pQl[2];
  const bf16* pKh[2]; const bf16* pKl[2];
#pragma unroll
  for (int cc = 0; cc < 2; ++cc) {
    long ga = (long)(bm + srow + cc * 16) * kHDP2 + scol;
    long gb = (long)(bn + srow + cc * 16) * kHDP2 + scol;
    pQh[cc] = qh + ga; pQl[cc] = ql + ga;
    pKh[cc] = kh + gb; pKl[cc] = kl + gb;
  }
  int nt = kHDP2 >> 5;
#pragma unroll
  for (int cc = 0; cc < 2; ++cc) {
    int lb = w * 1024 + cc * 512;
    glds16(pQh[cc], &Sqh[0][0][0] + lb);
    glds16(pQl[cc], &Sql[0][0][0] + lb);
    glds16(pKh[cc], &Skh[0][0][0] + lb);
    glds16(pKl[cc], &Skl[0][0][0] + lb);
  }
  if (nt > 1) {
#pragma unroll
    for (int cc = 0; cc < 2; ++cc) {
      int lb = 4096 + w * 1024 + cc * 512;
      glds16(pQh[cc] + 32, &Sqh[0][0][0] + lb);
      glds16(pQl[cc] + 32, &Sql[0][0][0] + lb);
      glds16(pKh[cc] + 32, &Skh[0][0][0] + lb);
      glds16(pKl[cc] + 32, &Skl[0][0][0] + lb);
    }
  }
  long koff = 64;
  for (int t = 0; t < nt; ++t) {
    int p = t & 1;
    if (t + 1 < nt) pipe_wait8(); else pipe_wait0();
    bf16x8 ah[4], al[4], bh[4], blv[4];
#pragma unroll
    for (int i = 0; i < 4; ++i) {
      ah[i]  = *(const bf16x8*)&Sqh[p][wr + i * 16 + fr][fq * 8];
      al[i]  = *(const bf16x8*)&Sql[p][wr + i * 16 + fr][fq * 8];
      bh[i]  = *(const bf16x8*)&Skh[p][wc + i * 16 + fr][fq * 8];
      blv[i] = *(const bf16x8*)&Skl[p][wc + i * 16 + fr][fq * 8];
    }
#pragma unroll
    for (int i = 0; i < 4; ++i)
#pragma unroll
      for (int j = 0; j < 4; ++j) {
        acc[i][j] = __builtin_amdgcn_mfma_f32_16x16x32_bf16(ah[i], bh[j],  acc[i][j], 0, 0, 0);
        acc[i][j] = __builtin_amdgcn_mfma_f32_16x16x32_bf16(ah[i], blv[j], acc[i][j], 0, 0, 0);
        acc[i][j] = __builtin_amdgcn_mfma_f32_16x16x32_bf16(al[i], bh[j],  acc[i][j], 0, 0, 0);
      }
    pipe_readdone();
    if (t + 2 < nt) {
      int pb = p * 4096;
#pragma unroll
      for (int cc = 0; cc < 2; ++cc) {
        int lb = pb + w * 1024 + cc * 512;
        glds16(pQh[cc] + koff, &Sqh[0][0][0] + lb);
        glds16(pQl[cc] + koff, &Sql[0][0][0] + lb);
        glds16(pKh[cc] + koff, &Skh[0][0][0] + lb);
        glds16(pKl[cc] + koff, &Skl[0][0][0] + lb);
      }
      koff += 32;
    }
  }
#pragma unroll
  for (int i = 0; i < 4; ++i)
#pragma unroll
    for (int j = 0; j < 4; ++j) {
      int gn = bn + wc + j * 16 + fr;
      if (gn >= kT) continue;
#pragma unroll
      for (int r = 0; r < 4; ++r) {
        int gm = bm + wr + i * 16 + fq * 4 + r;
        if (gm >= kT) continue;
        So[(long)gm * kT + gn] = acc[i][j][r];
      }
    }
}

// ---------------------------------------------------------------------------
// Complex-fused MFMA GEMM (FFN): 128x256 tile, 8 waves, single-buffered
// 48 KB LDS, plain 2-barrier loop (m97 structure: occupancy + intensity).
// Requirements: padded bf16 operands (A rows >= gridY*128, B rows >=
// gridX*256, lda/ldb == K mult of 32). C writes guarded by M/N.
// ---------------------------------------------------------------------------
template <typename TC>
__global__ __launch_bounds__(512) void k_cgemm(
    const bf16* __restrict__ Ar, const bf16* __restrict__ Ai,
    const bf16* __restrict__ Br, const bf16* __restrict__ Bi,
    TC* __restrict__ Cr, TC* __restrict__ Ci,
    const float* __restrict__ biasR, const float* __restrict__ biasI,
    float bscale, int accum, int relu, int Nreal,
    int M, int N, int K, int lda, int ldb, int ldc) {
  __shared__ __align__(16) bf16 Asr[128][32];
  __shared__ __align__(16) bf16 Asi[128][32];
  __shared__ __align__(16) bf16 Bsr[256][32];
  __shared__ __align__(16) bf16 Bsi[256][32];
  int bx = blockIdx.x, by = blockIdx.y;
  xcd_swizzle(bx, by);
  int bm = by * 128, bn = bx * 256;
  int tid = threadIdx.x;
  int lane = tid & 63, w = tid >> 6;        // 8 waves
  int wr = (w >> 2) * 64, wc = (w & 3) * 64;
  int fr = lane & 15, fq = lane >> 4;
  f32x4 acR[4][4] = {}, acI[4][4] = {};
  // staging: wave w stages rows w*16+(lane>>2); A 1 call, B 2 calls (c*128).
  int srow = w * 16 + (lane >> 2);
  int scol = (lane & 3) * 8;
  const bf16* pAr = Ar + (long)(bm + srow) * lda + scol;
  const bf16* pAi = Ai + (long)(bm + srow) * lda + scol;
  const bf16* pBr[2];
  const bf16* pBi[2];
#pragma unroll
  for (int c = 0; c < 2; ++c) {
    long gb = (long)(bn + c * 128 + srow) * ldb + scol;
    pBr[c] = Br + gb;
    pBi[c] = Bi + gb;
  }
  const short ks = (short)0x8000;
  const bf16x8 sgn = {ks, ks, ks, ks, ks, ks, ks, ks};
  for (int k0 = 0; k0 < K; k0 += 32) {
    glds16(pAr + k0, &Asr[0][0] + w * 512);
    glds16(pAi + k0, &Asi[0][0] + w * 512);
#pragma unroll
    for (int c = 0; c < 2; ++c) {
      int lb = c * 4096 + w * 512;
      glds16(pBr[c] + k0, &Bsr[0][0] + lb);
      glds16(pBi[c] + k0, &Bsi[0][0] + lb);
    }
    __syncthreads();
    bf16x8 ar[4], ai[4], nai[4];
#pragma unroll
    for (int i = 0; i < 4; ++i) {
      ar[i] = *(const bf16x8*)&Asr[wr + i * 16 + fr][fq * 8];
      ai[i] = *(const bf16x8*)&Asi[wr + i * 16 + fr][fq * 8];
      nai[i] = ai[i] ^ sgn;
    }
#pragma unroll
    for (int j = 0; j < 4; ++j) {
      bf16x8 br = *(const bf16x8*)&Bsr[wc + j * 16 + fr][fq * 8];
      bf16x8 bi = *(const bf16x8*)&Bsi[wc + j * 16 + fr][fq * 8];
#pragma unroll
      for (int i = 0; i < 4; ++i) {
        acR[i][j] = __builtin_amdgcn_mfma_f32_16x16x32_bf16(ar[i],  br, acR[i][j], 0, 0, 0);
        acR[i][j] = __builtin_amdgcn_mfma_f32_16x16x32_bf16(nai[i], bi, acR[i][j], 0, 0, 0);
        acI[i][j] = __builtin_amdgcn_mfma_f32_16x16x32_bf16(ai[i],  br, acI[i][j], 0, 0, 0);
        acI[i][j] = __builtin_amdgcn_mfma_f32_16x16x32_bf16(ar[i],  bi, acI[i][j], 0, 0, 0);
      }
    }
    __syncthreads();
  }
#pragma unroll
  for (int i = 0; i < 4; ++i)
#pragma unroll
    for (int j = 0; j < 4; ++j) {
      int gn = bn + wc + j * 16 + fr;
      if (gn >= N) continue;
      float br_ = 0.f, bi_ = 0.f;
      if (gn < Nreal) { br_ = biasR[gn]; bi_ = biasI[gn]; }
#pragma unroll
      for (int r = 0; r < 4; ++r) {
        int gm = bm + wr + i * 16 + fq * 4 + r;
        if (gm >= M) continue;
        long co = (long)gm * ldc + gn;
        float vR = acR[i][j][r] + bscale * (br_ - bi_);
        float vI = acI[i][j][r] + bscale * (br_ + bi_);
        if (accum) { vR += ldf(Cr, co); vI += ldf(Ci, co); }
        if (relu) { vR = fmaxf(vR, 0.f); vI = fmaxf(vI, 0.f); }
        sto(Cr, co, vR);
        sto(Ci, co, vI);
      }
    }
}

// ---------------------------------------------------------------------------
// Fused PV: Cr = P0@Vr + P2@Vi ; Ci = P0@Vi + P1@Vr. B is KxN (register path).
// ---------------------------------------------------------------------------
__global__ __launch_bounds__(256) void k_pv(
    const bf16* __restrict__ P, const bf16* __restrict__ Vr,
    const bf16* __restrict__ Vi, bf16* __restrict__ Cr,
    bf16* __restrict__ Ci, int M, int N, int K, int ldp, int ldv, int ldc) {
  __shared__ __align__(16) bf16 Ps0[128][40];
  __shared__ __align__(16) bf16 Ps1[128][40];
  __shared__ __align__(16) bf16 Ps2[128][40];
  __shared__ __align__(16) bf16 Vsr[128][40];
  __shared__ __align__(16) bf16 Vsi[128][40];
  int tid = threadIdx.x;
  int bm = blockIdx.y * 128, bn = blockIdx.x * 128;
  int lane = tid & 63, w = tid >> 6;
  int wr = (w >> 1) * 64, wc = (w & 1) * 64;
  int fr = lane & 15, fq = lane >> 4;
  f32x4 acR[4][4] = {}, acI[4][4] = {};
  int sr = tid >> 1, sk = (tid & 1) * 16;
  int kk = tid >> 3, nq = (tid & 7) * 16;
  for (int k0 = 0; k0 < K; k0 += 32) {
    stage_row16(P,            bm + sr, M, ldp, k0 + sk, K, &Ps0[sr][sk]);
    stage_row16(P + kS2P,     bm + sr, M, ldp, k0 + sk, K, &Ps1[sr][sk]);
    stage_row16(P + 2 * kS2P, bm + sr, M, ldp, k0 + sk, K, &Ps2[sr][sk]);
    {
      int gk = k0 + kk;
      bf16 t0[16], t1[16];
      if (gk < K && bn + nq + 16 <= N) {
        load16(Vr + (long)gk * ldv + bn + nq, t0);
        load16(Vi + (long)gk * ldv + bn + nq, t1);
      } else {
#pragma unroll
        for (int e = 0; e < 16; ++e) {
          int gn = bn + nq + e;
          bool ok = (gk < K && gn < N);
          t0[e] = __float2bfloat16(ok ? ldf(Vr, (long)gk * ldv + gn) : 0.f);
          t1[e] = __float2bfloat16(ok ? ldf(Vi, (long)gk * ldv + gn) : 0.f);
        }
      }
#pragma unroll
      for (int e = 0; e < 16; ++e) {
        Vsr[nq + e][kk] = t0[e];
        Vsi[nq + e][kk] = t1[e];
      }
    }
    __syncthreads();
    bf16x8 p0[4], p1[4], p2[4], vr[4], vi[4];
#pragma unroll
    for (int i = 0; i < 4; ++i) {
      p0[i] = *(const bf16x8*)&Ps0[wr + i * 16 + fr][fq * 8];
      p1[i] = *(const bf16x8*)&Ps1[wr + i * 16 + fr][fq * 8];
      p2[i] = *(const bf16x8*)&Ps2[wr + i * 16 + fr][fq * 8];
      vr[i] = *(const bf16x8*)&Vsr[wc + i * 16 + fr][fq * 8];
      vi[i] = *(const bf16x8*)&Vsi[wc + i * 16 + fr][fq * 8];
    }
#pragma unroll
    for (int i = 0; i < 4; ++i)
#pragma unroll
      for (int j = 0; j < 4; ++j) {
        acR[i][j] = __builtin_amdgcn_mfma_f32_16x16x32_bf16(p0[i], vr[j], acR[i][j], 0, 0, 0);
        acR[i][j] = __builtin_amdgcn_mfma_f32_16x16x32_bf16(p2[i], vi[j], acR[i][j], 0, 0, 0);
        acI[i][j] = __builtin_amdgcn_mfma_f32_16x16x32_bf16(p0[i], vi[j], acI[i][j], 0, 0, 0);
        acI[i][j] = __builtin_amdgcn_mfma_f32_16x16x32_bf16(p1[i], vr[j], acI[i][j], 0, 0, 0);
      }
    __syncthreads();
  }
#pragma unroll
  for (int i = 0; i < 4; ++i)
#pragma unroll
    for (int j = 0; j < 4; ++j) {
      int gn = bn + wc + j * 16 + fr;
      if (gn >= N) continue;
#pragma unroll
      for (int r = 0; r < 4; ++r) {
        int gm = bm + wr + i * 16 + fq * 4 + r;
        if (gm >= M) continue;
        long co = (long)gm * ldc + gn;
        Cr[co] = __float2bfloat16(acR[i][j][r]);
        Ci[co] = __float2bfloat16(acI[i][j][r]);
      }
    }
}

// Fused softmax over 4 fp32 score mats + fold to 3 bf16 P mats (stride kS2P).
__global__ __launch_bounds__(256) void k_smf(const float* __restrict__ S,
                                             bf16* __restrict__ P) {
  long rbase = (long)blockIdx.x * kT;
  long pbase = (long)blockIdx.x * kTP;
  int tid = threadIdx.x;
  int lane = tid & 63, w = tid >> 6;
  float v[4][4];
  float mx[4] = {-3.4e38f, -3.4e38f, -3.4e38f, -3.4e38f};
#pragma unroll
  for (int c = 0; c < 4; ++c) {
    const float* row = S + c * kS2 + rbase;
#pragma unroll
    for (int q = 0; q < 4; ++q) {
      int i = tid + q * 256;
      v[c][q] = (i < kT) ? row[i] : -3.4e38f;
      mx[c] = fmaxf(mx[c], v[c][q]);
    }
  }
  __shared__ float redm[4][4];
  for (int o = 32; o > 0; o >>= 1)
#pragma unroll
    for (int c = 0; c < 4; ++c) mx[c] = fmaxf(mx[c], __shfl_down(mx[c], o));
  if (lane == 0)
#pragma unroll
    for (int c = 0; c < 4; ++c) redm[w][c] = mx[c];
  __syncthreads();
#pragma unroll
  for (int c = 0; c < 4; ++c)
    mx[c] = fmaxf(fmaxf(redm[0][c], redm[1][c]), fmaxf(redm[2][c], redm[3][c]));
  __syncthreads();
  float sm[4] = {0.f, 0.f, 0.f, 0.f};
#pragma unroll
  for (int c = 0; c < 4; ++c)
#pragma unroll
    for (int q = 0; q < 4; ++q) {
      int i = tid + q * 256;
      if (i < kT) {
        v[c][q] = expf(kAttnScale * (v[c][q] - mx[c]));
        sm[c] += v[c][q];
      }
    }
  __shared__ float reds[4][4];
  for (int o = 32; o > 0; o >>= 1)
#pragma unroll
    for (int c = 0; c < 4; ++c) sm[c] += __shfl_down(sm[c], o);
  if (lane == 0)
#pragma unroll
    for (int c = 0; c < 4; ++c) reds[w][c] = sm[c];
  __syncthreads();
  float inv[4];
#pragma unroll
  for (int c = 0; c < 4; ++c)
    inv[c] = 1.f / (reds[0][c] + reds[1][c] + reds[2][c] + reds[3][c]);
  bf16* p0 = P + pbase;
  bf16* p1 = P + kS2P + pbase;
  bf16* p2 = P + 2 * kS2P + pbase;
#pragma unroll
  for (int q = 0; q < 4; ++q) {
    int i = tid + q * 256;
    if (i >= kT) continue;
    float a0 = v[0][q] * inv[0], a1 = v[1][q] * inv[1];
    float a2 = v[2][q] * inv[2], a3 = v[3][q] * inv[3];
    p0[i] = __float2bfloat16(a0 - a3);
    p1[i] = __float2bfloat16(a1 + a2);
    p2[i] = __float2bfloat16(a1 - a2);
  }
}

__global__ __launch_bounds__(256) void k_ln(float* __restrict__ X,
                                            const float* __restrict__ g,
                                            const float* __restrict__ b, int d) {
  long row = blockIdx.x;
  float* x = X + row * d;
  int tid = threadIdx.x;
  float s = 0.f, s2 = 0.f;
  for (int i = tid; i < d; i += 256) {
    float v = x[i];
    s += v;
    s2 = fmaf(v, v, s2);
  }
  __shared__ float rs[4], rs2[4];
  for (int o = 32; o > 0; o >>= 1) {
    s += __shfl_down(s, o);
    s2 += __shfl_down(s2, o);
  }
  int lane = tid & 63, w = tid >> 6;
  if (lane == 0) { rs[w] = s; rs2[w] = s2; }
  __syncthreads();
  float st = rs[0] + rs[1] + rs[2] + rs[3];
  float s2t = rs2[0] + rs2[1] + rs2[2] + rs2[3];
  float m = st / d;
  float var = s2t / d - m * m;
  float inv = rsqrtf(var + 1e-5f);
  for (int i = tid; i < d; i += 256) x[i] = (x[i] - m) * inv * g[i] + b[i];
}

__global__ void k_mask(const float* __restrict__ gr_, const float* __restrict__ gi_,
                       const float* __restrict__ c2wr, const float* __restrict__ c2br,
                       const float* __restrict__ c2wi, const float* __restrict__ c2bi,
                       float* __restrict__ spec) {
  long idx = (long)blockIdx.x * 256 + threadIdx.x;
  long total = (long)kB * 2 * kBINS * kT;
  if (idx >= total) return;
  int t = (int)(idx % kT);
  long r0 = idx / kT;
  int bin = (int)(r0 % kBINS);
  long r1 = r0 / kBINS;
  int ch = (int)(r1 % 2);
  int b = (int)(r1 / 2);
  long ro = ((long)(b * kT + t)) * kD + (bin * 2 + ch);
  float gr = gr_[ro], gi = gi_[ro];
  float wr = c2wr[ch], br = c2br[ch], wi = c2wi[ch], bi = c2bi[ch];
  float mr = (gr * wr + br) - (gi * wi + bi);
  float mi = (gi * wr + br) + (gr * wi + bi);
  float re = spec[idx * 2], im = spec[idx * 2 + 1];
  spec[idx * 2]     = re / (1.f + expf(-mr));
  spec[idx * 2 + 1] = im / (1.f + expf(-mi));
}

extern "C" void kernel_launch(void* const* d_in, const int* in_sizes, int n_in,
                              void* d_out, int out_size, void* d_ws, size_t ws_size,
                              hipStream_t stream) {
  const float* mix        = (const float*)d_in[0];
  const float* window     = (const float*)d_in[1];
  const float* c1wr       = (const float*)d_in[2];
  const float* c1br       = (const float*)d_in[3];
  const float* c1wi       = (const float*)d_in[4];
  const float* c1bi       = (const float*)d_in[5];
  const float* c2wr       = (const float*)d_in[6];
  const float* c2br       = (const float*)d_in[7];
  const float* c2wi       = (const float*)d_in[8];
  const float* c2bi       = (const float*)d_in[9];
  const float* attn_in_w  = (const float*)d_in[10];
  const float* attn_in_b  = (const float*)d_in[11];
  const float* attn_out_w = (const float*)d_in[12];
  const float* attn_out_b = (const float*)d_in[13];
  const float* l1wr       = (const float*)d_in[14];
  const float* l1br       = (const float*)d_in[15];
  const float* l1wi       = (const float*)d_in[16];
  const float* l1bi       = (const float*)d_in[17];
  const float* l2wr       = (const float*)d_in[18];
  const float* l2br       = (const float*)d_in[19];
  const float* l2wi       = (const float*)d_in[20];
  const float* l2bi       = (const float*)d_in[21];
  const float* n1_gr      = (const float*)d_in[22];
  const float* n1_br      = (const float*)d_in[23];
  const float* n1_gi      = (const float*)d_in[24];
  const float* n1_bi      = (const float*)d_in[25];
  const float* n2_gr      = (const float*)d_in[26];
  const float* n2_br      = (const float*)d_in[27];
  const float* n2_gi      = (const float*)d_in[28];
  const float* n2_bi      = (const float*)d_in[29];

  // ---- workspace layout (bytes), all constexpr. kNeed = 188,922,816.
  constexpr long eX    = (long)kMP * kDP2;     // 7,188,480
  constexpr long eQK2  = (long)kQKr * kHDP2;   // 3,683,328
  constexpr long eAout = (long)kBS * kDP;      // 7,089,088
  constexpr long eV    = (long)kBS * kHDP;     // 3,558,336
  constexpr long eWp   = (long)kWr * kDP2;     // 2,396,160
  constexpr long eHidp = (long)kMP * kNHP;     // 14,266,368
  constexpr long eW1p  = (long)kW1R * kDP2;    // 9,052,160
  constexpr long eW2p  = (long)kW2R * kNHP;    // 9,510,912

  constexpr size_t oX    = 0;
  constexpr size_t oQK   = oX + 4 * eX * 2;            //  57,507,840
  constexpr size_t oAout = oQK + 8 * eQK2 * 2;         // 116,441,088
  constexpr size_t oV    = oAout + 2 * eAout * 2;      // 144,797,440
  constexpr size_t oW    = oV + 2 * eV * 2;            // 159,030,784
  constexpr size_t oP    = oW + 5 * eWp * 2;           // 182,992,384
  constexpr size_t oTW   = oP + 3 * kS2P * 2;          // 187,460,992
  constexpr size_t kNeed = 188922816;
  static_assert(oTW + 8192 <= kNeed, "tw overflow");
  constexpr size_t oSS = oW;                           // scores overlay W
  static_assert(oSS + 8 * kS2 * 4 <= oP, "sS overflow");
  static_assert(2 * (long)kBS * kD * 4 <= (long)oQK, "xr/xi overlay");
  static_assert((long)kD * kDP * 2 <= (long)(oW - oV), "Wob overlay");
  // FFN overlays (attention dead):
  constexpr size_t oAb  = oQK;
  constexpr size_t oWF  = oAb + 2 * eX * 2;            //  86,261,760
  constexpr size_t oHid = oWF + 2 * eW2p * 2;          // 124,305,408
  static_assert(2 * eW1p * 2 <= 2 * eW2p * 2, "W slot sized by W2");
  static_assert(oHid + 2 * eHidp * 2 <= oTW, "hid overflow");
  static_assert((long)kNSIG * kT * 2048 * 4 <= (long)(oTW - oAb), "frames");

  char* wsb = (char*)d_ws;
  if (ws_size < kNeed) return;  // fail signature: out0 all-zero (2.578125)

  bf16*  Xrh = (bf16*)(wsb + oX);
  bf16*  Xrl = Xrh + eX;
  bf16*  Xih = Xrl + eX;
  bf16*  Xil = Xih + eX;
  bf16*  Qrh = (bf16*)(wsb + oQK);
  bf16*  Qrl = Qrh + eQK2;
  bf16*  Qih = Qrl + eQK2;
  bf16*  Qil = Qih + eQK2;
  bf16*  Krh = Qil + eQK2;
  bf16*  Krl = Krh + eQK2;
  bf16*  Kih = Krl + eQK2;
  bf16*  Kil = Kih + eQK2;
  bf16*  aoutR = (bf16*)(wsb + oAout);
  bf16*  aoutI = aoutR + eAout;
  bf16*  Vr = (bf16*)(wsb + oV);
  bf16*  Vi = Vr + eV;
  bf16*  Wqh = (bf16*)(wsb + oW);
  bf16*  Wql = Wqh + eWp;
  bf16*  Wkh = Wql + eWp;
  bf16*  Wkl = Wkh + eWp;
  bf16*  Wvh = Wkl + eWp;
  float* sS = (float*)(wsb + oSS);
  bf16*  Pbuf = (bf16*)(wsb + oP);
  bf16*  Wob = (bf16*)(wsb + oV);          // out-proj W (V dead)
  float* xr = (float*)(wsb + oX);          // post-attn fp32 (X dead)
  float* xi = xr + (long)kBS * kD;
  // FFN pointers:
  bf16*  AbR = (bf16*)(wsb + oAb);
  bf16*  AbI = AbR + eX;
  bf16*  w1rH = (bf16*)(wsb + oWF);
  bf16*  w1iH = w1rH + eW1p;
  bf16*  w2rH = (bf16*)(wsb + oWF);
  bf16*  w2iH = w2rH + eW2p;
  bf16*  hidR = (bf16*)(wsb + oHid);
  bf16*  hidI = hidR + eHidp;
  float* frames = (float*)(wsb + oAb);
  float2* tw = (float2*)(wsb + oTW);

  float* out0 = (float*)d_out;
  float* spec = out0 + (long)kNSIG * kL;

  auto cvt2 = [&](const float* src, bf16* dst, int dstRows, int ldd,
                  int srows, int scols, int lds) {
    long total = (long)dstRows * ldd;
    k_cvt2<<<(int)((total + 255) / 256), 256, 0, stream>>>(src, dst, total,
                                                           ldd, srows, scols,
                                                           lds);
  };
  auto cvt2s = [&](const float* src, bf16* dh, bf16* dl, int dstRows, int ldd,
                   int srows, int scols, int lds) {
    long total = (long)dstRows * ldd;
    k_cvt2s<<<(int)((total + 255) / 256), 256, 0, stream>>>(
        src, dh, dl, total, ldd, srows, scols, lds);
  };

  // 0) zero workspace (pads must be zero for glds paths), twiddle table
  hipMemsetAsync(d_ws, 0, kNeed, stream);
  k_twiddle<<<4, 256, 0, stream>>>(tw);

  // 1) STFT -> spec (out1)
  k_stft<<<dim3(kT, kNSIG), 256, 0, stream>>>(mix, window, tw, spec);

  // 2) conv1 + pos-enc -> split-bf16 tokens (stride kDP2)
  long nct = (long)kB * 2 * kBINS * kT;
  k_conv1_pe<<<(nct + 255) / 256, 256, 0, stream>>>(spec, c1wr, c1br, c1wi,
                                                    c1bi, Xrh, Xrl, Xih, Xil);

  // 3) attention, per head
  for (int h = 0; h < 2; ++h) {
    const float* Wq = attn_in_w + (long)(h * kHD) * kD;
    const float* Wk = attn_in_w + (long)(kD + h * kHD) * kD;
    const float* Wv = attn_in_w + (long)(2 * kD + h * kHD) * kD;
    const float* bq = attn_in_b + h * kHD;
    const float* bk = attn_in_b + kD + h * kHD;
    const float* bv = attn_in_b + 2 * kD + h * kHD;
    cvt2s(Wq, Wqh, Wql, kWr, kDP2, kHD, kD, kD);
    cvt2s(Wk, Wkh, Wkl, kWr, kDP2, kHD, kD, kD);
    cvt2(Wv, Wvh, kWr, kDP2, kHD, kD, kD);
    k_mfma2<bf16, bf16><<<dim3(9, 27), 256, 0, stream>>>(
        Xrh, Xih, Wvh, Vr, Vi, bv, 1.f, 1.f, kBS, kHD, kD, kDP2, kDP2, kHDP);
    k_gemm3s<<<dim3(9, 27), 256, 0, stream>>>(
        Xrh, Xrl, Wqh, Wql, Qrh, Qrl, bq, kBS, kHD, kDP2, kDP2, kDP2, kHDP2);
    k_gemm3s<<<dim3(9, 27), 256, 0, stream>>>(
        Xih, Xil, Wqh, Wql, Qih, Qil, bq, kBS, kHD, kDP2, kDP2, kDP2, kHDP2);
    k_gemm3s<<<dim3(9, 27), 256, 0, stream>>>(
        Xrh, Xrl, Wkh, Wkl, Krh, Krl, bk, kBS, kHD, kDP2, kDP2, kDP2, kHDP2);
    k_gemm3s<<<dim3(9, 27), 256, 0, stream>>>(
        Xih, Xil, Wkh, Wkl, Kih, Kil, bk, kBS, kHD, kDP2, kDP2, kDP2, kHDP2);
    for (int bp = 0; bp < 2; ++bp) {
      k_qkt3<<<dim3(7, 7, 8), 256, 0, stream>>>(Qrh, Qrl, Qih, Qil,
                                                Krh, Krl, Kih, Kil, sS, bp);
      for (int bl = 0; bl < 2; ++bl) {
        int b = bp * 2 + bl;
        k_smf<<<kT, 256, 0, stream>>>(sS + (long)bl * 4 * kS2, Pbuf);
        k_pv<<<dim3(9, 7), 256, 0, stream>>>(
            Pbuf, Vr + (long)b * kT * kHDP, Vi + (long)b * kT * kHDP,
            aoutR + (long)b * kT * kDP + h * kHD,
            aoutI + (long)b * kT * kDP + h * kHD,
            kT, kHD, kT, kTP, kHDP, kDP);
      }
    }
  }

  // 4) output projection (register path) -> fp32 xr, xi (X arena; X dead)
  cvt2(attn_out_w, Wob, kD, kDP, kD, kD, kD);
  k_mfma2<bf16, float><<<dim3(17, 27), 256, 0, stream>>>(
      aoutR, aoutI, Wob, xr, xi, attn_out_b, 0.f, 2.f,
      kBS, kD, kD, kDP, kDP, kD);

  // 5) LN1
  k_ln<<<kBS, 256, 0, stream>>>(xr, n1_gr, n1_br, kD);
  k_ln<<<kBS, 256, 0, stream>>>(xi, n1_gi, n1_bi, kD);

  // 6) FFN (complex-fused, 128x256 tile / 8 waves / single-buffer LDS)
  cvt2(xr, AbR, kMP, kDP2, kBS, kD, kD);
  cvt2(xi, AbI, kMP, kDP2, kBS, kD, kD);
  for (int nh = 0; nh < 2; ++nh) {
    int srows = (nh ? kDFF - kNH : kNH);   // 4096 : 4104
    cvt2(l1wr + (long)nh * kNH * kD, w1rH, kW1R, kDP2, srows, kD, kD);
    cvt2(l1wi + (long)nh * kNH * kD, w1iH, kW1R, kDP2, srows, kD, kD);
    k_cgemm<bf16><<<dim3(17, 27), 512, 0, stream>>>(
        AbR, AbI, w1rH, w1iH, hidR, hidI,
        l1br + nh * kNH, l1bi + nh * kNH, 1.f, 0, 1, srows,
        kBS, kNHP, kDP2, kDP2, kDP2, kNHP);
    cvt2(l2wr + nh * kNH, w2rH, kW2R, kNHP, kD, srows, kDFF);
    cvt2(l2wi + nh * kNH, w2iH, kW2R, kNHP, kD, srows, kDFF);
    k_cgemm<float><<<dim3(9, 27), 512, 0, stream>>>(
        hidR, hidI, w2rH, w2iH, xr, xi,
        l2br, l2bi, (nh == 0 ? 1.f : 0.f), nh, 0, kD,
        kBS, kD, kNHP, kNHP, kNHP, kD);
  }

  // 7) LN2
  k_ln<<<kBS, 256, 0, stream>>>(xr, n2_gr, n2_br, kD);
  k_ln<<<kBS, 256, 0, stream>>>(xi, n2_gi, n2_bi, kD);

  // 8) mask + gate spec in place
  k_mask<<<(nct + 255) / 256, 256, 0, stream>>>(xr, xi, c2wr, c2br, c2wi,
                                                c2bi, spec);

  // 9) iSTFT + overlap-add
  k_istft<<<dim3(kT, kNSIG), 256, 0, stream>>>(spec, window, tw, frames);
  k_gather<<<(int)(((long)kNSIG * kL + 255) / 256), 256, 0, stream>>>(
      frames, window, out0);
}